// Round 1
// baseline (1216.538 us; speedup 1.0000x reference)
//
#include <hip/hip_runtime.h>
#include <cstdint>
#include <cstddef>

#define DI __device__ __forceinline__

namespace pk {

constexpr int NB1 = 65536;      // stage-1 nodes (B*N)
constexpr int NE  = 1048576;    // edges (B*N*DEG)
constexpr int BG  = 8;          // graphs
constexpr int KP1 = 2458;       // top-k 1
constexpr int KP2 = 738;        // top-k 2
constexpr int NN2 = BG*KP1;     // 19664
constexpr int NN3 = BG*KP2;     // 5904
constexpr int CAP2 = 524288;    // edge-buffer cap after pool1 (expected ~94K)
constexpr int CAP3 = 131072;    // edge-buffer cap after pool2 (expected ~8.5K)

DI float lrelu(float x){ return x > 0.f ? x : 0.2f*x; }
DI float eluf(float x){ return x > 0.f ? x : expf(x) - 1.f; }

// ---- stage-1 projection: xp = pos @ W1 (K=3), plus attention logits per head
__global__ __launch_bounds__(256) void k_xp1(
    const float* __restrict__ pos, const float* __restrict__ W,
    const float* __restrict__ as_, const float* __restrict__ ad_,
    float* __restrict__ xp, float* __restrict__ als, float* __restrict__ ald){
  int i = blockIdx.x*256 + threadIdx.x;
  if(i >= NB1) return;
  float p0=pos[3*i], p1=pos[3*i+1], p2=pos[3*i+2];
  float row[32];
#pragma unroll
  for(int c=0;c<32;c++) row[c] = p0*W[c] + p1*W[32+c] + p2*W[64+c];
  float s0=0.f,d0=0.f,s1=0.f,d1=0.f;
#pragma unroll
  for(int f=0;f<16;f++){
    s0 += row[f]*as_[f];        d0 += row[f]*ad_[f];
    s1 += row[16+f]*as_[16+f];  d1 += row[16+f]*ad_[16+f];
  }
  float4* o = reinterpret_cast<float4*>(xp + (size_t)i*32);
#pragma unroll
  for(int q=0;q<8;q++) o[q] = make_float4(row[4*q],row[4*q+1],row[4*q+2],row[4*q+3]);
  als[2*i]=s0; als[2*i+1]=s1; ald[2*i]=d0; ald[2*i+1]=d1;
}

DI int edge_m(const int* mptr, int fixedm, int mcap){
  int m = mptr ? *mptr : fixedm;
  return m < mcap ? m : mcap;
}

__global__ __launch_bounds__(256) void k_edge_count(
    const int* __restrict__ de, const int* __restrict__ mptr,
    int fixedm, int mcap, int* __restrict__ cnt){
  int i = blockIdx.x*256 + threadIdx.x;
  if(i < edge_m(mptr,fixedm,mcap)) atomicAdd(&cnt[de[i]], 1);
}

__global__ __launch_bounds__(256) void k_scatter(
    const int* __restrict__ se, const int* __restrict__ de,
    const int* __restrict__ mptr, int fixedm, int mcap,
    int* __restrict__ cursor, int* __restrict__ eo){
  int i = blockIdx.x*256 + threadIdx.x;
  if(i < edge_m(mptr,fixedm,mcap)){
    int p = atomicAdd(&cursor[de[i]], 1);
    eo[p] = se[i];
  }
}

__global__ __launch_bounds__(256) void k_edge_compact(
    const int* __restrict__ se, const int* __restrict__ de,
    const int* __restrict__ mptr, int fixedm, int mcap,
    const int* __restrict__ newid, int* __restrict__ ocnt,
    int* __restrict__ ons, int* __restrict__ ond, int ocap){
  int i = blockIdx.x*256 + threadIdx.x;
  if(i >= edge_m(mptr,fixedm,mcap)) return;
  int a = newid[se[i]], b = newid[de[i]];
  if(a>=0 && b>=0){
    int s = atomicAdd(ocnt, 1);
    if(s < ocap){ ons[s]=a; ond[s]=b; }
  }
}

// single-block hierarchical exclusive scan (wave shfl + LDS wave sums)
__global__ __launch_bounds__(1024) void k_scan(
    const int* __restrict__ cnt, int n, int* __restrict__ rowptr, int* __restrict__ cursor){
  __shared__ int wsum[16];
  __shared__ int carry;
  int tid = threadIdx.x, lane = tid & 63, w = tid >> 6;
  if(tid==0) carry = 0;
  __syncthreads();
  const int PER = 16, CH = 1024*PER;
  for(int bb=0; bb<n; bb+=CH){
    int vals[PER]; int s=0;
    int i0 = bb + tid*PER;
#pragma unroll
    for(int j=0;j<PER;j++){ int i=i0+j; int v=(i<n)?cnt[i]:0; vals[j]=s; s+=v; }
    int inc = s;
    for(int o=1;o<64;o<<=1){ int t=__shfl_up(inc,o,64); if(lane>=o) inc+=t; }
    if(lane==63) wsum[w]=inc;
    __syncthreads();
    int wb=0;
    for(int k=0;k<w;k++) wb+=wsum[k];
    int c0 = carry;
    int tb = c0 + wb + inc - s;
#pragma unroll
    for(int j=0;j<PER;j++){ int i=i0+j; if(i<n){ int e=tb+vals[j]; rowptr[i]=e; cursor[i]=e; } }
    __syncthreads();
    if(tid==1023) carry = c0 + wb + inc;
    __syncthreads();
  }
  if(tid==0) rowptr[n]=carry;
}

// GAT softmax-aggregate: C=H*F lanes per dst node, two passes over incoming
// edges (max, then exp/acc), self-loop folded in. al loads are wave-broadcast;
// xp gathers are C-wide coalesced.
template<int H,int F>
__global__ __launch_bounds__(256) void k_gat_agg(
    const float* __restrict__ xp, const float* __restrict__ als,
    const float* __restrict__ ald, const int* __restrict__ rowptr,
    const int* __restrict__ esrc, const float* __restrict__ bias,
    float* __restrict__ out, int n){
  constexpr int C = H*F;
  int t = blockIdx.x*256 + threadIdx.x;
  int node = t / C, j = t % C, hh = j / F;
  if(node >= n) return;
  float aldn = ald[node*H+hh];
  float es = lrelu(als[node*H+hh] + aldn);
  int r0 = rowptr[node], r1 = rowptr[node+1];
  float mx = es;
  for(int k=r0;k<r1;k++){ int s=esrc[k]; mx = fmaxf(mx, lrelu(als[s*H+hh]+aldn)); }
  float den = expf(es-mx);
  float acc = den * xp[(size_t)node*C+j];
  for(int k=r0;k<r1;k++){
    int s=esrc[k];
    float ex = expf(lrelu(als[s*H+hh]+aldn)-mx);
    den += ex;
    acc += ex * xp[(size_t)s*C+j];
  }
  out[(size_t)node*C+j] = acc/den + bias[j];
}

__global__ __launch_bounds__(256) void k_al(
    const float* __restrict__ xp, const float* __restrict__ a_s,
    const float* __restrict__ a_d, int n, int H, int F,
    float* __restrict__ als, float* __restrict__ ald){
  int i = blockIdx.x*256+threadIdx.x;
  if(i >= n*H) return;
  int node = i/H, hh = i%H;
  const float* row = xp + (size_t)node*H*F + hh*F;
  float s=0.f, d=0.f;
  for(int f=0;f<F;f++){ s += row[f]*a_s[hh*F+f]; d += row[f]*a_d[hh*F+f]; }
  als[i]=s; ald[i]=d;
}

__global__ __launch_bounds__(256) void k_inorm_stats(
    const float* __restrict__ x, int R, int C, int RS, float* __restrict__ accum){
  int g = blockIdx.x / RS, blk = blockIdx.x % RS;
  int NS = 256 / C;
  int c = threadIdx.x % C, rs = threadIdx.x / C;
  int chunk = (R + RS - 1)/RS;
  int rlo = blk*chunk, rhi = rlo+chunk; if(rhi>R) rhi=R;
  float s=0.f, sq=0.f;
  for(int r=rlo+rs; r<rhi; r+=NS){ float v = x[((size_t)g*R+r)*C + c]; s+=v; sq+=v*v; }
  atomicAdd(&accum[(g*C+c)*2], s);
  atomicAdd(&accum[(g*C+c)*2+1], sq);
}

__global__ __launch_bounds__(256) void k_inorm_apply(
    float* __restrict__ x, const float* __restrict__ accum, int R, int C, int total){
  int i = blockIdx.x*256+threadIdx.x;
  if(i>=total) return;
  int c = i % C; int g = i / (R*C);
  float s = accum[(g*C+c)*2], sq = accum[(g*C+c)*2+1];
  float mu = s / (float)R;
  float var = sq / (float)R - mu*mu; var = fmaxf(var, 0.f);
  float v = (x[i]-mu)*rsqrtf(var+1e-5f);
  x[i] = eluf(v);
}

__global__ __launch_bounds__(256) void k_score(
    const float* __restrict__ x, const float* __restrict__ p,
    int C, int n, float* __restrict__ score, unsigned* __restrict__ u){
  int i = blockIdx.x*256+threadIdx.x;
  if(i>=n) return;
  float a=0.f, nn=0.f;
  for(int c=0;c<C;c++){ float pv=p[c]; a += x[(size_t)i*C+c]*pv; nn += pv*pv; }
  float sv = tanhf(a/sqrtf(nn));
  score[i]=sv;
  unsigned bts = __float_as_uint(sv);
  u[i] = (bts & 0x80000000u) ? ~bts : (bts | 0x80000000u);
}

// per-graph 3-level radix select on orderable uints: exact k-th value + #ties needed
__global__ __launch_bounds__(1024) void k_select(
    const unsigned* __restrict__ u, int R, int Ksel,
    unsigned* __restrict__ thr_out, int* __restrict__ need_out){
  __shared__ int hist[2048];
  __shared__ int seg[32];
  __shared__ int sh_b, sh_k;
  int g = blockIdx.x, tid = threadIdx.x;
  const unsigned* ug = u + (size_t)g*R;
  unsigned prefix = 0;
  int K = Ksel;
  for(int lev=0; lev<3; lev++){
    int shf = (lev==0)?21:((lev==1)?10:0);
    int nb  = (lev==2)?1024:2048;
    for(int i=tid;i<2048;i+=1024) hist[i]=0;
    __syncthreads();
    for(int i=tid;i<R;i+=1024){
      unsigned v = ug[i];
      bool ok = (lev==0) || (lev==1 && (v>>21)==prefix) || (lev==2 && (v>>10)==prefix);
      if(ok) atomicAdd(&hist[(v>>shf)&(nb-1)], 1);
    }
    __syncthreads();
    int W = nb/32;
    if(tid<32){ int s=0; int lo=nb-W*(tid+1); for(int b=lo;b<lo+W;b++) s+=hist[b]; seg[tid]=s; }
    __syncthreads();
    if(tid==0){
      int kk=K, sgi=0;
      while(seg[sgi]<kk){ kk-=seg[sgi]; sgi++; }
      int b = nb-1-W*sgi;
      while(hist[b]<kk){ kk-=hist[b]; b--; }
      sh_b=b; sh_k=kk;
    }
    __syncthreads();
    int b = sh_b; K = sh_k;
    if(lev==0) prefix = (unsigned)b;
    else if(lev==1) prefix = (prefix<<11) | (unsigned)b;
    else prefix = (prefix<<10) | (unsigned)b;
    __syncthreads();
  }
  if(tid==0){ thr_out[g]=prefix; need_out[g]=K; }
}

// deterministic compaction: take u>thr plus lowest-index u==thr (matches lax.top_k ties)
__global__ __launch_bounds__(1024) void k_compact(
    const unsigned* __restrict__ u, const float* __restrict__ score,
    const unsigned* __restrict__ thr_arr, const int* __restrict__ need_arr,
    int R, int Kout, int* __restrict__ newid, int* __restrict__ oldid,
    float* __restrict__ scale){
  __shared__ int wsA[16], wsB[16];
  __shared__ int carr0, carr1;
  int g = blockIdx.x, tid = threadIdx.x, lane = tid&63, w = tid>>6;
  unsigned thr = thr_arr[g]; int need = need_arr[g];
  if(tid==0){ carr0=0; carr1=0; }
  __syncthreads();
  for(int bb=0; bb<R; bb+=1024){
    int i = bb + tid; bool in = i < R;
    unsigned uv = in ? u[(size_t)g*R+i] : 0u;
    int eq = (in && uv==thr) ? 1:0;
    int gt = (in && uv>thr) ? 1:0;
    int inc = eq;
    for(int o=1;o<64;o<<=1){ int t=__shfl_up(inc,o,64); if(lane>=o) inc+=t; }
    if(lane==63) wsA[w]=inc;
    __syncthreads();
    int wb=0; for(int k=0;k<w;k++) wb+=wsA[k];
    int eq_excl = carr0 + wb + inc - eq;
    int take = (gt || (eq && eq_excl<need)) ? 1 : 0;
    int inc2 = take;
    for(int o=1;o<64;o<<=1){ int t=__shfl_up(inc2,o,64); if(lane>=o) inc2+=t; }
    if(lane==63) wsB[w]=inc2;
    __syncthreads();
    int wb2=0; for(int k=0;k<w;k++) wb2+=wsB[k];
    int pos = carr1 + wb2 + inc2 - take;
    if(take){
      int nr = g*Kout + pos;
      newid[(size_t)g*R+i] = nr;
      oldid[nr] = g*R+i;
      scale[nr] = score[(size_t)g*R+i];
    }
    __syncthreads();
    if(tid==1023){ carr0 += wb + inc; carr1 += wb2 + inc2; }
    __syncthreads();
  }
}

__global__ __launch_bounds__(256) void k_pool_gather(
    const float* __restrict__ x, const int* __restrict__ oldid,
    const float* __restrict__ scale, int C, int total, float* __restrict__ xnew){
  int i = blockIdx.x*256+threadIdx.x;
  if(i>=total) return;
  int r = i / C, c = i % C;
  xnew[i] = x[(size_t)oldid[r]*C + c] * scale[r];
}

// dense row-GEMM: block = 256 threads = (256/CO subgroups) x CO channels,
// each subgroup owns NPG rows staged in LDS (broadcast reads)
template<int K,int CO,int NPG,bool DOELU>
__global__ __launch_bounds__(256) void k_gemm(
    const float* __restrict__ X, const float* __restrict__ W,
    const float* __restrict__ bias, float* __restrict__ Y, int n){
  constexpr int SUB = 256/CO;
  constexpr int NB = SUB*NPG;
  __shared__ float xs[NB][K];
  int tid = threadIdx.x;
  int c = tid % CO, sg = tid / CO;
  int n0 = blockIdx.x * NB;
  for(int idx=tid; idx<NB*K; idx+=256){
    int r = idx / K, k = idx % K;
    int row = n0 + r;
    xs[r][k] = (row < n) ? X[(size_t)row*K + k] : 0.f;
  }
  __syncthreads();
  float acc[NPG];
#pragma unroll
  for(int q=0;q<NPG;q++) acc[q]=0.f;
  for(int k=0;k<K;k++){
    float wv = W[(size_t)k*CO + c];
#pragma unroll
    for(int q=0;q<NPG;q++) acc[q] += xs[sg*NPG+q][k]*wv;
  }
  float bv = bias ? bias[c] : 0.f;
#pragma unroll
  for(int q=0;q<NPG;q++){
    int row = n0 + sg*NPG + q;
    if(row < n){
      float v = acc[q] + bv;
      if(DOELU) v = eluf(v);
      Y[(size_t)row*CO + c] = v;
    }
  }
}

__global__ __launch_bounds__(256) void k_mlp(
    const float* __restrict__ X, const float* __restrict__ W,
    const float* __restrict__ b, float* __restrict__ Y,
    int n, int K, int CO, int act){
  int i = blockIdx.x*256+threadIdx.x;
  if(i>=n*CO) return;
  int r=i/CO, c=i%CO;
  float a=0.f;
  for(int k=0;k<K;k++) a += X[(size_t)r*K+k]*W[(size_t)k*CO+c];
  a += b[c];
  if(act) a = eluf(a);
  Y[i]=a;
}

__global__ __launch_bounds__(256) void k_attn(
    const float* __restrict__ gate, const float* __restrict__ h,
    float* __restrict__ gout){
  __shared__ float pbuf[KP2];
  __shared__ float red[256];
  int g = blockIdx.x, tid = threadIdx.x;
  float mx = -1e30f;
  for(int r=tid;r<KP2;r+=256) mx = fmaxf(mx, gate[g*KP2+r]);
  red[tid]=mx; __syncthreads();
  for(int s=128;s>0;s>>=1){ if(tid<s) red[tid]=fmaxf(red[tid],red[tid+s]); __syncthreads(); }
  mx = red[0]; __syncthreads();
  float sm=0.f;
  for(int r=tid;r<KP2;r+=256){ float e=expf(gate[g*KP2+r]-mx); pbuf[r]=e; sm+=e; }
  red[tid]=sm; __syncthreads();
  for(int s=128;s>0;s>>=1){ if(tid<s) red[tid]+=red[tid+s]; __syncthreads(); }
  float inv = 1.f/red[0];
  float acc=0.f;
  for(int r=0;r<KP2;r++) acc += pbuf[r]*h[((size_t)g*KP2+r)*256 + tid];
  gout[g*256+tid]=acc*inv;
}

__global__ __launch_bounds__(64) void k_head(
    const float* __restrict__ z2, const float* __restrict__ w3,
    const float* __restrict__ b3, float* __restrict__ out){
  __shared__ float zc[10]; __shared__ float mred, sred;
  int g=blockIdx.x, tid=threadIdx.x;
  if(tid<10){
    float a=0.f;
    for(int k=0;k<128;k++) a += z2[g*128+k]*w3[k*10+tid];
    zc[tid]=a+b3[tid];
  }
  __syncthreads();
  if(tid==0){
    float m=zc[0];
    for(int k=1;k<10;k++) m=fmaxf(m,zc[k]);
    float s=0.f;
    for(int k=0;k<10;k++) s+=expf(zc[k]-m);
    mred=m; sred=logf(s);
  }
  __syncthreads();
  if(tid<10) out[g*10+tid]=zc[tid]-mred-sred;
}

} // namespace pk

extern "C" void kernel_launch(void* const* d_in, const int* in_sizes, int n_in,
                              void* d_out, int out_size, void* d_ws, size_t ws_size,
                              hipStream_t stream){
  using namespace pk;
  (void)in_sizes; (void)n_in; (void)out_size;
  const float* pos = (const float*)d_in[0];
  const int*   src = (const int*)d_in[1];
  const int*   dst = (const int*)d_in[2];
  const float* W1  = (const float*)d_in[3];
  const float* as1 = (const float*)d_in[4];
  const float* ad1 = (const float*)d_in[5];
  const float* b1  = (const float*)d_in[6];
  const float* p1  = (const float*)d_in[7];
  const float* W2  = (const float*)d_in[8];
  const float* as2 = (const float*)d_in[9];
  const float* ad2 = (const float*)d_in[10];
  const float* b2  = (const float*)d_in[11];
  const float* p2  = (const float*)d_in[12];
  const float* W3  = (const float*)d_in[13];
  const float* as3 = (const float*)d_in[14];
  const float* ad3 = (const float*)d_in[15];
  const float* b3  = (const float*)d_in[16];
  const float* gw1 = (const float*)d_in[17];
  const float* gb1 = (const float*)d_in[18];
  const float* gw2 = (const float*)d_in[19];
  const float* gb2 = (const float*)d_in[20];
  const float* aw  = (const float*)d_in[21];
  const float* ab  = (const float*)d_in[22];
  const float* w1  = (const float*)d_in[23];
  const float* bb1 = (const float*)d_in[24];
  const float* w2  = (const float*)d_in[25];
  const float* bb2 = (const float*)d_in[26];
  const float* w3  = (const float*)d_in[27];
  const float* bb3 = (const float*)d_in[28];
  float* out = (float*)d_out;

  char* base = (char*)d_ws; size_t off = 0;
  auto alloc = [&](size_t nbytes)->char*{
    char* p = base + off; off = (off + nbytes + 255) & ~(size_t)255; return p;
  };
  // --- zero-init region (one memset) ---
  int*   cnt1  = (int*)alloc((size_t)NB1*4);
  int*   cnt2  = (int*)alloc((size_t)NN2*4);
  int*   cnt3  = (int*)alloc((size_t)NN3*4);
  int*   ecnt2 = (int*)alloc(4);
  int*   ecnt3 = (int*)alloc(4);
  float* acc1  = (float*)alloc((size_t)BG*32*2*4);
  float* acc2  = (float*)alloc((size_t)BG*128*2*4);
  float* acc3  = (float*)alloc((size_t)BG*256*2*4);
  size_t zend = off;
  // --- 0xFF-init region (newid = -1, one memset) ---
  int*   newid1 = (int*)alloc((size_t)NB1*4);
  int*   newid2 = (int*)alloc((size_t)NN2*4);
  size_t fstart = (size_t)((char*)newid1 - base);
  size_t fend = off;
  // --- plain scratch ---
  float*    xp1    = (float*)alloc((size_t)NB1*32*4);
  float*    als1   = (float*)alloc((size_t)NB1*2*4);
  float*    ald1   = (float*)alloc((size_t)NB1*2*4);
  int*      rowptr1= (int*)alloc((size_t)(NB1+1)*4);
  int*      cursor1= (int*)alloc((size_t)NB1*4);
  int*      esrc1  = (int*)alloc((size_t)NE*4);
  float*    out1   = (float*)alloc((size_t)NB1*32*4);
  float*    score1 = (float*)alloc((size_t)NB1*4);
  unsigned* u1     = (unsigned*)alloc((size_t)NB1*4);
  unsigned* thr1   = (unsigned*)alloc((size_t)BG*4);
  int*      need1  = (int*)alloc((size_t)BG*4);
  int*      oldid1 = (int*)alloc((size_t)NN2*4);
  float*    scale1 = (float*)alloc((size_t)NN2*4);
  float*    xnew1  = (float*)alloc((size_t)NN2*32*4);
  int*      ns2    = (int*)alloc((size_t)CAP2*4);
  int*      nd2    = (int*)alloc((size_t)CAP2*4);
  int*      rowptr2= (int*)alloc((size_t)(NN2+1)*4);
  int*      cursor2= (int*)alloc((size_t)NN2*4);
  int*      esrc2  = (int*)alloc((size_t)CAP2*4);
  float*    xp2    = (float*)alloc((size_t)NN2*128*4);
  float*    als2   = (float*)alloc((size_t)NN2*2*4);
  float*    ald2   = (float*)alloc((size_t)NN2*2*4);
  float*    out2   = (float*)alloc((size_t)NN2*128*4);
  float*    score2 = (float*)alloc((size_t)NN2*4);
  unsigned* u2     = (unsigned*)alloc((size_t)NN2*4);
  unsigned* thr2   = (unsigned*)alloc((size_t)BG*4);
  int*      need2  = (int*)alloc((size_t)BG*4);
  int*      oldid2 = (int*)alloc((size_t)NN3*4);
  float*    scale2 = (float*)alloc((size_t)NN3*4);
  float*    xnew2  = (float*)alloc((size_t)NN3*128*4);
  int*      ns3    = (int*)alloc((size_t)CAP3*4);
  int*      nd3    = (int*)alloc((size_t)CAP3*4);
  int*      rowptr3= (int*)alloc((size_t)(NN3+1)*4);
  int*      cursor3= (int*)alloc((size_t)NN3*4);
  int*      esrc3  = (int*)alloc((size_t)CAP3*4);
  float*    xp3    = (float*)alloc((size_t)NN3*256*4);
  float*    als3   = (float*)alloc((size_t)NN3*4);
  float*    ald3   = (float*)alloc((size_t)NN3*4);
  float*    out3   = (float*)alloc((size_t)NN3*256*4);
  float*    gateb  = (float*)alloc((size_t)NN3*64*4);
  float*    gatev  = (float*)alloc((size_t)NN3*4);
  float*    hbuf   = (float*)alloc((size_t)NN3*256*4);
  float*    gvec   = (float*)alloc((size_t)BG*256*4);
  float*    z1     = (float*)alloc((size_t)BG*512*4);
  float*    z2     = (float*)alloc((size_t)BG*128*4);
  if(off > ws_size) return;  // workspace too small: fail visibly

  auto cdiv = [](int a, int b){ return (a+b-1)/b; };

  hipMemsetAsync(base, 0, zend, stream);
  hipMemsetAsync(base + fstart, 0xFF, fend - fstart, stream);

  // ---------------- stage 1: GAT(3->32, H=2,F=16) ----------------
  k_xp1<<<cdiv(NB1,256),256,0,stream>>>(pos,W1,as1,ad1,xp1,als1,ald1);
  k_edge_count<<<cdiv(NE,256),256,0,stream>>>(dst,nullptr,NE,NE,cnt1);
  k_scan<<<1,1024,0,stream>>>(cnt1,NB1,rowptr1,cursor1);
  k_scatter<<<cdiv(NE,256),256,0,stream>>>(src,dst,nullptr,NE,NE,cursor1,esrc1);
  k_gat_agg<2,16><<<cdiv(NB1*32,256),256,0,stream>>>(xp1,als1,ald1,rowptr1,esrc1,b1,out1,NB1);
  k_inorm_stats<<<BG*16,256,0,stream>>>(out1,8192,32,16,acc1);
  k_inorm_apply<<<cdiv(NB1*32,256),256,0,stream>>>(out1,acc1,8192,32,NB1*32);
  // ---------------- pool 1 (k=2458) ----------------
  k_score<<<cdiv(NB1,256),256,0,stream>>>(out1,p1,32,NB1,score1,u1);
  k_select<<<BG,1024,0,stream>>>(u1,8192,KP1,thr1,need1);
  k_compact<<<BG,1024,0,stream>>>(u1,score1,thr1,need1,8192,KP1,newid1,oldid1,scale1);
  k_pool_gather<<<cdiv(NN2*32,256),256,0,stream>>>(out1,oldid1,scale1,32,NN2*32,xnew1);
  k_edge_compact<<<cdiv(NE,256),256,0,stream>>>(src,dst,nullptr,NE,NE,newid1,ecnt2,ns2,nd2,CAP2);
  // ---------------- stage 2: GAT(32->128, H=2,F=64) ----------------
  k_edge_count<<<cdiv(CAP2,256),256,0,stream>>>(nd2,ecnt2,0,CAP2,cnt2);
  k_scan<<<1,1024,0,stream>>>(cnt2,NN2,rowptr2,cursor2);
  k_scatter<<<cdiv(CAP2,256),256,0,stream>>>(ns2,nd2,ecnt2,0,CAP2,cursor2,esrc2);
  k_gemm<32,128,4,false><<<cdiv(NN2,8),256,0,stream>>>(xnew1,W2,nullptr,xp2,NN2);
  k_al<<<cdiv(NN2*2,256),256,0,stream>>>(xp2,as2,ad2,NN2,2,64,als2,ald2);
  k_gat_agg<2,64><<<cdiv(NN2*128,256),256,0,stream>>>(xp2,als2,ald2,rowptr2,esrc2,b2,out2,NN2);
  k_inorm_stats<<<BG*16,256,0,stream>>>(out2,KP1,128,16,acc2);
  k_inorm_apply<<<cdiv(NN2*128,256),256,0,stream>>>(out2,acc2,KP1,128,NN2*128);
  // ---------------- pool 2 (k=738) ----------------
  k_score<<<cdiv(NN2,256),256,0,stream>>>(out2,p2,128,NN2,score2,u2);
  k_select<<<BG,1024,0,stream>>>(u2,KP1,KP2,thr2,need2);
  k_compact<<<BG,1024,0,stream>>>(u2,score2,thr2,need2,KP1,KP2,newid2,oldid2,scale2);
  k_pool_gather<<<cdiv(NN3*128,256),256,0,stream>>>(out2,oldid2,scale2,128,NN3*128,xnew2);
  k_edge_compact<<<cdiv(CAP2,256),256,0,stream>>>(ns2,nd2,ecnt2,0,CAP2,newid2,ecnt3,ns3,nd3,CAP3);
  // ---------------- stage 3: GAT(128->256, H=1,F=256) ----------------
  k_edge_count<<<cdiv(CAP3,256),256,0,stream>>>(nd3,ecnt3,0,CAP3,cnt3);
  k_scan<<<1,1024,0,stream>>>(cnt3,NN3,rowptr3,cursor3);
  k_scatter<<<cdiv(CAP3,256),256,0,stream>>>(ns3,nd3,ecnt3,0,CAP3,cursor3,esrc3);
  k_gemm<128,256,4,false><<<cdiv(NN3,4),256,0,stream>>>(xnew2,W3,nullptr,xp3,NN3);
  k_al<<<cdiv(NN3,256),256,0,stream>>>(xp3,as3,ad3,NN3,1,256,als3,ald3);
  k_gat_agg<1,256><<<cdiv(NN3*256,256),256,0,stream>>>(xp3,als3,ald3,rowptr3,esrc3,b3,out3,NN3);
  k_inorm_stats<<<BG*8,256,0,stream>>>(out3,KP2,256,8,acc3);
  k_inorm_apply<<<cdiv(NN3*256,256),256,0,stream>>>(out3,acc3,KP2,256,NN3*256);
  // ---------------- global attention + MLP head ----------------
  k_gemm<256,64,2,true><<<cdiv(NN3,8),256,0,stream>>>(out3,gw1,gb1,gateb,NN3);
  k_mlp<<<cdiv(NN3,256),256,0,stream>>>(gateb,gw2,gb2,gatev,NN3,64,1,0);
  k_gemm<256,256,4,true><<<cdiv(NN3,4),256,0,stream>>>(out3,aw,ab,hbuf,NN3);
  k_attn<<<BG,256,0,stream>>>(gatev,hbuf,gvec);
  k_mlp<<<cdiv(8*512,256),256,0,stream>>>(gvec,w1,bb1,z1,8,256,512,1);
  k_mlp<<<cdiv(8*128,256),256,0,stream>>>(z1,w2,bb2,z2,8,512,128,1);
  k_head<<<BG,64,0,stream>>>(z2,w3,bb3,out);
}

// Round 2
// 1067.028 us; speedup vs baseline: 1.1401x; 1.1401x over previous
//
#include <hip/hip_runtime.h>
#include <cstdint>
#include <cstddef>

#define DI __device__ __forceinline__

namespace pk {

constexpr int NB1 = 65536;      // stage-1 nodes (B*N)
constexpr int NE  = 1048576;    // edges (B*N*DEG)
constexpr int BG  = 8;          // graphs
constexpr int KP1 = 2458;       // top-k 1
constexpr int KP2 = 738;        // top-k 2
constexpr int NN2 = BG*KP1;     // 19664
constexpr int NN3 = BG*KP2;     // 5904
constexpr int CAP2 = 524288;    // edge-buffer cap after pool1 (expected ~94K)
constexpr int CAP3 = 131072;    // edge-buffer cap after pool2 (expected ~8.5K)

DI float lrelu(float x){ return x > 0.f ? x : 0.2f*x; }
DI float eluf(float x){ return x > 0.f ? x : expf(x) - 1.f; }

// ---- stage-1 projection: xp = pos @ W1 (K=3), plus attention logits per head
__global__ __launch_bounds__(256) void k_xp1(
    const float* __restrict__ pos, const float* __restrict__ W,
    const float* __restrict__ as_, const float* __restrict__ ad_,
    float* __restrict__ xp, float* __restrict__ als, float* __restrict__ ald){
  int i = blockIdx.x*256 + threadIdx.x;
  if(i >= NB1) return;
  float p0=pos[3*i], p1=pos[3*i+1], p2=pos[3*i+2];
  float row[32];
#pragma unroll
  for(int c=0;c<32;c++) row[c] = p0*W[c] + p1*W[32+c] + p2*W[64+c];
  float s0=0.f,d0=0.f,s1=0.f,d1=0.f;
#pragma unroll
  for(int f=0;f<16;f++){
    s0 += row[f]*as_[f];        d0 += row[f]*ad_[f];
    s1 += row[16+f]*as_[16+f];  d1 += row[16+f]*ad_[16+f];
  }
  float4* o = reinterpret_cast<float4*>(xp + (size_t)i*32);
#pragma unroll
  for(int q=0;q<8;q++) o[q] = make_float4(row[4*q],row[4*q+1],row[4*q+2],row[4*q+3]);
  als[2*i]=s0; als[2*i+1]=s1; ald[2*i]=d0; ald[2*i+1]=d1;
}

DI int edge_m(const int* mptr, int fixedm, int mcap){
  int m = mptr ? *mptr : fixedm;
  return m < mcap ? m : mcap;
}

__global__ __launch_bounds__(256) void k_edge_count(
    const int* __restrict__ de, const int* __restrict__ mptr,
    int fixedm, int mcap, int* __restrict__ cnt){
  int i = blockIdx.x*256 + threadIdx.x;
  if(i < edge_m(mptr,fixedm,mcap)) atomicAdd(&cnt[de[i]], 1);
}

__global__ __launch_bounds__(256) void k_scatter(
    const int* __restrict__ se, const int* __restrict__ de,
    const int* __restrict__ mptr, int fixedm, int mcap,
    int* __restrict__ cursor, int* __restrict__ eo){
  int i = blockIdx.x*256 + threadIdx.x;
  if(i < edge_m(mptr,fixedm,mcap)){
    int p = atomicAdd(&cursor[de[i]], 1);
    eo[p] = se[i];
  }
}

// block-aggregated stream compaction: one global atomic per block (survivor
// order is irrelevant downstream — CSR row-internal order doesn't affect
// max/sum). Fixes the 190us single-counter atomic serialization seen in R1.
__global__ __launch_bounds__(256) void k_edge_compact(
    const int* __restrict__ se, const int* __restrict__ de,
    const int* __restrict__ mptr, int fixedm, int mcap,
    const int* __restrict__ newid, int* __restrict__ ocnt,
    int* __restrict__ ons, int* __restrict__ ond, int ocap){
  __shared__ int wcnt[4];
  __shared__ int gbase;
  int tid = threadIdx.x;
  int i = blockIdx.x*256 + tid;
  int m = edge_m(mptr,fixedm,mcap);
  bool act = false; int a = 0, b = 0;
  if(i < m){
    a = newid[se[i]]; b = newid[de[i]];
    act = (a >= 0 && b >= 0);
  }
  unsigned long long mask = __ballot(act);
  int lane = tid & 63, w = tid >> 6;
  int rank = __popcll(mask & ((1ull << lane) - 1ull));
  if(lane == 0) wcnt[w] = __popcll(mask);
  __syncthreads();
  if(tid == 0){
    int t = wcnt[0] + wcnt[1] + wcnt[2] + wcnt[3];
    gbase = t ? atomicAdd(ocnt, t) : 0;
  }
  __syncthreads();
  if(act){
    int off = 0;
    for(int k = 0; k < w; k++) off += wcnt[k];
    int s = gbase + off + rank;
    if(s < ocap){ ons[s] = a; ond[s] = b; }
  }
}

// single-block hierarchical exclusive scan (wave shfl + LDS wave sums)
__global__ __launch_bounds__(1024) void k_scan(
    const int* __restrict__ cnt, int n, int* __restrict__ rowptr, int* __restrict__ cursor){
  __shared__ int wsum[16];
  __shared__ int carry;
  int tid = threadIdx.x, lane = tid & 63, w = tid >> 6;
  if(tid==0) carry = 0;
  __syncthreads();
  const int PER = 16, CH = 1024*PER;
  for(int bb=0; bb<n; bb+=CH){
    int vals[PER]; int s=0;
    int i0 = bb + tid*PER;
#pragma unroll
    for(int j=0;j<PER;j++){ int i=i0+j; int v=(i<n)?cnt[i]:0; vals[j]=s; s+=v; }
    int inc = s;
    for(int o=1;o<64;o<<=1){ int t=__shfl_up(inc,o,64); if(lane>=o) inc+=t; }
    if(lane==63) wsum[w]=inc;
    __syncthreads();
    int wb=0;
    for(int k=0;k<w;k++) wb+=wsum[k];
    int c0 = carry;
    int tb = c0 + wb + inc - s;
#pragma unroll
    for(int j=0;j<PER;j++){ int i=i0+j; if(i<n){ int e=tb+vals[j]; rowptr[i]=e; cursor[i]=e; } }
    __syncthreads();
    if(tid==1023) carry = c0 + wb + inc;
    __syncthreads();
  }
  if(tid==0) rowptr[n]=carry;
}

// GAT softmax-aggregate: C=H*F lanes per dst node, two passes over incoming
// edges (max, then exp/acc), self-loop folded in. al loads are wave-broadcast;
// xp gathers are C-wide coalesced.
template<int H,int F>
__global__ __launch_bounds__(256) void k_gat_agg(
    const float* __restrict__ xp, const float* __restrict__ als,
    const float* __restrict__ ald, const int* __restrict__ rowptr,
    const int* __restrict__ esrc, const float* __restrict__ bias,
    float* __restrict__ out, int n){
  constexpr int C = H*F;
  int t = blockIdx.x*256 + threadIdx.x;
  int node = t / C, j = t % C, hh = j / F;
  if(node >= n) return;
  float aldn = ald[node*H+hh];
  float es = lrelu(als[node*H+hh] + aldn);
  int r0 = rowptr[node], r1 = rowptr[node+1];
  float mx = es;
  for(int k=r0;k<r1;k++){ int s=esrc[k]; mx = fmaxf(mx, lrelu(als[s*H+hh]+aldn)); }
  float den = expf(es-mx);
  float acc = den * xp[(size_t)node*C+j];
  for(int k=r0;k<r1;k++){
    int s=esrc[k];
    float ex = expf(lrelu(als[s*H+hh]+aldn)-mx);
    den += ex;
    acc += ex * xp[(size_t)s*C+j];
  }
  out[(size_t)node*C+j] = acc/den + bias[j];
}

__global__ __launch_bounds__(256) void k_al(
    const float* __restrict__ xp, const float* __restrict__ a_s,
    const float* __restrict__ a_d, int n, int H, int F,
    float* __restrict__ als, float* __restrict__ ald){
  int i = blockIdx.x*256+threadIdx.x;
  if(i >= n*H) return;
  int node = i/H, hh = i%H;
  const float* row = xp + (size_t)node*H*F + hh*F;
  float s=0.f, d=0.f;
  for(int f=0;f<F;f++){ s += row[f]*a_s[hh*F+f]; d += row[f]*a_d[hh*F+f]; }
  als[i]=s; ald[i]=d;
}

__global__ __launch_bounds__(256) void k_inorm_stats(
    const float* __restrict__ x, int R, int C, int RS, float* __restrict__ accum){
  int g = blockIdx.x / RS, blk = blockIdx.x % RS;
  int NS = 256 / C;
  int c = threadIdx.x % C, rs = threadIdx.x / C;
  int chunk = (R + RS - 1)/RS;
  int rlo = blk*chunk, rhi = rlo+chunk; if(rhi>R) rhi=R;
  float s=0.f, sq=0.f;
  for(int r=rlo+rs; r<rhi; r+=NS){ float v = x[((size_t)g*R+r)*C + c]; s+=v; sq+=v*v; }
  atomicAdd(&accum[(g*C+c)*2], s);
  atomicAdd(&accum[(g*C+c)*2+1], sq);
}

__global__ __launch_bounds__(256) void k_inorm_apply(
    float* __restrict__ x, const float* __restrict__ accum, int R, int C, int total){
  int i = blockIdx.x*256+threadIdx.x;
  if(i>=total) return;
  int c = i % C; int g = i / (R*C);
  float s = accum[(g*C+c)*2], sq = accum[(g*C+c)*2+1];
  float mu = s / (float)R;
  float var = sq / (float)R - mu*mu; var = fmaxf(var, 0.f);
  float v = (x[i]-mu)*rsqrtf(var+1e-5f);
  x[i] = eluf(v);
}

__global__ __launch_bounds__(256) void k_score(
    const float* __restrict__ x, const float* __restrict__ p,
    int C, int n, float* __restrict__ score, unsigned* __restrict__ u){
  int i = blockIdx.x*256+threadIdx.x;
  if(i>=n) return;
  float a=0.f, nn=0.f;
  for(int c=0;c<C;c++){ float pv=p[c]; a += x[(size_t)i*C+c]*pv; nn += pv*pv; }
  float sv = tanhf(a/sqrtf(nn));
  score[i]=sv;
  unsigned bts = __float_as_uint(sv);
  u[i] = (bts & 0x80000000u) ? ~bts : (bts | 0x80000000u);
}

// per-graph 3-level radix select on orderable uints: exact k-th value + #ties needed
__global__ __launch_bounds__(1024) void k_select(
    const unsigned* __restrict__ u, int R, int Ksel,
    unsigned* __restrict__ thr_out, int* __restrict__ need_out){
  __shared__ int hist[2048];
  __shared__ int seg[32];
  __shared__ int sh_b, sh_k;
  int g = blockIdx.x, tid = threadIdx.x;
  const unsigned* ug = u + (size_t)g*R;
  unsigned prefix = 0;
  int K = Ksel;
  for(int lev=0; lev<3; lev++){
    int shf = (lev==0)?21:((lev==1)?10:0);
    int nb  = (lev==2)?1024:2048;
    for(int i=tid;i<2048;i+=1024) hist[i]=0;
    __syncthreads();
    for(int i=tid;i<R;i+=1024){
      unsigned v = ug[i];
      bool ok = (lev==0) || (lev==1 && (v>>21)==prefix) || (lev==2 && (v>>10)==prefix);
      if(ok) atomicAdd(&hist[(v>>shf)&(nb-1)], 1);
    }
    __syncthreads();
    int W = nb/32;
    if(tid<32){ int s=0; int lo=nb-W*(tid+1); for(int b=lo;b<lo+W;b++) s+=hist[b]; seg[tid]=s; }
    __syncthreads();
    if(tid==0){
      int kk=K, sgi=0;
      while(seg[sgi]<kk){ kk-=seg[sgi]; sgi++; }
      int b = nb-1-W*sgi;
      while(hist[b]<kk){ kk-=hist[b]; b--; }
      sh_b=b; sh_k=kk;
    }
    __syncthreads();
    int b = sh_b; K = sh_k;
    if(lev==0) prefix = (unsigned)b;
    else if(lev==1) prefix = (prefix<<11) | (unsigned)b;
    else prefix = (prefix<<10) | (unsigned)b;
    __syncthreads();
  }
  if(tid==0){ thr_out[g]=prefix; need_out[g]=K; }
}

// deterministic compaction: take u>thr plus lowest-index u==thr (matches lax.top_k ties)
__global__ __launch_bounds__(1024) void k_compact(
    const unsigned* __restrict__ u, const float* __restrict__ score,
    const unsigned* __restrict__ thr_arr, const int* __restrict__ need_arr,
    int R, int Kout, int* __restrict__ newid, int* __restrict__ oldid,
    float* __restrict__ scale){
  __shared__ int wsA[16], wsB[16];
  __shared__ int carr0, carr1;
  int g = blockIdx.x, tid = threadIdx.x, lane = tid&63, w = tid>>6;
  unsigned thr = thr_arr[g]; int need = need_arr[g];
  if(tid==0){ carr0=0; carr1=0; }
  __syncthreads();
  for(int bb=0; bb<R; bb+=1024){
    int i = bb + tid; bool in = i < R;
    unsigned uv = in ? u[(size_t)g*R+i] : 0u;
    int eq = (in && uv==thr) ? 1:0;
    int gt = (in && uv>thr) ? 1:0;
    int inc = eq;
    for(int o=1;o<64;o<<=1){ int t=__shfl_up(inc,o,64); if(lane>=o) inc+=t; }
    if(lane==63) wsA[w]=inc;
    __syncthreads();
    int wb=0; for(int k=0;k<w;k++) wb+=wsA[k];
    int eq_excl = carr0 + wb + inc - eq;
    int take = (gt || (eq && eq_excl<need)) ? 1 : 0;
    int inc2 = take;
    for(int o=1;o<64;o<<=1){ int t=__shfl_up(inc2,o,64); if(lane>=o) inc2+=t; }
    if(lane==63) wsB[w]=inc2;
    __syncthreads();
    int wb2=0; for(int k=0;k<w;k++) wb2+=wsB[k];
    int pos = carr1 + wb2 + inc2 - take;
    if(take){
      int nr = g*Kout + pos;
      newid[(size_t)g*R+i] = nr;
      oldid[nr] = g*R+i;
      scale[nr] = score[(size_t)g*R+i];
    }
    __syncthreads();
    if(tid==1023){ carr0 += wb + inc; carr1 += wb2 + inc2; }
    __syncthreads();
  }
}

__global__ __launch_bounds__(256) void k_pool_gather(
    const float* __restrict__ x, const int* __restrict__ oldid,
    const float* __restrict__ scale, int C, int total, float* __restrict__ xnew){
  int i = blockIdx.x*256+threadIdx.x;
  if(i>=total) return;
  int r = i / C, c = i % C;
  xnew[i] = x[(size_t)oldid[r]*C + c] * scale[r];
}

// dense row-GEMM: block = 256 threads = (256/CO subgroups) x CO channels,
// each subgroup owns NPG rows staged in LDS (broadcast reads)
template<int K,int CO,int NPG,bool DOELU>
__global__ __launch_bounds__(256) void k_gemm(
    const float* __restrict__ X, const float* __restrict__ W,
    const float* __restrict__ bias, float* __restrict__ Y, int n){
  constexpr int SUB = 256/CO;
  constexpr int NB = SUB*NPG;
  __shared__ float xs[NB][K];
  int tid = threadIdx.x;
  int c = tid % CO, sg = tid / CO;
  int n0 = blockIdx.x * NB;
  for(int idx=tid; idx<NB*K; idx+=256){
    int r = idx / K, k = idx % K;
    int row = n0 + r;
    xs[r][k] = (row < n) ? X[(size_t)row*K + k] : 0.f;
  }
  __syncthreads();
  float acc[NPG];
#pragma unroll
  for(int q=0;q<NPG;q++) acc[q]=0.f;
  for(int k=0;k<K;k++){
    float wv = W[(size_t)k*CO + c];
#pragma unroll
    for(int q=0;q<NPG;q++) acc[q] += xs[sg*NPG+q][k]*wv;
  }
  float bv = bias ? bias[c] : 0.f;
#pragma unroll
  for(int q=0;q<NPG;q++){
    int row = n0 + sg*NPG + q;
    if(row < n){
      float v = acc[q] + bv;
      if(DOELU) v = eluf(v);
      Y[(size_t)row*CO + c] = v;
    }
  }
}

__global__ __launch_bounds__(256) void k_mlp(
    const float* __restrict__ X, const float* __restrict__ W,
    const float* __restrict__ b, float* __restrict__ Y,
    int n, int K, int CO, int act){
  int i = blockIdx.x*256+threadIdx.x;
  if(i>=n*CO) return;
  int r=i/CO, c=i%CO;
  float a=0.f;
  for(int k=0;k<K;k++) a += X[(size_t)r*K+k]*W[(size_t)k*CO+c];
  a += b[c];
  if(act) a = eluf(a);
  Y[i]=a;
}

__global__ __launch_bounds__(256) void k_attn(
    const float* __restrict__ gate, const float* __restrict__ h,
    float* __restrict__ gout){
  __shared__ float pbuf[KP2];
  __shared__ float red[256];
  int g = blockIdx.x, tid = threadIdx.x;
  float mx = -1e30f;
  for(int r=tid;r<KP2;r+=256) mx = fmaxf(mx, gate[g*KP2+r]);
  red[tid]=mx; __syncthreads();
  for(int s=128;s>0;s>>=1){ if(tid<s) red[tid]=fmaxf(red[tid],red[tid+s]); __syncthreads(); }
  mx = red[0]; __syncthreads();
  float sm=0.f;
  for(int r=tid;r<KP2;r+=256){ float e=expf(gate[g*KP2+r]-mx); pbuf[r]=e; sm+=e; }
  red[tid]=sm; __syncthreads();
  for(int s=128;s>0;s>>=1){ if(tid<s) red[tid]+=red[tid+s]; __syncthreads(); }
  float inv = 1.f/red[0];
  float acc=0.f;
  for(int r=0;r<KP2;r++) acc += pbuf[r]*h[((size_t)g*KP2+r)*256 + tid];
  gout[g*256+tid]=acc*inv;
}

__global__ __launch_bounds__(64) void k_head(
    const float* __restrict__ z2, const float* __restrict__ w3,
    const float* __restrict__ b3, float* __restrict__ out){
  __shared__ float zc[10]; __shared__ float mred, sred;
  int g=blockIdx.x, tid=threadIdx.x;
  if(tid<10){
    float a=0.f;
    for(int k=0;k<128;k++) a += z2[g*128+k]*w3[k*10+tid];
    zc[tid]=a+b3[tid];
  }
  __syncthreads();
  if(tid==0){
    float m=zc[0];
    for(int k=1;k<10;k++) m=fmaxf(m,zc[k]);
    float s=0.f;
    for(int k=0;k<10;k++) s+=expf(zc[k]-m);
    mred=m; sred=logf(s);
  }
  __syncthreads();
  if(tid<10) out[g*10+tid]=zc[tid]-mred-sred;
}

} // namespace pk

extern "C" void kernel_launch(void* const* d_in, const int* in_sizes, int n_in,
                              void* d_out, int out_size, void* d_ws, size_t ws_size,
                              hipStream_t stream){
  using namespace pk;
  (void)in_sizes; (void)n_in; (void)out_size;
  const float* pos = (const float*)d_in[0];
  const int*   src = (const int*)d_in[1];
  const int*   dst = (const int*)d_in[2];
  const float* W1  = (const float*)d_in[3];
  const float* as1 = (const float*)d_in[4];
  const float* ad1 = (const float*)d_in[5];
  const float* b1  = (const float*)d_in[6];
  const float* p1  = (const float*)d_in[7];
  const float* W2  = (const float*)d_in[8];
  const float* as2 = (const float*)d_in[9];
  const float* ad2 = (const float*)d_in[10];
  const float* b2  = (const float*)d_in[11];
  const float* p2  = (const float*)d_in[12];
  const float* W3  = (const float*)d_in[13];
  const float* as3 = (const float*)d_in[14];
  const float* ad3 = (const float*)d_in[15];
  const float* b3  = (const float*)d_in[16];
  const float* gw1 = (const float*)d_in[17];
  const float* gb1 = (const float*)d_in[18];
  const float* gw2 = (const float*)d_in[19];
  const float* gb2 = (const float*)d_in[20];
  const float* aw  = (const float*)d_in[21];
  const float* ab  = (const float*)d_in[22];
  const float* w1  = (const float*)d_in[23];
  const float* bb1 = (const float*)d_in[24];
  const float* w2  = (const float*)d_in[25];
  const float* bb2 = (const float*)d_in[26];
  const float* w3  = (const float*)d_in[27];
  const float* bb3 = (const float*)d_in[28];
  float* out = (float*)d_out;

  char* base = (char*)d_ws; size_t off = 0;
  auto alloc = [&](size_t nbytes)->char*{
    char* p = base + off; off = (off + nbytes + 255) & ~(size_t)255; return p;
  };
  // --- zero-init region (one memset) ---
  int*   cnt1  = (int*)alloc((size_t)NB1*4);
  int*   cnt2  = (int*)alloc((size_t)NN2*4);
  int*   cnt3  = (int*)alloc((size_t)NN3*4);
  int*   ecnt2 = (int*)alloc(4);
  int*   ecnt3 = (int*)alloc(4);
  float* acc1  = (float*)alloc((size_t)BG*32*2*4);
  float* acc2  = (float*)alloc((size_t)BG*128*2*4);
  float* acc3  = (float*)alloc((size_t)BG*256*2*4);
  size_t zend = off;
  // --- 0xFF-init region (newid = -1, one memset) ---
  int*   newid1 = (int*)alloc((size_t)NB1*4);
  int*   newid2 = (int*)alloc((size_t)NN2*4);
  size_t fstart = (size_t)((char*)newid1 - base);
  size_t fend = off;
  // --- plain scratch ---
  float*    xp1    = (float*)alloc((size_t)NB1*32*4);
  float*    als1   = (float*)alloc((size_t)NB1*2*4);
  float*    ald1   = (float*)alloc((size_t)NB1*2*4);
  int*      rowptr1= (int*)alloc((size_t)(NB1+1)*4);
  int*      cursor1= (int*)alloc((size_t)NB1*4);
  int*      esrc1  = (int*)alloc((size_t)NE*4);
  float*    out1   = (float*)alloc((size_t)NB1*32*4);
  float*    score1 = (float*)alloc((size_t)NB1*4);
  unsigned* u1     = (unsigned*)alloc((size_t)NB1*4);
  unsigned* thr1   = (unsigned*)alloc((size_t)BG*4);
  int*      need1  = (int*)alloc((size_t)BG*4);
  int*      oldid1 = (int*)alloc((size_t)NN2*4);
  float*    scale1 = (float*)alloc((size_t)NN2*4);
  float*    xnew1  = (float*)alloc((size_t)NN2*32*4);
  int*      ns2    = (int*)alloc((size_t)CAP2*4);
  int*      nd2    = (int*)alloc((size_t)CAP2*4);
  int*      rowptr2= (int*)alloc((size_t)(NN2+1)*4);
  int*      cursor2= (int*)alloc((size_t)NN2*4);
  int*      esrc2  = (int*)alloc((size_t)CAP2*4);
  float*    xp2    = (float*)alloc((size_t)NN2*128*4);
  float*    als2   = (float*)alloc((size_t)NN2*2*4);
  float*    ald2   = (float*)alloc((size_t)NN2*2*4);
  float*    out2   = (float*)alloc((size_t)NN2*128*4);
  float*    score2 = (float*)alloc((size_t)NN2*4);
  unsigned* u2     = (unsigned*)alloc((size_t)NN2*4);
  unsigned* thr2   = (unsigned*)alloc((size_t)BG*4);
  int*      need2  = (int*)alloc((size_t)BG*4);
  int*      oldid2 = (int*)alloc((size_t)NN3*4);
  float*    scale2 = (float*)alloc((size_t)NN3*4);
  float*    xnew2  = (float*)alloc((size_t)NN3*128*4);
  int*      ns3    = (int*)alloc((size_t)CAP3*4);
  int*      nd3    = (int*)alloc((size_t)CAP3*4);
  int*      rowptr3= (int*)alloc((size_t)(NN3+1)*4);
  int*      cursor3= (int*)alloc((size_t)NN3*4);
  int*      esrc3  = (int*)alloc((size_t)CAP3*4);
  float*    xp3    = (float*)alloc((size_t)NN3*256*4);
  float*    als3   = (float*)alloc((size_t)NN3*4);
  float*    ald3   = (float*)alloc((size_t)NN3*4);
  float*    out3   = (float*)alloc((size_t)NN3*256*4);
  float*    gateb  = (float*)alloc((size_t)NN3*64*4);
  float*    gatev  = (float*)alloc((size_t)NN3*4);
  float*    hbuf   = (float*)alloc((size_t)NN3*256*4);
  float*    gvec   = (float*)alloc((size_t)BG*256*4);
  float*    z1     = (float*)alloc((size_t)BG*512*4);
  float*    z2     = (float*)alloc((size_t)BG*128*4);
  if(off > ws_size) return;  // workspace too small: fail visibly

  auto cdiv = [](int a, int b){ return (a+b-1)/b; };

  hipMemsetAsync(base, 0, zend, stream);
  hipMemsetAsync(base + fstart, 0xFF, fend - fstart, stream);

  // ---------------- stage 1: GAT(3->32, H=2,F=16) ----------------
  k_xp1<<<cdiv(NB1,256),256,0,stream>>>(pos,W1,as1,ad1,xp1,als1,ald1);
  k_edge_count<<<cdiv(NE,256),256,0,stream>>>(dst,nullptr,NE,NE,cnt1);
  k_scan<<<1,1024,0,stream>>>(cnt1,NB1,rowptr1,cursor1);
  k_scatter<<<cdiv(NE,256),256,0,stream>>>(src,dst,nullptr,NE,NE,cursor1,esrc1);
  k_gat_agg<2,16><<<cdiv(NB1*32,256),256,0,stream>>>(xp1,als1,ald1,rowptr1,esrc1,b1,out1,NB1);
  k_inorm_stats<<<BG*16,256,0,stream>>>(out1,8192,32,16,acc1);
  k_inorm_apply<<<cdiv(NB1*32,256),256,0,stream>>>(out1,acc1,8192,32,NB1*32);
  // ---------------- pool 1 (k=2458) ----------------
  k_score<<<cdiv(NB1,256),256,0,stream>>>(out1,p1,32,NB1,score1,u1);
  k_select<<<BG,1024,0,stream>>>(u1,8192,KP1,thr1,need1);
  k_compact<<<BG,1024,0,stream>>>(u1,score1,thr1,need1,8192,KP1,newid1,oldid1,scale1);
  k_pool_gather<<<cdiv(NN2*32,256),256,0,stream>>>(out1,oldid1,scale1,32,NN2*32,xnew1);
  k_edge_compact<<<cdiv(NE,256),256,0,stream>>>(src,dst,nullptr,NE,NE,newid1,ecnt2,ns2,nd2,CAP2);
  // ---------------- stage 2: GAT(32->128, H=2,F=64) ----------------
  k_edge_count<<<cdiv(CAP2,256),256,0,stream>>>(nd2,ecnt2,0,CAP2,cnt2);
  k_scan<<<1,1024,0,stream>>>(cnt2,NN2,rowptr2,cursor2);
  k_scatter<<<cdiv(CAP2,256),256,0,stream>>>(ns2,nd2,ecnt2,0,CAP2,cursor2,esrc2);
  k_gemm<32,128,4,false><<<cdiv(NN2,8),256,0,stream>>>(xnew1,W2,nullptr,xp2,NN2);
  k_al<<<cdiv(NN2*2,256),256,0,stream>>>(xp2,as2,ad2,NN2,2,64,als2,ald2);
  k_gat_agg<2,64><<<cdiv(NN2*128,256),256,0,stream>>>(xp2,als2,ald2,rowptr2,esrc2,b2,out2,NN2);
  k_inorm_stats<<<BG*16,256,0,stream>>>(out2,KP1,128,16,acc2);
  k_inorm_apply<<<cdiv(NN2*128,256),256,0,stream>>>(out2,acc2,KP1,128,NN2*128);
  // ---------------- pool 2 (k=738) ----------------
  k_score<<<cdiv(NN2,256),256,0,stream>>>(out2,p2,128,NN2,score2,u2);
  k_select<<<BG,1024,0,stream>>>(u2,KP1,KP2,thr2,need2);
  k_compact<<<BG,1024,0,stream>>>(u2,score2,thr2,need2,KP1,KP2,newid2,oldid2,scale2);
  k_pool_gather<<<cdiv(NN3*128,256),256,0,stream>>>(out2,oldid2,scale2,128,NN3*128,xnew2);
  k_edge_compact<<<cdiv(CAP2,256),256,0,stream>>>(ns2,nd2,ecnt2,0,CAP2,newid2,ecnt3,ns3,nd3,CAP3);
  // ---------------- stage 3: GAT(128->256, H=1,F=256) ----------------
  k_edge_count<<<cdiv(CAP3,256),256,0,stream>>>(nd3,ecnt3,0,CAP3,cnt3);
  k_scan<<<1,1024,0,stream>>>(cnt3,NN3,rowptr3,cursor3);
  k_scatter<<<cdiv(CAP3,256),256,0,stream>>>(ns3,nd3,ecnt3,0,CAP3,cursor3,esrc3);
  k_gemm<128,256,4,false><<<cdiv(NN3,4),256,0,stream>>>(xnew2,W3,nullptr,xp3,NN3);
  k_al<<<cdiv(NN3,256),256,0,stream>>>(xp3,as3,ad3,NN3,1,256,als3,ald3);
  k_gat_agg<1,256><<<cdiv(NN3*256,256),256,0,stream>>>(xp3,als3,ald3,rowptr3,esrc3,b3,out3,NN3);
  k_inorm_stats<<<BG*8,256,0,stream>>>(out3,KP2,256,8,acc3);
  k_inorm_apply<<<cdiv(NN3*256,256),256,0,stream>>>(out3,acc3,KP2,256,NN3*256);
  // ---------------- global attention + MLP head ----------------
  k_gemm<256,64,2,true><<<cdiv(NN3,8),256,0,stream>>>(out3,gw1,gb1,gateb,NN3);
  k_mlp<<<cdiv(NN3,256),256,0,stream>>>(gateb,gw2,gb2,gatev,NN3,64,1,0);
  k_gemm<256,256,4,true><<<cdiv(NN3,4),256,0,stream>>>(out3,aw,ab,hbuf,NN3);
  k_attn<<<BG,256,0,stream>>>(gatev,hbuf,gvec);
  k_mlp<<<cdiv(8*512,256),256,0,stream>>>(gvec,w1,bb1,z1,8,256,512,1);
  k_mlp<<<cdiv(8*128,256),256,0,stream>>>(z1,w2,bb2,z2,8,512,128,1);
  k_head<<<BG,64,0,stream>>>(z2,w3,bb3,out);
}

// Round 3
// 874.614 us; speedup vs baseline: 1.3909x; 1.2200x over previous
//
#include <hip/hip_runtime.h>
#include <cstdint>
#include <cstddef>

#define DI __device__ __forceinline__

namespace pk {

constexpr int NB1 = 65536;      // stage-1 nodes (B*N)
constexpr int NE  = 1048576;    // edges (B*N*DEG)
constexpr int BG  = 8;          // graphs
constexpr int KP1 = 2458;       // top-k 1
constexpr int KP2 = 738;        // top-k 2
constexpr int NN2 = BG*KP1;     // 19664
constexpr int NN3 = BG*KP2;     // 5904
constexpr int CAP2 = 524288;    // edge-buffer cap after pool1 (expected ~94K)
constexpr int CAP3 = 131072;    // edge-buffer cap after pool2 (expected ~8.5K)

DI float lrelu(float x){ return x > 0.f ? x : 0.2f*x; }
DI float eluf(float x){ return x > 0.f ? x : expf(x) - 1.f; }

// ---- stage-1 projection: xp = pos @ W1 (K=3), plus attention logits per head
__global__ __launch_bounds__(256) void k_xp1(
    const float* __restrict__ pos, const float* __restrict__ W,
    const float* __restrict__ as_, const float* __restrict__ ad_,
    float* __restrict__ xp, float* __restrict__ als, float* __restrict__ ald){
  int i = blockIdx.x*256 + threadIdx.x;
  if(i >= NB1) return;
  float p0=pos[3*i], p1=pos[3*i+1], p2=pos[3*i+2];
  float row[32];
#pragma unroll
  for(int c=0;c<32;c++) row[c] = p0*W[c] + p1*W[32+c] + p2*W[64+c];
  float s0=0.f,d0=0.f,s1=0.f,d1=0.f;
#pragma unroll
  for(int f=0;f<16;f++){
    s0 += row[f]*as_[f];        d0 += row[f]*ad_[f];
    s1 += row[16+f]*as_[16+f];  d1 += row[16+f]*ad_[16+f];
  }
  float4* o = reinterpret_cast<float4*>(xp + (size_t)i*32);
#pragma unroll
  for(int q=0;q<8;q++) o[q] = make_float4(row[4*q],row[4*q+1],row[4*q+2],row[4*q+3]);
  als[2*i]=s0; als[2*i+1]=s1; ald[2*i]=d0; ald[2*i+1]=d1;
}

DI int edge_m(const int* mptr, int fixedm, int mcap){
  int m = mptr ? *mptr : fixedm;
  return m < mcap ? m : mcap;
}

__global__ __launch_bounds__(256) void k_edge_count(
    const int* __restrict__ de, const int* __restrict__ mptr,
    int fixedm, int mcap, int* __restrict__ cnt){
  int i = blockIdx.x*256 + threadIdx.x;
  if(i < edge_m(mptr,fixedm,mcap)) atomicAdd(&cnt[de[i]], 1);
}

__global__ __launch_bounds__(256) void k_scatter(
    const int* __restrict__ se, const int* __restrict__ de,
    const int* __restrict__ mptr, int fixedm, int mcap,
    int* __restrict__ cursor, int* __restrict__ eo){
  int i = blockIdx.x*256 + threadIdx.x;
  if(i < edge_m(mptr,fixedm,mcap)){
    int p = atomicAdd(&cursor[de[i]], 1);
    eo[p] = se[i];
  }
}

// block-aggregated stream compaction: one global atomic per block (survivor
// order is irrelevant downstream — CSR row-internal order doesn't affect
// max/sum).
__global__ __launch_bounds__(256) void k_edge_compact(
    const int* __restrict__ se, const int* __restrict__ de,
    const int* __restrict__ mptr, int fixedm, int mcap,
    const int* __restrict__ newid, int* __restrict__ ocnt,
    int* __restrict__ ons, int* __restrict__ ond, int ocap){
  __shared__ int wcnt[4];
  __shared__ int gbase;
  int tid = threadIdx.x;
  int i = blockIdx.x*256 + tid;
  int m = edge_m(mptr,fixedm,mcap);
  bool act = false; int a = 0, b = 0;
  if(i < m){
    a = newid[se[i]]; b = newid[de[i]];
    act = (a >= 0 && b >= 0);
  }
  unsigned long long mask = __ballot(act);
  int lane = tid & 63, w = tid >> 6;
  int rank = __popcll(mask & ((1ull << lane) - 1ull));
  if(lane == 0) wcnt[w] = __popcll(mask);
  __syncthreads();
  if(tid == 0){
    int t = wcnt[0] + wcnt[1] + wcnt[2] + wcnt[3];
    gbase = t ? atomicAdd(ocnt, t) : 0;
  }
  __syncthreads();
  if(act){
    int off = 0;
    for(int k = 0; k < w; k++) off += wcnt[k];
    int s = gbase + off + rank;
    if(s < ocap){ ons[s] = a; ond[s] = b; }
  }
}

// single-block hierarchical exclusive scan (wave shfl + LDS wave sums)
__global__ __launch_bounds__(1024) void k_scan(
    const int* __restrict__ cnt, int n, int* __restrict__ rowptr, int* __restrict__ cursor){
  __shared__ int wsum[16];
  __shared__ int carry;
  int tid = threadIdx.x, lane = tid & 63, w = tid >> 6;
  if(tid==0) carry = 0;
  __syncthreads();
  const int PER = 16, CH = 1024*PER;
  for(int bb=0; bb<n; bb+=CH){
    int vals[PER]; int s=0;
    int i0 = bb + tid*PER;
#pragma unroll
    for(int j=0;j<PER;j++){ int i=i0+j; int v=(i<n)?cnt[i]:0; vals[j]=s; s+=v; }
    int inc = s;
    for(int o=1;o<64;o<<=1){ int t=__shfl_up(inc,o,64); if(lane>=o) inc+=t; }
    if(lane==63) wsum[w]=inc;
    __syncthreads();
    int wb=0;
    for(int k=0;k<w;k++) wb+=wsum[k];
    int c0 = carry;
    int tb = c0 + wb + inc - s;
#pragma unroll
    for(int j=0;j<PER;j++){ int i=i0+j; if(i<n){ int e=tb+vals[j]; rowptr[i]=e; cursor[i]=e; } }
    __syncthreads();
    if(tid==1023) carry = c0 + wb + inc;
    __syncthreads();
  }
  if(tid==0) rowptr[n]=carry;
}

// GAT softmax-aggregate: C=H*F lanes per dst node, two passes over incoming
// edges (max, then exp/acc), self-loop folded in.
template<int H,int F>
__global__ __launch_bounds__(256) void k_gat_agg(
    const float* __restrict__ xp, const float* __restrict__ als,
    const float* __restrict__ ald, const int* __restrict__ rowptr,
    const int* __restrict__ esrc, const float* __restrict__ bias,
    float* __restrict__ out, int n){
  constexpr int C = H*F;
  int t = blockIdx.x*256 + threadIdx.x;
  int node = t / C, j = t % C, hh = j / F;
  if(node >= n) return;
  float aldn = ald[node*H+hh];
  float es = lrelu(als[node*H+hh] + aldn);
  int r0 = rowptr[node], r1 = rowptr[node+1];
  float mx = es;
  for(int k=r0;k<r1;k++){ int s=esrc[k]; mx = fmaxf(mx, lrelu(als[s*H+hh]+aldn)); }
  float den = expf(es-mx);
  float acc = den * xp[(size_t)node*C+j];
  for(int k=r0;k<r1;k++){
    int s=esrc[k];
    float ex = expf(lrelu(als[s*H+hh]+aldn)-mx);
    den += ex;
    acc += ex * xp[(size_t)s*C+j];
  }
  out[(size_t)node*C+j] = acc/den + bias[j];
}

__global__ __launch_bounds__(256) void k_al(
    const float* __restrict__ xp, const float* __restrict__ a_s,
    const float* __restrict__ a_d, int n, int H, int F,
    float* __restrict__ als, float* __restrict__ ald){
  int i = blockIdx.x*256+threadIdx.x;
  if(i >= n*H) return;
  int node = i/H, hh = i%H;
  const float* row = xp + (size_t)node*H*F + hh*F;
  float s=0.f, d=0.f;
  for(int f=0;f<F;f++){ s += row[f]*a_s[hh*F+f]; d += row[f]*a_d[hh*F+f]; }
  als[i]=s; ald[i]=d;
}

__global__ __launch_bounds__(256) void k_inorm_stats(
    const float* __restrict__ x, int R, int C, int RS, float* __restrict__ accum){
  int g = blockIdx.x / RS, blk = blockIdx.x % RS;
  int NS = 256 / C;
  int c = threadIdx.x % C, rs = threadIdx.x / C;
  int chunk = (R + RS - 1)/RS;
  int rlo = blk*chunk, rhi = rlo+chunk; if(rhi>R) rhi=R;
  float s=0.f, sq=0.f;
  for(int r=rlo+rs; r<rhi; r+=NS){ float v = x[((size_t)g*R+r)*C + c]; s+=v; sq+=v*v; }
  atomicAdd(&accum[(g*C+c)*2], s);
  atomicAdd(&accum[(g*C+c)*2+1], sq);
}

__global__ __launch_bounds__(256) void k_inorm_apply(
    float* __restrict__ x, const float* __restrict__ accum, int R, int C, int total){
  int i = blockIdx.x*256+threadIdx.x;
  if(i>=total) return;
  int c = i % C; int g = i / (R*C);
  float s = accum[(g*C+c)*2], sq = accum[(g*C+c)*2+1];
  float mu = s / (float)R;
  float var = sq / (float)R - mu*mu; var = fmaxf(var, 0.f);
  float v = (x[i]-mu)*rsqrtf(var+1e-5f);
  x[i] = eluf(v);
}

__global__ __launch_bounds__(256) void k_score(
    const float* __restrict__ x, const float* __restrict__ p,
    int C, int n, float* __restrict__ score, unsigned* __restrict__ u){
  int i = blockIdx.x*256+threadIdx.x;
  if(i>=n) return;
  float a=0.f, nn=0.f;
  for(int c=0;c<C;c++){ float pv=p[c]; a += x[(size_t)i*C+c]*pv; nn += pv*pv; }
  float sv = tanhf(a/sqrtf(nn));
  score[i]=sv;
  unsigned bts = __float_as_uint(sv);
  u[i] = (bts & 0x80000000u) ? ~bts : (bts | 0x80000000u);
}

// per-graph 3-level radix select on orderable uints: exact k-th value + #ties needed
__global__ __launch_bounds__(1024) void k_select(
    const unsigned* __restrict__ u, int R, int Ksel,
    unsigned* __restrict__ thr_out, int* __restrict__ need_out){
  __shared__ int hist[2048];
  __shared__ int seg[32];
  __shared__ int sh_b, sh_k;
  int g = blockIdx.x, tid = threadIdx.x;
  const unsigned* ug = u + (size_t)g*R;
  unsigned prefix = 0;
  int K = Ksel;
  for(int lev=0; lev<3; lev++){
    int shf = (lev==0)?21:((lev==1)?10:0);
    int nb  = (lev==2)?1024:2048;
    for(int i=tid;i<2048;i+=1024) hist[i]=0;
    __syncthreads();
    for(int i=tid;i<R;i+=1024){
      unsigned v = ug[i];
      bool ok = (lev==0) || (lev==1 && (v>>21)==prefix) || (lev==2 && (v>>10)==prefix);
      if(ok) atomicAdd(&hist[(v>>shf)&(nb-1)], 1);
    }
    __syncthreads();
    int W = nb/32;
    if(tid<32){ int s=0; int lo=nb-W*(tid+1); for(int b=lo;b<lo+W;b++) s+=hist[b]; seg[tid]=s; }
    __syncthreads();
    if(tid==0){
      int kk=K, sgi=0;
      while(seg[sgi]<kk){ kk-=seg[sgi]; sgi++; }
      int b = nb-1-W*sgi;
      while(hist[b]<kk){ kk-=hist[b]; b--; }
      sh_b=b; sh_k=kk;
    }
    __syncthreads();
    int b = sh_b; K = sh_k;
    if(lev==0) prefix = (unsigned)b;
    else if(lev==1) prefix = (prefix<<11) | (unsigned)b;
    else prefix = (prefix<<10) | (unsigned)b;
    __syncthreads();
  }
  if(tid==0){ thr_out[g]=prefix; need_out[g]=K; }
}

// deterministic compaction: take u>thr plus lowest-index u==thr (matches lax.top_k ties)
__global__ __launch_bounds__(1024) void k_compact(
    const unsigned* __restrict__ u, const float* __restrict__ score,
    const unsigned* __restrict__ thr_arr, const int* __restrict__ need_arr,
    int R, int Kout, int* __restrict__ newid, int* __restrict__ oldid,
    float* __restrict__ scale){
  __shared__ int wsA[16], wsB[16];
  __shared__ int carr0, carr1;
  int g = blockIdx.x, tid = threadIdx.x, lane = tid&63, w = tid>>6;
  unsigned thr = thr_arr[g]; int need = need_arr[g];
  if(tid==0){ carr0=0; carr1=0; }
  __syncthreads();
  for(int bb=0; bb<R; bb+=1024){
    int i = bb + tid; bool in = i < R;
    unsigned uv = in ? u[(size_t)g*R+i] : 0u;
    int eq = (in && uv==thr) ? 1:0;
    int gt = (in && uv>thr) ? 1:0;
    int inc = eq;
    for(int o=1;o<64;o<<=1){ int t=__shfl_up(inc,o,64); if(lane>=o) inc+=t; }
    if(lane==63) wsA[w]=inc;
    __syncthreads();
    int wb=0; for(int k=0;k<w;k++) wb+=wsA[k];
    int eq_excl = carr0 + wb + inc - eq;
    int take = (gt || (eq && eq_excl<need)) ? 1 : 0;
    int inc2 = take;
    for(int o=1;o<64;o<<=1){ int t=__shfl_up(inc2,o,64); if(lane>=o) inc2+=t; }
    if(lane==63) wsB[w]=inc2;
    __syncthreads();
    int wb2=0; for(int k=0;k<w;k++) wb2+=wsB[k];
    int pos = carr1 + wb2 + inc2 - take;
    if(take){
      int nr = g*Kout + pos;
      newid[(size_t)g*R+i] = nr;
      oldid[nr] = g*R+i;
      scale[nr] = score[(size_t)g*R+i];
    }
    __syncthreads();
    if(tid==1023){ carr0 += wb + inc; carr1 += wb2 + inc2; }
    __syncthreads();
  }
}

__global__ __launch_bounds__(256) void k_pool_gather(
    const float* __restrict__ x, const int* __restrict__ oldid,
    const float* __restrict__ scale, int C, int total, float* __restrict__ xnew){
  int i = blockIdx.x*256+threadIdx.x;
  if(i>=total) return;
  int r = i / C, c = i % C;
  xnew[i] = x[(size_t)oldid[r]*C + c] * scale[r];
}

// dense row-GEMM: block = 256 threads = (256/CO subgroups) x CO channels,
// each subgroup owns NPG rows staged in LDS (broadcast reads)
template<int K,int CO,int NPG,bool DOELU>
__global__ __launch_bounds__(256) void k_gemm(
    const float* __restrict__ X, const float* __restrict__ W,
    const float* __restrict__ bias, float* __restrict__ Y, int n){
  constexpr int SUB = 256/CO;
  constexpr int NB = SUB*NPG;
  __shared__ float xs[NB][K];
  int tid = threadIdx.x;
  int c = tid % CO, sg = tid / CO;
  int n0 = blockIdx.x * NB;
  for(int idx=tid; idx<NB*K; idx+=256){
    int r = idx / K, k = idx % K;
    int row = n0 + r;
    xs[r][k] = (row < n) ? X[(size_t)row*K + k] : 0.f;
  }
  __syncthreads();
  float acc[NPG];
#pragma unroll
  for(int q=0;q<NPG;q++) acc[q]=0.f;
  for(int k=0;k<K;k++){
    float wv = W[(size_t)k*CO + c];
#pragma unroll
    for(int q=0;q<NPG;q++) acc[q] += xs[sg*NPG+q][k]*wv;
  }
  float bv = bias ? bias[c] : 0.f;
#pragma unroll
  for(int q=0;q<NPG;q++){
    int row = n0 + sg*NPG + q;
    if(row < n){
      float v = acc[q] + bv;
      if(DOELU) v = eluf(v);
      Y[(size_t)row*CO + c] = v;
    }
  }
}

// tiny-n tail MLP: compile-time K fully pipelined (unroll 16 -> 16 loads in
// flight instead of ~2; fixes the 130us latency-serialized z2 GEMM from R2)
template<int K,int CO,int ACT>
__global__ __launch_bounds__(256) void k_mlp_t(
    const float* __restrict__ X, const float* __restrict__ W,
    const float* __restrict__ b, float* __restrict__ Y, int n){
  int i = blockIdx.x*256+threadIdx.x;
  if(i>=n*CO) return;
  int r=i/CO, c=i%CO;
  const float* xr = X + (size_t)r*K;
  float a=0.f;
#pragma unroll 16
  for(int k=0;k<K;k++) a = fmaf(xr[k], W[(size_t)k*CO+c], a);
  a += b[c];
  if(ACT) a = eluf(a);
  Y[i]=a;
}

// gate scalar: wave per row, 64 lanes over K=64, coalesced + shuffle reduce
__global__ __launch_bounds__(256) void k_gatev(
    const float* __restrict__ gateb, const float* __restrict__ gw2,
    const float* __restrict__ gb2, float* __restrict__ gatev, int n){
  int wv = (blockIdx.x*256 + threadIdx.x) >> 6;
  int lane = threadIdx.x & 63;
  if(wv >= n) return;
  float v = gateb[(size_t)wv*64 + lane] * gw2[lane];
#pragma unroll
  for(int o=32;o>0;o>>=1) v += __shfl_down(v, o, 64);
  if(lane==0) gatev[wv] = v + gb2[0];
}

// per-graph softmax over gate scalars -> normalized probs
__global__ __launch_bounds__(256) void k_attn_probs(
    const float* __restrict__ gate, float* __restrict__ prob){
  __shared__ float red[256];
  int g = blockIdx.x, tid = threadIdx.x;
  float mx = -1e30f;
  for(int r=tid;r<KP2;r+=256) mx = fmaxf(mx, gate[g*KP2+r]);
  red[tid]=mx; __syncthreads();
  for(int s=128;s>0;s>>=1){ if(tid<s) red[tid]=fmaxf(red[tid],red[tid+s]); __syncthreads(); }
  mx = red[0]; __syncthreads();
  float sm=0.f;
  for(int r=tid;r<KP2;r+=256) sm += expf(gate[g*KP2+r]-mx);
  red[tid]=sm; __syncthreads();
  for(int s=128;s>0;s>>=1){ if(tid<s) red[tid]+=red[tid+s]; __syncthreads(); }
  float inv = 1.f/red[0];
  for(int r=tid;r<KP2;r+=256) prob[g*KP2+r] = expf(gate[g*KP2+r]-mx)*inv;
}

// weighted sum: grid (graph, r-chunk); block partial atomicAdd into zeroed gvec
__global__ __launch_bounds__(256) void k_attn_acc(
    const float* __restrict__ prob, const float* __restrict__ h,
    float* __restrict__ gvec, int RS){
  int g = blockIdx.x, blk = blockIdx.y, c = threadIdx.x;
  int chunk = (KP2 + RS - 1)/RS;
  int rlo = blk*chunk, rhi = rlo+chunk; if(rhi>KP2) rhi=KP2;
  float acc = 0.f;
#pragma unroll 4
  for(int r=rlo; r<rhi; r++)
    acc += prob[g*KP2+r] * h[((size_t)g*KP2+r)*256 + c];
  atomicAdd(&gvec[g*256+c], acc);
}

__global__ __launch_bounds__(64) void k_head(
    const float* __restrict__ z2, const float* __restrict__ w3,
    const float* __restrict__ b3, float* __restrict__ out){
  __shared__ float zc[10]; __shared__ float mred, sred;
  int g=blockIdx.x, tid=threadIdx.x;
  if(tid<10){
    float a=0.f;
#pragma unroll 16
    for(int k=0;k<128;k++) a += z2[g*128+k]*w3[k*10+tid];
    zc[tid]=a+b3[tid];
  }
  __syncthreads();
  if(tid==0){
    float m=zc[0];
    for(int k=1;k<10;k++) m=fmaxf(m,zc[k]);
    float s=0.f;
    for(int k=0;k<10;k++) s+=expf(zc[k]-m);
    mred=m; sred=logf(s);
  }
  __syncthreads();
  if(tid<10) out[g*10+tid]=zc[tid]-mred-sred;
}

} // namespace pk

extern "C" void kernel_launch(void* const* d_in, const int* in_sizes, int n_in,
                              void* d_out, int out_size, void* d_ws, size_t ws_size,
                              hipStream_t stream){
  using namespace pk;
  (void)in_sizes; (void)n_in; (void)out_size;
  const float* pos = (const float*)d_in[0];
  const int*   src = (const int*)d_in[1];
  const int*   dst = (const int*)d_in[2];
  const float* W1  = (const float*)d_in[3];
  const float* as1 = (const float*)d_in[4];
  const float* ad1 = (const float*)d_in[5];
  const float* b1  = (const float*)d_in[6];
  const float* p1  = (const float*)d_in[7];
  const float* W2  = (const float*)d_in[8];
  const float* as2 = (const float*)d_in[9];
  const float* ad2 = (const float*)d_in[10];
  const float* b2  = (const float*)d_in[11];
  const float* p2  = (const float*)d_in[12];
  const float* W3  = (const float*)d_in[13];
  const float* as3 = (const float*)d_in[14];
  const float* ad3 = (const float*)d_in[15];
  const float* b3  = (const float*)d_in[16];
  const float* gw1 = (const float*)d_in[17];
  const float* gb1 = (const float*)d_in[18];
  const float* gw2 = (const float*)d_in[19];
  const float* gb2 = (const float*)d_in[20];
  const float* aw  = (const float*)d_in[21];
  const float* ab  = (const float*)d_in[22];
  const float* w1  = (const float*)d_in[23];
  const float* bb1 = (const float*)d_in[24];
  const float* w2  = (const float*)d_in[25];
  const float* bb2 = (const float*)d_in[26];
  const float* w3  = (const float*)d_in[27];
  const float* bb3 = (const float*)d_in[28];
  float* out = (float*)d_out;

  char* base = (char*)d_ws; size_t off = 0;
  auto alloc = [&](size_t nbytes)->char*{
    char* p = base + off; off = (off + nbytes + 255) & ~(size_t)255; return p;
  };
  // --- zero-init region (one memset) ---
  int*   cnt1  = (int*)alloc((size_t)NB1*4);
  int*   cnt2  = (int*)alloc((size_t)NN2*4);
  int*   cnt3  = (int*)alloc((size_t)NN3*4);
  int*   ecnt2 = (int*)alloc(4);
  int*   ecnt3 = (int*)alloc(4);
  float* acc1  = (float*)alloc((size_t)BG*32*2*4);
  float* acc2  = (float*)alloc((size_t)BG*128*2*4);
  float* acc3  = (float*)alloc((size_t)BG*256*2*4);
  float* gvec  = (float*)alloc((size_t)BG*256*4);
  size_t zend = off;
  // --- 0xFF-init region (newid = -1, one memset) ---
  int*   newid1 = (int*)alloc((size_t)NB1*4);
  int*   newid2 = (int*)alloc((size_t)NN2*4);
  size_t fstart = (size_t)((char*)newid1 - base);
  size_t fend = off;
  // --- plain scratch ---
  float*    xp1    = (float*)alloc((size_t)NB1*32*4);
  float*    als1   = (float*)alloc((size_t)NB1*2*4);
  float*    ald1   = (float*)alloc((size_t)NB1*2*4);
  int*      rowptr1= (int*)alloc((size_t)(NB1+1)*4);
  int*      cursor1= (int*)alloc((size_t)NB1*4);
  int*      esrc1  = (int*)alloc((size_t)NE*4);
  float*    out1   = (float*)alloc((size_t)NB1*32*4);
  float*    score1 = (float*)alloc((size_t)NB1*4);
  unsigned* u1     = (unsigned*)alloc((size_t)NB1*4);
  unsigned* thr1   = (unsigned*)alloc((size_t)BG*4);
  int*      need1  = (int*)alloc((size_t)BG*4);
  int*      oldid1 = (int*)alloc((size_t)NN2*4);
  float*    scale1 = (float*)alloc((size_t)NN2*4);
  float*    xnew1  = (float*)alloc((size_t)NN2*32*4);
  int*      ns2    = (int*)alloc((size_t)CAP2*4);
  int*      nd2    = (int*)alloc((size_t)CAP2*4);
  int*      rowptr2= (int*)alloc((size_t)(NN2+1)*4);
  int*      cursor2= (int*)alloc((size_t)NN2*4);
  int*      esrc2  = (int*)alloc((size_t)CAP2*4);
  float*    xp2    = (float*)alloc((size_t)NN2*128*4);
  float*    als2   = (float*)alloc((size_t)NN2*2*4);
  float*    ald2   = (float*)alloc((size_t)NN2*2*4);
  float*    out2   = (float*)alloc((size_t)NN2*128*4);
  float*    score2 = (float*)alloc((size_t)NN2*4);
  unsigned* u2     = (unsigned*)alloc((size_t)NN2*4);
  unsigned* thr2   = (unsigned*)alloc((size_t)BG*4);
  int*      need2  = (int*)alloc((size_t)BG*4);
  int*      oldid2 = (int*)alloc((size_t)NN3*4);
  float*    scale2 = (float*)alloc((size_t)NN3*4);
  float*    xnew2  = (float*)alloc((size_t)NN3*128*4);
  int*      ns3    = (int*)alloc((size_t)CAP3*4);
  int*      nd3    = (int*)alloc((size_t)CAP3*4);
  int*      rowptr3= (int*)alloc((size_t)(NN3+1)*4);
  int*      cursor3= (int*)alloc((size_t)NN3*4);
  int*      esrc3  = (int*)alloc((size_t)CAP3*4);
  float*    xp3    = (float*)alloc((size_t)NN3*256*4);
  float*    als3   = (float*)alloc((size_t)NN3*4);
  float*    ald3   = (float*)alloc((size_t)NN3*4);
  float*    out3   = (float*)alloc((size_t)NN3*256*4);
  float*    gateb  = (float*)alloc((size_t)NN3*64*4);
  float*    gatev  = (float*)alloc((size_t)NN3*4);
  float*    probs  = (float*)alloc((size_t)NN3*4);
  float*    hbuf   = (float*)alloc((size_t)NN3*256*4);
  float*    z1     = (float*)alloc((size_t)BG*512*4);
  float*    z2     = (float*)alloc((size_t)BG*128*4);
  if(off > ws_size) return;  // workspace too small: fail visibly

  auto cdiv = [](int a, int b){ return (a+b-1)/b; };

  hipMemsetAsync(base, 0, zend, stream);
  hipMemsetAsync(base + fstart, 0xFF, fend - fstart, stream);

  // ---------------- stage 1: GAT(3->32, H=2,F=16) ----------------
  k_xp1<<<cdiv(NB1,256),256,0,stream>>>(pos,W1,as1,ad1,xp1,als1,ald1);
  k_edge_count<<<cdiv(NE,256),256,0,stream>>>(dst,nullptr,NE,NE,cnt1);
  k_scan<<<1,1024,0,stream>>>(cnt1,NB1,rowptr1,cursor1);
  k_scatter<<<cdiv(NE,256),256,0,stream>>>(src,dst,nullptr,NE,NE,cursor1,esrc1);
  k_gat_agg<2,16><<<cdiv(NB1*32,256),256,0,stream>>>(xp1,als1,ald1,rowptr1,esrc1,b1,out1,NB1);
  k_inorm_stats<<<BG*16,256,0,stream>>>(out1,8192,32,16,acc1);
  k_inorm_apply<<<cdiv(NB1*32,256),256,0,stream>>>(out1,acc1,8192,32,NB1*32);
  // ---------------- pool 1 (k=2458) ----------------
  k_score<<<cdiv(NB1,256),256,0,stream>>>(out1,p1,32,NB1,score1,u1);
  k_select<<<BG,1024,0,stream>>>(u1,8192,KP1,thr1,need1);
  k_compact<<<BG,1024,0,stream>>>(u1,score1,thr1,need1,8192,KP1,newid1,oldid1,scale1);
  k_pool_gather<<<cdiv(NN2*32,256),256,0,stream>>>(out1,oldid1,scale1,32,NN2*32,xnew1);
  k_edge_compact<<<cdiv(NE,256),256,0,stream>>>(src,dst,nullptr,NE,NE,newid1,ecnt2,ns2,nd2,CAP2);
  // ---------------- stage 2: GAT(32->128, H=2,F=64) ----------------
  k_edge_count<<<cdiv(CAP2,256),256,0,stream>>>(nd2,ecnt2,0,CAP2,cnt2);
  k_scan<<<1,1024,0,stream>>>(cnt2,NN2,rowptr2,cursor2);
  k_scatter<<<cdiv(CAP2,256),256,0,stream>>>(ns2,nd2,ecnt2,0,CAP2,cursor2,esrc2);
  k_gemm<32,128,4,false><<<cdiv(NN2,8),256,0,stream>>>(xnew1,W2,nullptr,xp2,NN2);
  k_al<<<cdiv(NN2*2,256),256,0,stream>>>(xp2,as2,ad2,NN2,2,64,als2,ald2);
  k_gat_agg<2,64><<<cdiv(NN2*128,256),256,0,stream>>>(xp2,als2,ald2,rowptr2,esrc2,b2,out2,NN2);
  k_inorm_stats<<<BG*16,256,0,stream>>>(out2,KP1,128,16,acc2);
  k_inorm_apply<<<cdiv(NN2*128,256),256,0,stream>>>(out2,acc2,KP1,128,NN2*128);
  // ---------------- pool 2 (k=738) ----------------
  k_score<<<cdiv(NN2,256),256,0,stream>>>(out2,p2,128,NN2,score2,u2);
  k_select<<<BG,1024,0,stream>>>(u2,KP1,KP2,thr2,need2);
  k_compact<<<BG,1024,0,stream>>>(u2,score2,thr2,need2,KP1,KP2,newid2,oldid2,scale2);
  k_pool_gather<<<cdiv(NN3*128,256),256,0,stream>>>(out2,oldid2,scale2,128,NN3*128,xnew2);
  k_edge_compact<<<cdiv(CAP2,256),256,0,stream>>>(ns2,nd2,ecnt2,0,CAP2,newid2,ecnt3,ns3,nd3,CAP3);
  // ---------------- stage 3: GAT(128->256, H=1,F=256) ----------------
  k_edge_count<<<cdiv(CAP3,256),256,0,stream>>>(nd3,ecnt3,0,CAP3,cnt3);
  k_scan<<<1,1024,0,stream>>>(cnt3,NN3,rowptr3,cursor3);
  k_scatter<<<cdiv(CAP3,256),256,0,stream>>>(ns3,nd3,ecnt3,0,CAP3,cursor3,esrc3);
  k_gemm<128,256,4,false><<<cdiv(NN3,4),256,0,stream>>>(xnew2,W3,nullptr,xp3,NN3);
  k_al<<<cdiv(NN3,256),256,0,stream>>>(xp3,as3,ad3,NN3,1,256,als3,ald3);
  k_gat_agg<1,256><<<cdiv(NN3*256,256),256,0,stream>>>(xp3,als3,ald3,rowptr3,esrc3,b3,out3,NN3);
  k_inorm_stats<<<BG*8,256,0,stream>>>(out3,KP2,256,8,acc3);
  k_inorm_apply<<<cdiv(NN3*256,256),256,0,stream>>>(out3,acc3,KP2,256,NN3*256);
  // ---------------- global attention + MLP head ----------------
  k_gemm<256,64,2,true><<<cdiv(NN3,8),256,0,stream>>>(out3,gw1,gb1,gateb,NN3);
  k_gatev<<<cdiv(NN3,4),256,0,stream>>>(gateb,gw2,gb2,gatev,NN3);
  k_gemm<256,256,4,true><<<cdiv(NN3,4),256,0,stream>>>(out3,aw,ab,hbuf,NN3);
  k_attn_probs<<<BG,256,0,stream>>>(gatev,probs);
  k_attn_acc<<<dim3(BG,24),256,0,stream>>>(probs,hbuf,gvec,24);
  k_mlp_t<256,512,1><<<cdiv(BG*512,256),256,0,stream>>>(gvec,w1,bb1,z1,BG);
  k_mlp_t<512,128,1><<<cdiv(BG*128,256),256,0,stream>>>(z1,w2,bb2,z2,BG);
  k_head<<<BG,64,0,stream>>>(z2,w3,bb3,out);
}

// Round 4
// 820.944 us; speedup vs baseline: 1.4819x; 1.0654x over previous
//
#include <hip/hip_runtime.h>
#include <cstdint>
#include <cstddef>

#define DI __device__ __forceinline__

namespace pk {

constexpr int NB1 = 65536;      // stage-1 nodes (B*N)
constexpr int NE  = 1048576;    // edges (B*N*DEG)
constexpr int BG  = 8;          // graphs
constexpr int KP1 = 2458;       // top-k 1
constexpr int KP2 = 738;        // top-k 2
constexpr int NN2 = BG*KP1;     // 19664
constexpr int NN3 = BG*KP2;     // 5904
constexpr int CAP2 = 524288;    // edge-buffer cap after pool1 (expected ~94K)
constexpr int CAP3 = 131072;    // edge-buffer cap after pool2 (expected ~8.5K)

DI float lrelu(float x){ return x > 0.f ? x : 0.2f*x; }
DI float eluf(float x){ return x > 0.f ? x : expf(x) - 1.f; }

// ---- stage-1 projection: xp = pos @ W1 (K=3), plus attention logits per head
__global__ __launch_bounds__(256) void k_xp1(
    const float* __restrict__ pos, const float* __restrict__ W,
    const float* __restrict__ as_, const float* __restrict__ ad_,
    float* __restrict__ xp, float* __restrict__ als, float* __restrict__ ald){
  int i = blockIdx.x*256 + threadIdx.x;
  if(i >= NB1) return;
  float p0=pos[3*i], p1=pos[3*i+1], p2=pos[3*i+2];
  float row[32];
#pragma unroll
  for(int c=0;c<32;c++) row[c] = p0*W[c] + p1*W[32+c] + p2*W[64+c];
  float s0=0.f,d0=0.f,s1=0.f,d1=0.f;
#pragma unroll
  for(int f=0;f<16;f++){
    s0 += row[f]*as_[f];        d0 += row[f]*ad_[f];
    s1 += row[16+f]*as_[16+f];  d1 += row[16+f]*ad_[16+f];
  }
  float4* o = reinterpret_cast<float4*>(xp + (size_t)i*32);
#pragma unroll
  for(int q=0;q<8;q++) o[q] = make_float4(row[4*q],row[4*q+1],row[4*q+2],row[4*q+3]);
  als[2*i]=s0; als[2*i+1]=s1; ald[2*i]=d0; ald[2*i+1]=d1;
}

DI int edge_m(const int* mptr, int fixedm, int mcap){
  int m = mptr ? *mptr : fixedm;
  return m < mcap ? m : mcap;
}

__global__ __launch_bounds__(256) void k_edge_count(
    const int* __restrict__ de, const int* __restrict__ mptr,
    int fixedm, int mcap, int* __restrict__ cnt){
  int i = blockIdx.x*256 + threadIdx.x;
  if(i < edge_m(mptr,fixedm,mcap)) atomicAdd(&cnt[de[i]], 1);
}

__global__ __launch_bounds__(256) void k_scatter(
    const int* __restrict__ se, const int* __restrict__ de,
    const int* __restrict__ mptr, int fixedm, int mcap,
    int* __restrict__ cursor, int* __restrict__ eo){
  int i = blockIdx.x*256 + threadIdx.x;
  if(i < edge_m(mptr,fixedm,mcap)){
    int p = atomicAdd(&cursor[de[i]], 1);
    eo[p] = se[i];
  }
}

// block-aggregated stream compaction: one global atomic per block
__global__ __launch_bounds__(256) void k_edge_compact(
    const int* __restrict__ se, const int* __restrict__ de,
    const int* __restrict__ mptr, int fixedm, int mcap,
    const int* __restrict__ newid, int* __restrict__ ocnt,
    int* __restrict__ ons, int* __restrict__ ond, int ocap){
  __shared__ int wcnt[4];
  __shared__ int gbase;
  int tid = threadIdx.x;
  int i = blockIdx.x*256 + tid;
  int m = edge_m(mptr,fixedm,mcap);
  bool act = false; int a = 0, b = 0;
  if(i < m){
    a = newid[se[i]]; b = newid[de[i]];
    act = (a >= 0 && b >= 0);
  }
  unsigned long long mask = __ballot(act);
  int lane = tid & 63, w = tid >> 6;
  int rank = __popcll(mask & ((1ull << lane) - 1ull));
  if(lane == 0) wcnt[w] = __popcll(mask);
  __syncthreads();
  if(tid == 0){
    int t = wcnt[0] + wcnt[1] + wcnt[2] + wcnt[3];
    gbase = t ? atomicAdd(ocnt, t) : 0;
  }
  __syncthreads();
  if(act){
    int off = 0;
    for(int k = 0; k < w; k++) off += wcnt[k];
    int s = gbase + off + rank;
    if(s < ocap){ ons[s] = a; ond[s] = b; }
  }
}

// single-block hierarchical exclusive scan (wave shfl + LDS wave sums)
__global__ __launch_bounds__(1024) void k_scan(
    const int* __restrict__ cnt, int n, int* __restrict__ rowptr, int* __restrict__ cursor){
  __shared__ int wsum[16];
  __shared__ int carry;
  int tid = threadIdx.x, lane = tid & 63, w = tid >> 6;
  if(tid==0) carry = 0;
  __syncthreads();
  const int PER = 16, CH = 1024*PER;
  for(int bb=0; bb<n; bb+=CH){
    int vals[PER]; int s=0;
    int i0 = bb + tid*PER;
#pragma unroll
    for(int j=0;j<PER;j++){ int i=i0+j; int v=(i<n)?cnt[i]:0; vals[j]=s; s+=v; }
    int inc = s;
    for(int o=1;o<64;o<<=1){ int t=__shfl_up(inc,o,64); if(lane>=o) inc+=t; }
    if(lane==63) wsum[w]=inc;
    __syncthreads();
    int wb=0;
    for(int k=0;k<w;k++) wb+=wsum[k];
    int c0 = carry;
    int tb = c0 + wb + inc - s;
#pragma unroll
    for(int j=0;j<PER;j++){ int i=i0+j; if(i<n){ int e=tb+vals[j]; rowptr[i]=e; cursor[i]=e; } }
    __syncthreads();
    if(tid==1023) carry = c0 + wb + inc;
    __syncthreads();
  }
  if(tid==0) rowptr[n]=carry;
}

// attention weights: one thread per (node,head). 2-pass max/exp over CSR
// edges; stores UNNORMALIZED edge weights (CSR-position-indexed), self
// weight, and denominator. Kills the per-channel exp duplication (R3: 32M
// exps -> 2M).
template<int H>
__global__ __launch_bounds__(256) void k_gat_w(
    const float* __restrict__ als, const float* __restrict__ ald,
    const int* __restrict__ rowptr, const int* __restrict__ esrc,
    float* __restrict__ wexp, float* __restrict__ wself,
    float* __restrict__ wden, int n){
  int t = blockIdx.x*256 + threadIdx.x;
  if(t >= n*H) return;
  int node = t / H, hh = t % H;
  float aldn = ald[node*H+hh];
  float es = lrelu(als[node*H+hh] + aldn);
  int r0 = rowptr[node], r1 = rowptr[node+1];
  float mx = es;
  for(int k=r0;k<r1;k++) mx = fmaxf(mx, lrelu(als[esrc[k]*H+hh] + aldn));
  float sw = expf(es - mx);
  float den = sw;
  for(int k=r0;k<r1;k++){
    float ex = expf(lrelu(als[esrc[k]*H+hh] + aldn) - mx);
    wexp[(size_t)k*H+hh] = ex;
    den += ex;
  }
  wself[node*H+hh] = sw;
  wden[node*H+hh] = den;
}

// weighted aggregate: thread = (node, 4-channel group). Inner loop per edge:
// 1 broadcast weight load + 1 float4 xp gather + 4 FMAs.
template<int H,int F>
__global__ __launch_bounds__(256) void k_gat_agg(
    const float* __restrict__ xp, const int* __restrict__ rowptr,
    const int* __restrict__ esrc, const float* __restrict__ wexp,
    const float* __restrict__ wself, const float* __restrict__ wden,
    const float* __restrict__ bias, float* __restrict__ out, int n){
  constexpr int C = H*F, C4 = C/4;
  int t = blockIdx.x*256 + threadIdx.x;
  int node = t / C4, p = t % C4;
  if(node >= n) return;
  int hh = (4*p) / F;
  const float4* xp4 = (const float4*)xp;
  float4 xs = xp4[(size_t)node*C4 + p];
  float sw = wself[node*H+hh];
  float ax = sw*xs.x, ay = sw*xs.y, az = sw*xs.z, aw_ = sw*xs.w;
  int r0 = rowptr[node], r1 = rowptr[node+1];
  for(int k=r0;k<r1;k++){
    int s = esrc[k];
    float wv = wexp[(size_t)k*H+hh];
    float4 v = xp4[(size_t)s*C4 + p];
    ax += wv*v.x; ay += wv*v.y; az += wv*v.z; aw_ += wv*v.w;
  }
  float inv = 1.f / wden[node*H+hh];
  const float4* b4 = (const float4*)bias;
  float4 bv = b4[p];
  float4 r; r.x = ax*inv + bv.x; r.y = ay*inv + bv.y;
  r.z = az*inv + bv.z; r.w = aw_*inv + bv.w;
  ((float4*)out)[(size_t)node*C4 + p] = r;
}

__global__ __launch_bounds__(256) void k_al(
    const float* __restrict__ xp, const float* __restrict__ a_s,
    const float* __restrict__ a_d, int n, int H, int F,
    float* __restrict__ als, float* __restrict__ ald){
  int i = blockIdx.x*256+threadIdx.x;
  if(i >= n*H) return;
  int node = i/H, hh = i%H;
  const float* row = xp + (size_t)node*H*F + hh*F;
  float s=0.f, d=0.f;
  for(int f=0;f<F;f++){ s += row[f]*a_s[hh*F+f]; d += row[f]*a_d[hh*F+f]; }
  als[i]=s; ald[i]=d;
}

__global__ __launch_bounds__(256) void k_inorm_stats(
    const float* __restrict__ x, int R, int C, int RS, float* __restrict__ accum){
  int g = blockIdx.x / RS, blk = blockIdx.x % RS;
  int NS = 256 / C;
  int c = threadIdx.x % C, rs = threadIdx.x / C;
  int chunk = (R + RS - 1)/RS;
  int rlo = blk*chunk, rhi = rlo+chunk; if(rhi>R) rhi=R;
  float s=0.f, sq=0.f;
  for(int r=rlo+rs; r<rhi; r+=NS){ float v = x[((size_t)g*R+r)*C + c]; s+=v; sq+=v*v; }
  atomicAdd(&accum[(g*C+c)*2], s);
  atomicAdd(&accum[(g*C+c)*2+1], sq);
}

__global__ __launch_bounds__(256) void k_inorm_apply(
    float* __restrict__ x, const float* __restrict__ accum, int R, int C, int total){
  int i = blockIdx.x*256+threadIdx.x;
  if(i>=total) return;
  int c = i % C; int g = i / (R*C);
  float s = accum[(g*C+c)*2], sq = accum[(g*C+c)*2+1];
  float mu = s / (float)R;
  float var = sq / (float)R - mu*mu; var = fmaxf(var, 0.f);
  float v = (x[i]-mu)*rsqrtf(var+1e-5f);
  x[i] = eluf(v);
}

__global__ __launch_bounds__(256) void k_score(
    const float* __restrict__ x, const float* __restrict__ p,
    int C, int n, float* __restrict__ score, unsigned* __restrict__ u){
  int i = blockIdx.x*256+threadIdx.x;
  if(i>=n) return;
  float a=0.f, nn=0.f;
  for(int c=0;c<C;c++){ float pv=p[c]; a += x[(size_t)i*C+c]*pv; nn += pv*pv; }
  float sv = tanhf(a/sqrtf(nn));
  score[i]=sv;
  unsigned bts = __float_as_uint(sv);
  u[i] = (bts & 0x80000000u) ? ~bts : (bts | 0x80000000u);
}

// per-graph 3-level radix select on orderable uints: exact k-th value + #ties needed
__global__ __launch_bounds__(1024) void k_select(
    const unsigned* __restrict__ u, int R, int Ksel,
    unsigned* __restrict__ thr_out, int* __restrict__ need_out){
  __shared__ int hist[2048];
  __shared__ int seg[32];
  __shared__ int sh_b, sh_k;
  int g = blockIdx.x, tid = threadIdx.x;
  const unsigned* ug = u + (size_t)g*R;
  unsigned prefix = 0;
  int K = Ksel;
  for(int lev=0; lev<3; lev++){
    int shf = (lev==0)?21:((lev==1)?10:0);
    int nb  = (lev==2)?1024:2048;
    for(int i=tid;i<2048;i+=1024) hist[i]=0;
    __syncthreads();
    for(int i=tid;i<R;i+=1024){
      unsigned v = ug[i];
      bool ok = (lev==0) || (lev==1 && (v>>21)==prefix) || (lev==2 && (v>>10)==prefix);
      if(ok) atomicAdd(&hist[(v>>shf)&(nb-1)], 1);
    }
    __syncthreads();
    int W = nb/32;
    if(tid<32){ int s=0; int lo=nb-W*(tid+1); for(int b=lo;b<lo+W;b++) s+=hist[b]; seg[tid]=s; }
    __syncthreads();
    if(tid==0){
      int kk=K, sgi=0;
      while(seg[sgi]<kk){ kk-=seg[sgi]; sgi++; }
      int b = nb-1-W*sgi;
      while(hist[b]<kk){ kk-=hist[b]; b--; }
      sh_b=b; sh_k=kk;
    }
    __syncthreads();
    int b = sh_b; K = sh_k;
    if(lev==0) prefix = (unsigned)b;
    else if(lev==1) prefix = (prefix<<11) | (unsigned)b;
    else prefix = (prefix<<10) | (unsigned)b;
    __syncthreads();
  }
  if(tid==0){ thr_out[g]=prefix; need_out[g]=K; }
}

// deterministic compaction: take u>thr plus lowest-index u==thr (matches lax.top_k ties)
__global__ __launch_bounds__(1024) void k_compact(
    const unsigned* __restrict__ u, const float* __restrict__ score,
    const unsigned* __restrict__ thr_arr, const int* __restrict__ need_arr,
    int R, int Kout, int* __restrict__ newid, int* __restrict__ oldid,
    float* __restrict__ scale){
  __shared__ int wsA[16], wsB[16];
  __shared__ int carr0, carr1;
  int g = blockIdx.x, tid = threadIdx.x, lane = tid&63, w = tid>>6;
  unsigned thr = thr_arr[g]; int need = need_arr[g];
  if(tid==0){ carr0=0; carr1=0; }
  __syncthreads();
  for(int bb=0; bb<R; bb+=1024){
    int i = bb + tid; bool in = i < R;
    unsigned uv = in ? u[(size_t)g*R+i] : 0u;
    int eq = (in && uv==thr) ? 1:0;
    int gt = (in && uv>thr) ? 1:0;
    int inc = eq;
    for(int o=1;o<64;o<<=1){ int t=__shfl_up(inc,o,64); if(lane>=o) inc+=t; }
    if(lane==63) wsA[w]=inc;
    __syncthreads();
    int wb=0; for(int k=0;k<w;k++) wb+=wsA[k];
    int eq_excl = carr0 + wb + inc - eq;
    int take = (gt || (eq && eq_excl<need)) ? 1 : 0;
    int inc2 = take;
    for(int o=1;o<64;o<<=1){ int t=__shfl_up(inc2,o,64); if(lane>=o) inc2+=t; }
    if(lane==63) wsB[w]=inc2;
    __syncthreads();
    int wb2=0; for(int k=0;k<w;k++) wb2+=wsB[k];
    int pos = carr1 + wb2 + inc2 - take;
    if(take){
      int nr = g*Kout + pos;
      newid[(size_t)g*R+i] = nr;
      oldid[nr] = g*R+i;
      scale[nr] = score[(size_t)g*R+i];
    }
    __syncthreads();
    if(tid==1023){ carr0 += wb + inc; carr1 += wb2 + inc2; }
    __syncthreads();
  }
}

__global__ __launch_bounds__(256) void k_pool_gather(
    const float* __restrict__ x, const int* __restrict__ oldid,
    const float* __restrict__ scale, int C, int total, float* __restrict__ xnew){
  int i = blockIdx.x*256+threadIdx.x;
  if(i>=total) return;
  int r = i / C, c = i % C;
  xnew[i] = x[(size_t)oldid[r]*C + c] * scale[r];
}

// dense row-GEMM: block = 256 threads = (256/CO subgroups) x CO channels
template<int K,int CO,int NPG,bool DOELU>
__global__ __launch_bounds__(256) void k_gemm(
    const float* __restrict__ X, const float* __restrict__ W,
    const float* __restrict__ bias, float* __restrict__ Y, int n){
  constexpr int SUB = 256/CO;
  constexpr int NB = SUB*NPG;
  __shared__ float xs[NB][K];
  int tid = threadIdx.x;
  int c = tid % CO, sg = tid / CO;
  int n0 = blockIdx.x * NB;
  for(int idx=tid; idx<NB*K; idx+=256){
    int r = idx / K, k = idx % K;
    int row = n0 + r;
    xs[r][k] = (row < n) ? X[(size_t)row*K + k] : 0.f;
  }
  __syncthreads();
  float acc[NPG];
#pragma unroll
  for(int q=0;q<NPG;q++) acc[q]=0.f;
  for(int k=0;k<K;k++){
    float wv = W[(size_t)k*CO + c];
#pragma unroll
    for(int q=0;q<NPG;q++) acc[q] += xs[sg*NPG+q][k]*wv;
  }
  float bv = bias ? bias[c] : 0.f;
#pragma unroll
  for(int q=0;q<NPG;q++){
    int row = n0 + sg*NPG + q;
    if(row < n){
      float v = acc[q] + bv;
      if(DOELU) v = eluf(v);
      Y[(size_t)row*CO + c] = v;
    }
  }
}

// tiny-n tail MLP: compile-time K fully pipelined
template<int K,int CO,int ACT>
__global__ __launch_bounds__(256) void k_mlp_t(
    const float* __restrict__ X, const float* __restrict__ W,
    const float* __restrict__ b, float* __restrict__ Y, int n){
  int i = blockIdx.x*256+threadIdx.x;
  if(i>=n*CO) return;
  int r=i/CO, c=i%CO;
  const float* xr = X + (size_t)r*K;
  float a=0.f;
#pragma unroll 16
  for(int k=0;k<K;k++) a = fmaf(xr[k], W[(size_t)k*CO+c], a);
  a += b[c];
  if(ACT) a = eluf(a);
  Y[i]=a;
}

// gate scalar: wave per row, 64 lanes over K=64, coalesced + shuffle reduce
__global__ __launch_bounds__(256) void k_gatev(
    const float* __restrict__ gateb, const float* __restrict__ gw2,
    const float* __restrict__ gb2, float* __restrict__ gatev, int n){
  int wv = (blockIdx.x*256 + threadIdx.x) >> 6;
  int lane = threadIdx.x & 63;
  if(wv >= n) return;
  float v = gateb[(size_t)wv*64 + lane] * gw2[lane];
#pragma unroll
  for(int o=32;o>0;o>>=1) v += __shfl_down(v, o, 64);
  if(lane==0) gatev[wv] = v + gb2[0];
}

// per-graph softmax over gate scalars -> normalized probs
__global__ __launch_bounds__(256) void k_attn_probs(
    const float* __restrict__ gate, float* __restrict__ prob){
  __shared__ float red[256];
  int g = blockIdx.x, tid = threadIdx.x;
  float mx = -1e30f;
  for(int r=tid;r<KP2;r+=256) mx = fmaxf(mx, gate[g*KP2+r]);
  red[tid]=mx; __syncthreads();
  for(int s=128;s>0;s>>=1){ if(tid<s) red[tid]=fmaxf(red[tid],red[tid+s]); __syncthreads(); }
  mx = red[0]; __syncthreads();
  float sm=0.f;
  for(int r=tid;r<KP2;r+=256) sm += expf(gate[g*KP2+r]-mx);
  red[tid]=sm; __syncthreads();
  for(int s=128;s>0;s>>=1){ if(tid<s) red[tid]+=red[tid+s]; __syncthreads(); }
  float inv = 1.f/red[0];
  for(int r=tid;r<KP2;r+=256) prob[g*KP2+r] = expf(gate[g*KP2+r]-mx)*inv;
}

// weighted sum: grid (graph, r-chunk); block partial atomicAdd into zeroed gvec
__global__ __launch_bounds__(256) void k_attn_acc(
    const float* __restrict__ prob, const float* __restrict__ h,
    float* __restrict__ gvec, int RS){
  int g = blockIdx.x, blk = blockIdx.y, c = threadIdx.x;
  int chunk = (KP2 + RS - 1)/RS;
  int rlo = blk*chunk, rhi = rlo+chunk; if(rhi>KP2) rhi=KP2;
  float acc = 0.f;
#pragma unroll 4
  for(int r=rlo; r<rhi; r++)
    acc += prob[g*KP2+r] * h[((size_t)g*KP2+r)*256 + c];
  atomicAdd(&gvec[g*256+c], acc);
}

__global__ __launch_bounds__(64) void k_head(
    const float* __restrict__ z2, const float* __restrict__ w3,
    const float* __restrict__ b3, float* __restrict__ out){
  __shared__ float zc[10]; __shared__ float mred, sred;
  int g=blockIdx.x, tid=threadIdx.x;
  if(tid<10){
    float a=0.f;
#pragma unroll 16
    for(int k=0;k<128;k++) a += z2[g*128+k]*w3[k*10+tid];
    zc[tid]=a+b3[tid];
  }
  __syncthreads();
  if(tid==0){
    float m=zc[0];
    for(int k=1;k<10;k++) m=fmaxf(m,zc[k]);
    float s=0.f;
    for(int k=0;k<10;k++) s+=expf(zc[k]-m);
    mred=m; sred=logf(s);
  }
  __syncthreads();
  if(tid<10) out[g*10+tid]=zc[tid]-mred-sred;
}

} // namespace pk

extern "C" void kernel_launch(void* const* d_in, const int* in_sizes, int n_in,
                              void* d_out, int out_size, void* d_ws, size_t ws_size,
                              hipStream_t stream){
  using namespace pk;
  (void)in_sizes; (void)n_in; (void)out_size;
  const float* pos = (const float*)d_in[0];
  const int*   src = (const int*)d_in[1];
  const int*   dst = (const int*)d_in[2];
  const float* W1  = (const float*)d_in[3];
  const float* as1 = (const float*)d_in[4];
  const float* ad1 = (const float*)d_in[5];
  const float* b1  = (const float*)d_in[6];
  const float* p1  = (const float*)d_in[7];
  const float* W2  = (const float*)d_in[8];
  const float* as2 = (const float*)d_in[9];
  const float* ad2 = (const float*)d_in[10];
  const float* b2  = (const float*)d_in[11];
  const float* p2  = (const float*)d_in[12];
  const float* W3  = (const float*)d_in[13];
  const float* as3 = (const float*)d_in[14];
  const float* ad3 = (const float*)d_in[15];
  const float* b3  = (const float*)d_in[16];
  const float* gw1 = (const float*)d_in[17];
  const float* gb1 = (const float*)d_in[18];
  const float* gw2 = (const float*)d_in[19];
  const float* gb2 = (const float*)d_in[20];
  const float* aw  = (const float*)d_in[21];
  const float* ab  = (const float*)d_in[22];
  const float* w1  = (const float*)d_in[23];
  const float* bb1 = (const float*)d_in[24];
  const float* w2  = (const float*)d_in[25];
  const float* bb2 = (const float*)d_in[26];
  const float* w3  = (const float*)d_in[27];
  const float* bb3 = (const float*)d_in[28];
  float* out = (float*)d_out;

  char* base = (char*)d_ws; size_t off = 0;
  auto alloc = [&](size_t nbytes)->char*{
    char* p = base + off; off = (off + nbytes + 255) & ~(size_t)255; return p;
  };
  // --- zero-init region (one memset) ---
  int*   cnt1  = (int*)alloc((size_t)NB1*4);
  int*   cnt2  = (int*)alloc((size_t)NN2*4);
  int*   cnt3  = (int*)alloc((size_t)NN3*4);
  int*   ecnt2 = (int*)alloc(4);
  int*   ecnt3 = (int*)alloc(4);
  float* acc1  = (float*)alloc((size_t)BG*32*2*4);
  float* acc2  = (float*)alloc((size_t)BG*128*2*4);
  float* acc3  = (float*)alloc((size_t)BG*256*2*4);
  float* gvec  = (float*)alloc((size_t)BG*256*4);
  size_t zend = off;
  // --- 0xFF-init region (newid = -1, one memset) ---
  int*   newid1 = (int*)alloc((size_t)NB1*4);
  int*   newid2 = (int*)alloc((size_t)NN2*4);
  size_t fstart = (size_t)((char*)newid1 - base);
  size_t fend = off;
  // --- plain scratch ---
  float*    xp1    = (float*)alloc((size_t)NB1*32*4);
  float*    als1   = (float*)alloc((size_t)NB1*2*4);
  float*    ald1   = (float*)alloc((size_t)NB1*2*4);
  int*      rowptr1= (int*)alloc((size_t)(NB1+1)*4);
  int*      cursor1= (int*)alloc((size_t)NB1*4);
  int*      esrc1  = (int*)alloc((size_t)NE*4);
  float*    wexp1  = (float*)alloc((size_t)NE*2*4);
  float*    wself1 = (float*)alloc((size_t)NB1*2*4);
  float*    wden1  = (float*)alloc((size_t)NB1*2*4);
  float*    out1   = (float*)alloc((size_t)NB1*32*4);
  float*    score1 = (float*)alloc((size_t)NB1*4);
  unsigned* u1     = (unsigned*)alloc((size_t)NB1*4);
  unsigned* thr1   = (unsigned*)alloc((size_t)BG*4);
  int*      need1  = (int*)alloc((size_t)BG*4);
  int*      oldid1 = (int*)alloc((size_t)NN2*4);
  float*    scale1 = (float*)alloc((size_t)NN2*4);
  float*    xnew1  = (float*)alloc((size_t)NN2*32*4);
  int*      ns2    = (int*)alloc((size_t)CAP2*4);
  int*      nd2    = (int*)alloc((size_t)CAP2*4);
  int*      rowptr2= (int*)alloc((size_t)(NN2+1)*4);
  int*      cursor2= (int*)alloc((size_t)NN2*4);
  int*      esrc2  = (int*)alloc((size_t)CAP2*4);
  float*    wexp2  = (float*)alloc((size_t)CAP2*2*4);
  float*    wself2 = (float*)alloc((size_t)NN2*2*4);
  float*    wden2  = (float*)alloc((size_t)NN2*2*4);
  float*    xp2    = (float*)alloc((size_t)NN2*128*4);
  float*    als2   = (float*)alloc((size_t)NN2*2*4);
  float*    ald2   = (float*)alloc((size_t)NN2*2*4);
  float*    out2   = (float*)alloc((size_t)NN2*128*4);
  float*    score2 = (float*)alloc((size_t)NN2*4);
  unsigned* u2     = (unsigned*)alloc((size_t)NN2*4);
  unsigned* thr2   = (unsigned*)alloc((size_t)BG*4);
  int*      need2  = (int*)alloc((size_t)BG*4);
  int*      oldid2 = (int*)alloc((size_t)NN3*4);
  float*    scale2 = (float*)alloc((size_t)NN3*4);
  float*    xnew2  = (float*)alloc((size_t)NN3*128*4);
  int*      ns3    = (int*)alloc((size_t)CAP3*4);
  int*      nd3    = (int*)alloc((size_t)CAP3*4);
  int*      rowptr3= (int*)alloc((size_t)(NN3+1)*4);
  int*      cursor3= (int*)alloc((size_t)NN3*4);
  int*      esrc3  = (int*)alloc((size_t)CAP3*4);
  float*    wexp3  = (float*)alloc((size_t)CAP3*4);
  float*    wself3 = (float*)alloc((size_t)NN3*4);
  float*    wden3  = (float*)alloc((size_t)NN3*4);
  float*    xp3    = (float*)alloc((size_t)NN3*256*4);
  float*    als3   = (float*)alloc((size_t)NN3*4);
  float*    ald3   = (float*)alloc((size_t)NN3*4);
  float*    out3   = (float*)alloc((size_t)NN3*256*4);
  float*    gateb  = (float*)alloc((size_t)NN3*64*4);
  float*    gatev  = (float*)alloc((size_t)NN3*4);
  float*    probs  = (float*)alloc((size_t)NN3*4);
  float*    hbuf   = (float*)alloc((size_t)NN3*256*4);
  float*    z1     = (float*)alloc((size_t)BG*512*4);
  float*    z2     = (float*)alloc((size_t)BG*128*4);
  if(off > ws_size) return;  // workspace too small: fail visibly

  auto cdiv = [](int a, int b){ return (a+b-1)/b; };

  hipMemsetAsync(base, 0, zend, stream);
  hipMemsetAsync(base + fstart, 0xFF, fend - fstart, stream);

  // ---------------- stage 1: GAT(3->32, H=2,F=16) ----------------
  k_xp1<<<cdiv(NB1,256),256,0,stream>>>(pos,W1,as1,ad1,xp1,als1,ald1);
  k_edge_count<<<cdiv(NE,256),256,0,stream>>>(dst,nullptr,NE,NE,cnt1);
  k_scan<<<1,1024,0,stream>>>(cnt1,NB1,rowptr1,cursor1);
  k_scatter<<<cdiv(NE,256),256,0,stream>>>(src,dst,nullptr,NE,NE,cursor1,esrc1);
  k_gat_w<2><<<cdiv(NB1*2,256),256,0,stream>>>(als1,ald1,rowptr1,esrc1,wexp1,wself1,wden1,NB1);
  k_gat_agg<2,16><<<cdiv(NB1*8,256),256,0,stream>>>(xp1,rowptr1,esrc1,wexp1,wself1,wden1,b1,out1,NB1);
  k_inorm_stats<<<BG*16,256,0,stream>>>(out1,8192,32,16,acc1);
  k_inorm_apply<<<cdiv(NB1*32,256),256,0,stream>>>(out1,acc1,8192,32,NB1*32);
  // ---------------- pool 1 (k=2458) ----------------
  k_score<<<cdiv(NB1,256),256,0,stream>>>(out1,p1,32,NB1,score1,u1);
  k_select<<<BG,1024,0,stream>>>(u1,8192,KP1,thr1,need1);
  k_compact<<<BG,1024,0,stream>>>(u1,score1,thr1,need1,8192,KP1,newid1,oldid1,scale1);
  k_pool_gather<<<cdiv(NN2*32,256),256,0,stream>>>(out1,oldid1,scale1,32,NN2*32,xnew1);
  k_edge_compact<<<cdiv(NE,256),256,0,stream>>>(src,dst,nullptr,NE,NE,newid1,ecnt2,ns2,nd2,CAP2);
  // ---------------- stage 2: GAT(32->128, H=2,F=64) ----------------
  k_edge_count<<<cdiv(CAP2,256),256,0,stream>>>(nd2,ecnt2,0,CAP2,cnt2);
  k_scan<<<1,1024,0,stream>>>(cnt2,NN2,rowptr2,cursor2);
  k_scatter<<<cdiv(CAP2,256),256,0,stream>>>(ns2,nd2,ecnt2,0,CAP2,cursor2,esrc2);
  k_gemm<32,128,4,false><<<cdiv(NN2,8),256,0,stream>>>(xnew1,W2,nullptr,xp2,NN2);
  k_al<<<cdiv(NN2*2,256),256,0,stream>>>(xp2,as2,ad2,NN2,2,64,als2,ald2);
  k_gat_w<2><<<cdiv(NN2*2,256),256,0,stream>>>(als2,ald2,rowptr2,esrc2,wexp2,wself2,wden2,NN2);
  k_gat_agg<2,64><<<cdiv(NN2*32,256),256,0,stream>>>(xp2,rowptr2,esrc2,wexp2,wself2,wden2,b2,out2,NN2);
  k_inorm_stats<<<BG*16,256,0,stream>>>(out2,KP1,128,16,acc2);
  k_inorm_apply<<<cdiv(NN2*128,256),256,0,stream>>>(out2,acc2,KP1,128,NN2*128);
  // ---------------- pool 2 (k=738) ----------------
  k_score<<<cdiv(NN2,256),256,0,stream>>>(out2,p2,128,NN2,score2,u2);
  k_select<<<BG,1024,0,stream>>>(u2,KP1,KP2,thr2,need2);
  k_compact<<<BG,1024,0,stream>>>(u2,score2,thr2,need2,KP1,KP2,newid2,oldid2,scale2);
  k_pool_gather<<<cdiv(NN3*128,256),256,0,stream>>>(out2,oldid2,scale2,128,NN3*128,xnew2);
  k_edge_compact<<<cdiv(CAP2,256),256,0,stream>>>(ns2,nd2,ecnt2,0,CAP2,newid2,ecnt3,ns3,nd3,CAP3);
  // ---------------- stage 3: GAT(128->256, H=1,F=256) ----------------
  k_edge_count<<<cdiv(CAP3,256),256,0,stream>>>(nd3,ecnt3,0,CAP3,cnt3);
  k_scan<<<1,1024,0,stream>>>(cnt3,NN3,rowptr3,cursor3);
  k_scatter<<<cdiv(CAP3,256),256,0,stream>>>(ns3,nd3,ecnt3,0,CAP3,cursor3,esrc3);
  k_gemm<128,256,4,false><<<cdiv(NN3,4),256,0,stream>>>(xnew2,W3,nullptr,xp3,NN3);
  k_al<<<cdiv(NN3,256),256,0,stream>>>(xp3,as3,ad3,NN3,1,256,als3,ald3);
  k_gat_w<1><<<cdiv(NN3,256),256,0,stream>>>(als3,ald3,rowptr3,esrc3,wexp3,wself3,wden3,NN3);
  k_gat_agg<1,256><<<cdiv(NN3*64,256),256,0,stream>>>(xp3,rowptr3,esrc3,wexp3,wself3,wden3,b3,out3,NN3);
  k_inorm_stats<<<BG*8,256,0,stream>>>(out3,KP2,256,8,acc3);
  k_inorm_apply<<<cdiv(NN3*256,256),256,0,stream>>>(out3,acc3,KP2,256,NN3*256);
  // ---------------- global attention + MLP head ----------------
  k_gemm<256,64,2,true><<<cdiv(NN3,8),256,0,stream>>>(out3,gw1,gb1,gateb,NN3);
  k_gatev<<<cdiv(NN3,4),256,0,stream>>>(gateb,gw2,gb2,gatev,NN3);
  k_gemm<256,256,4,true><<<cdiv(NN3,4),256,0,stream>>>(out3,aw,ab,hbuf,NN3);
  k_attn_probs<<<BG,256,0,stream>>>(gatev,probs);
  k_attn_acc<<<dim3(BG,24),256,0,stream>>>(probs,hbuf,gvec,24);
  k_mlp_t<256,512,1><<<cdiv(BG*512,256),256,0,stream>>>(gvec,w1,bb1,z1,BG);
  k_mlp_t<512,128,1><<<cdiv(BG*128,256),256,0,stream>>>(z1,w2,bb2,z2,BG);
  k_head<<<BG,64,0,stream>>>(z2,w3,bb3,out);
}

// Round 5
// 715.730 us; speedup vs baseline: 1.6997x; 1.1470x over previous
//
#include <hip/hip_runtime.h>
#include <cstdint>
#include <cstddef>

#define DI __device__ __forceinline__

namespace pk {

constexpr int NB1 = 65536;      // stage-1 nodes (B*N)
constexpr int NE  = 1048576;    // edges (B*N*DEG)
constexpr int BG  = 8;          // graphs
constexpr int KP1 = 2458;       // top-k 1
constexpr int KP2 = 738;        // top-k 2
constexpr int NN2 = BG*KP1;     // 19664
constexpr int NN3 = BG*KP2;     // 5904
constexpr int CAP2 = 524288;    // edge-buffer cap after pool1 (expected ~94K)
constexpr int CAP3 = 131072;    // edge-buffer cap after pool2 (expected ~8.5K)

DI float lrelu(float x){ return x > 0.f ? x : 0.2f*x; }
DI float eluf(float x){ return x > 0.f ? x : expf(x) - 1.f; }

// ---- stage-1 projection: xp = pos @ W1 (K=3), plus attention logits per head
__global__ __launch_bounds__(256) void k_xp1(
    const float* __restrict__ pos, const float* __restrict__ W,
    const float* __restrict__ as_, const float* __restrict__ ad_,
    float* __restrict__ xp, float* __restrict__ als, float* __restrict__ ald){
  int i = blockIdx.x*256 + threadIdx.x;
  if(i >= NB1) return;
  float p0=pos[3*i], p1=pos[3*i+1], p2=pos[3*i+2];
  float row[32];
#pragma unroll
  for(int c=0;c<32;c++) row[c] = p0*W[c] + p1*W[32+c] + p2*W[64+c];
  float s0=0.f,d0=0.f,s1=0.f,d1=0.f;
#pragma unroll
  for(int f=0;f<16;f++){
    s0 += row[f]*as_[f];        d0 += row[f]*ad_[f];
    s1 += row[16+f]*as_[16+f];  d1 += row[16+f]*ad_[16+f];
  }
  float4* o = reinterpret_cast<float4*>(xp + (size_t)i*32);
#pragma unroll
  for(int q=0;q<8;q++) o[q] = make_float4(row[4*q],row[4*q+1],row[4*q+2],row[4*q+3]);
  als[2*i]=s0; als[2*i+1]=s1; ald[2*i]=d0; ald[2*i+1]=d1;
}

DI int edge_m(const int* mptr, int fixedm, int mcap){
  int m = mptr ? *mptr : fixedm;
  return m < mcap ? m : mcap;
}

__global__ __launch_bounds__(256) void k_edge_count(
    const int* __restrict__ de, const int* __restrict__ mptr,
    int fixedm, int mcap, int* __restrict__ cnt){
  int i = blockIdx.x*256 + threadIdx.x;
  if(i < edge_m(mptr,fixedm,mcap)) atomicAdd(&cnt[de[i]], 1);
}

__global__ __launch_bounds__(256) void k_scatter(
    const int* __restrict__ se, const int* __restrict__ de,
    const int* __restrict__ mptr, int fixedm, int mcap,
    int* __restrict__ cursor, int* __restrict__ eo){
  int i = blockIdx.x*256 + threadIdx.x;
  if(i < edge_m(mptr,fixedm,mcap)){
    int p = atomicAdd(&cursor[de[i]], 1);
    eo[p] = se[i];
  }
}

// block-aggregated stream compaction (one global atomic per block) with
// fused per-dst degree counting for the NEXT stage's CSR build.
__global__ __launch_bounds__(256) void k_edge_compact(
    const int* __restrict__ se, const int* __restrict__ de,
    const int* __restrict__ mptr, int fixedm, int mcap,
    const int* __restrict__ newid, int* __restrict__ ocnt,
    int* __restrict__ ons, int* __restrict__ ond, int ocap,
    int* __restrict__ cnt){
  __shared__ int wcnt[4];
  __shared__ int gbase;
  int tid = threadIdx.x;
  int i = blockIdx.x*256 + tid;
  int m = edge_m(mptr,fixedm,mcap);
  bool act = false; int a = 0, b = 0;
  if(i < m){
    a = newid[se[i]]; b = newid[de[i]];
    act = (a >= 0 && b >= 0);
  }
  unsigned long long mask = __ballot(act);
  int lane = tid & 63, w = tid >> 6;
  int rank = __popcll(mask & ((1ull << lane) - 1ull));
  if(lane == 0) wcnt[w] = __popcll(mask);
  __syncthreads();
  if(tid == 0){
    int t = wcnt[0] + wcnt[1] + wcnt[2] + wcnt[3];
    gbase = t ? atomicAdd(ocnt, t) : 0;
  }
  __syncthreads();
  if(act){
    int off = 0;
    for(int k = 0; k < w; k++) off += wcnt[k];
    int s = gbase + off + rank;
    if(s < ocap){ ons[s] = a; ond[s] = b; atomicAdd(&cnt[b], 1); }
  }
}

// ---- multi-block exclusive scan (3 dispatches). Replaces the single-block
// 88us latency-serialized k_scan from R4.
// part: 2048-elem tiles -> tile-local exclusive prefix + block sums
__global__ __launch_bounds__(256) void k_scan_part(
    const int* __restrict__ cnt, int n, int* __restrict__ pre,
    int* __restrict__ bsum){
  __shared__ int wsum[4];
  int tid = threadIdx.x, lane = tid & 63, w = tid >> 6;
  int base = blockIdx.x*2048 + tid*8;
  int v[8]; int s = 0;
#pragma unroll
  for(int j=0;j<8;j++){ int i = base+j; int x = (i<n)?cnt[i]:0; v[j]=s; s+=x; }
  int inc = s;
  for(int o=1;o<64;o<<=1){ int t=__shfl_up(inc,o,64); if(lane>=o) inc+=t; }
  if(lane==63) wsum[w]=inc;
  __syncthreads();
  int wb=0;
  for(int k=0;k<w;k++) wb+=wsum[k];
  int tb = wb + inc - s;
#pragma unroll
  for(int j=0;j<8;j++){ int i = base+j; if(i<n) pre[i]=tb+v[j]; }
  if(tid==255) bsum[blockIdx.x] = wb + inc;   // block total
}
// mid: exclusive-scan <=64 block sums in one wave; writes grand total to rowptr[n]
__global__ __launch_bounds__(64) void k_scan_mid(
    int* __restrict__ bsum, int nb, int* __restrict__ rowptr_n){
  int lane = threadIdx.x;
  int v = (lane<nb) ? bsum[lane] : 0;
  int inc = v;
  for(int o=1;o<64;o<<=1){ int t=__shfl_up(inc,o,64); if(lane>=o) inc+=t; }
  if(lane<nb) bsum[lane] = inc - v;
  if(lane==63) *rowptr_n = inc;
}
// add: apply block offsets; produce rowptr and cursor
__global__ __launch_bounds__(256) void k_scan_add(
    const int* __restrict__ pre, const int* __restrict__ bsum, int n,
    int* __restrict__ rowptr, int* __restrict__ cursor){
  int i = blockIdx.x*256 + threadIdx.x;
  if(i < n){
    int v = pre[i] + bsum[i >> 11];
    rowptr[i] = v; cursor[i] = v;
  }
}

// attention weights: one thread per (node,head). 2-pass max/exp over CSR
// edges; stores UNNORMALIZED edge weights (CSR-position-indexed), self
// weight, and denominator.
template<int H>
__global__ __launch_bounds__(256) void k_gat_w(
    const float* __restrict__ als, const float* __restrict__ ald,
    const int* __restrict__ rowptr, const int* __restrict__ esrc,
    float* __restrict__ wexp, float* __restrict__ wself,
    float* __restrict__ wden, int n){
  int t = blockIdx.x*256 + threadIdx.x;
  if(t >= n*H) return;
  int node = t / H, hh = t % H;
  float aldn = ald[node*H+hh];
  float es = lrelu(als[node*H+hh] + aldn);
  int r0 = rowptr[node], r1 = rowptr[node+1];
  float mx = es;
  for(int k=r0;k<r1;k++) mx = fmaxf(mx, lrelu(als[esrc[k]*H+hh] + aldn));
  float sw = expf(es - mx);
  float den = sw;
  for(int k=r0;k<r1;k++){
    float ex = expf(lrelu(als[esrc[k]*H+hh] + aldn) - mx);
    wexp[(size_t)k*H+hh] = ex;
    den += ex;
  }
  wself[node*H+hh] = sw;
  wden[node*H+hh] = den;
}

// weighted aggregate: thread = (node, 4-channel group). Inner loop per edge:
// 1 broadcast weight load + 1 float4 xp gather + 4 FMAs.
template<int H,int F>
__global__ __launch_bounds__(256) void k_gat_agg(
    const float* __restrict__ xp, const int* __restrict__ rowptr,
    const int* __restrict__ esrc, const float* __restrict__ wexp,
    const float* __restrict__ wself, const float* __restrict__ wden,
    const float* __restrict__ bias, float* __restrict__ out, int n){
  constexpr int C = H*F, C4 = C/4;
  int t = blockIdx.x*256 + threadIdx.x;
  int node = t / C4, p = t % C4;
  if(node >= n) return;
  int hh = (4*p) / F;
  const float4* xp4 = (const float4*)xp;
  float4 xs = xp4[(size_t)node*C4 + p];
  float sw = wself[node*H+hh];
  float ax = sw*xs.x, ay = sw*xs.y, az = sw*xs.z, aw_ = sw*xs.w;
  int r0 = rowptr[node], r1 = rowptr[node+1];
  for(int k=r0;k<r1;k++){
    int s = esrc[k];
    float wv = wexp[(size_t)k*H+hh];
    float4 v = xp4[(size_t)s*C4 + p];
    ax += wv*v.x; ay += wv*v.y; az += wv*v.z; aw_ += wv*v.w;
  }
  float inv = 1.f / wden[node*H+hh];
  const float4* b4 = (const float4*)bias;
  float4 bv = b4[p];
  float4 r; r.x = ax*inv + bv.x; r.y = ay*inv + bv.y;
  r.z = az*inv + bv.z; r.w = aw_*inv + bv.w;
  ((float4*)out)[(size_t)node*C4 + p] = r;
}

__global__ __launch_bounds__(256) void k_al(
    const float* __restrict__ xp, const float* __restrict__ a_s,
    const float* __restrict__ a_d, int n, int H, int F,
    float* __restrict__ als, float* __restrict__ ald){
  int i = blockIdx.x*256+threadIdx.x;
  if(i >= n*H) return;
  int node = i/H, hh = i%H;
  const float* row = xp + (size_t)node*H*F + hh*F;
  float s=0.f, d=0.f;
  for(int f=0;f<F;f++){ s += row[f]*a_s[hh*F+f]; d += row[f]*a_d[hh*F+f]; }
  als[i]=s; ald[i]=d;
}

__global__ __launch_bounds__(256) void k_inorm_stats(
    const float* __restrict__ x, int R, int C, int RS, float* __restrict__ accum){
  int g = blockIdx.x / RS, blk = blockIdx.x % RS;
  int NS = 256 / C;
  int c = threadIdx.x % C, rs = threadIdx.x / C;
  int chunk = (R + RS - 1)/RS;
  int rlo = blk*chunk, rhi = rlo+chunk; if(rhi>R) rhi=R;
  float s=0.f, sq=0.f;
  for(int r=rlo+rs; r<rhi; r+=NS){ float v = x[((size_t)g*R+r)*C + c]; s+=v; sq+=v*v; }
  atomicAdd(&accum[(g*C+c)*2], s);
  atomicAdd(&accum[(g*C+c)*2+1], sq);
}

__global__ __launch_bounds__(256) void k_inorm_apply(
    float* __restrict__ x, const float* __restrict__ accum, int R, int C, int total){
  int i = blockIdx.x*256+threadIdx.x;
  if(i>=total) return;
  int c = i % C; int g = i / (R*C);
  float s = accum[(g*C+c)*2], sq = accum[(g*C+c)*2+1];
  float mu = s / (float)R;
  float var = sq / (float)R - mu*mu; var = fmaxf(var, 0.f);
  float v = (x[i]-mu)*rsqrtf(var+1e-5f);
  x[i] = eluf(v);
}

__global__ __launch_bounds__(256) void k_score(
    const float* __restrict__ x, const float* __restrict__ p,
    int C, int n, float* __restrict__ score, unsigned* __restrict__ u){
  int i = blockIdx.x*256+threadIdx.x;
  if(i>=n) return;
  float a=0.f, nn=0.f;
  for(int c=0;c<C;c++){ float pv=p[c]; a += x[(size_t)i*C+c]*pv; nn += pv*pv; }
  float sv = tanhf(a/sqrtf(nn));
  score[i]=sv;
  unsigned bts = __float_as_uint(sv);
  u[i] = (bts & 0x80000000u) ? ~bts : (bts | 0x80000000u);
}

// per-graph 3-level radix select on orderable uints: exact k-th value + #ties needed
__global__ __launch_bounds__(1024) void k_select(
    const unsigned* __restrict__ u, int R, int Ksel,
    unsigned* __restrict__ thr_out, int* __restrict__ need_out){
  __shared__ int hist[2048];
  __shared__ int seg[32];
  __shared__ int sh_b, sh_k;
  int g = blockIdx.x, tid = threadIdx.x;
  const unsigned* ug = u + (size_t)g*R;
  unsigned prefix = 0;
  int K = Ksel;
  for(int lev=0; lev<3; lev++){
    int shf = (lev==0)?21:((lev==1)?10:0);
    int nb  = (lev==2)?1024:2048;
    for(int i=tid;i<2048;i+=1024) hist[i]=0;
    __syncthreads();
    for(int i=tid;i<R;i+=1024){
      unsigned v = ug[i];
      bool ok = (lev==0) || (lev==1 && (v>>21)==prefix) || (lev==2 && (v>>10)==prefix);
      if(ok) atomicAdd(&hist[(v>>shf)&(nb-1)], 1);
    }
    __syncthreads();
    int W = nb/32;
    if(tid<32){ int s=0; int lo=nb-W*(tid+1); for(int b=lo;b<lo+W;b++) s+=hist[b]; seg[tid]=s; }
    __syncthreads();
    if(tid==0){
      int kk=K, sgi=0;
      while(seg[sgi]<kk){ kk-=seg[sgi]; sgi++; }
      int b = nb-1-W*sgi;
      while(hist[b]<kk){ kk-=hist[b]; b--; }
      sh_b=b; sh_k=kk;
    }
    __syncthreads();
    int b = sh_b; K = sh_k;
    if(lev==0) prefix = (unsigned)b;
    else if(lev==1) prefix = (prefix<<11) | (unsigned)b;
    else prefix = (prefix<<10) | (unsigned)b;
    __syncthreads();
  }
  if(tid==0){ thr_out[g]=prefix; need_out[g]=K; }
}

// deterministic compaction: take u>thr plus lowest-index u==thr (matches lax.top_k ties)
__global__ __launch_bounds__(1024) void k_compact(
    const unsigned* __restrict__ u, const float* __restrict__ score,
    const unsigned* __restrict__ thr_arr, const int* __restrict__ need_arr,
    int R, int Kout, int* __restrict__ newid, int* __restrict__ oldid,
    float* __restrict__ scale){
  __shared__ int wsA[16], wsB[16];
  __shared__ int carr0, carr1;
  int g = blockIdx.x, tid = threadIdx.x, lane = tid&63, w = tid>>6;
  unsigned thr = thr_arr[g]; int need = need_arr[g];
  if(tid==0){ carr0=0; carr1=0; }
  __syncthreads();
  for(int bb=0; bb<R; bb+=1024){
    int i = bb + tid; bool in = i < R;
    unsigned uv = in ? u[(size_t)g*R+i] : 0u;
    int eq = (in && uv==thr) ? 1:0;
    int gt = (in && uv>thr) ? 1:0;
    int inc = eq;
    for(int o=1;o<64;o<<=1){ int t=__shfl_up(inc,o,64); if(lane>=o) inc+=t; }
    if(lane==63) wsA[w]=inc;
    __syncthreads();
    int wb=0; for(int k=0;k<w;k++) wb+=wsA[k];
    int eq_excl = carr0 + wb + inc - eq;
    int take = (gt || (eq && eq_excl<need)) ? 1 : 0;
    int inc2 = take;
    for(int o=1;o<64;o<<=1){ int t=__shfl_up(inc2,o,64); if(lane>=o) inc2+=t; }
    if(lane==63) wsB[w]=inc2;
    __syncthreads();
    int wb2=0; for(int k=0;k<w;k++) wb2+=wsB[k];
    int pos = carr1 + wb2 + inc2 - take;
    if(take){
      int nr = g*Kout + pos;
      newid[(size_t)g*R+i] = nr;
      oldid[nr] = g*R+i;
      scale[nr] = score[(size_t)g*R+i];
    }
    __syncthreads();
    if(tid==1023){ carr0 += wb + inc; carr1 += wb2 + inc2; }
    __syncthreads();
  }
}

__global__ __launch_bounds__(256) void k_pool_gather(
    const float* __restrict__ x, const int* __restrict__ oldid,
    const float* __restrict__ scale, int C, int total, float* __restrict__ xnew){
  int i = blockIdx.x*256+threadIdx.x;
  if(i>=total) return;
  int r = i / C, c = i % C;
  xnew[i] = x[(size_t)oldid[r]*C + c] * scale[r];
}

// dense row-GEMM: block = 256 threads = (256/CO subgroups) x CO channels
template<int K,int CO,int NPG,bool DOELU>
__global__ __launch_bounds__(256) void k_gemm(
    const float* __restrict__ X, const float* __restrict__ W,
    const float* __restrict__ bias, float* __restrict__ Y, int n){
  constexpr int SUB = 256/CO;
  constexpr int NB = SUB*NPG;
  __shared__ float xs[NB][K];
  int tid = threadIdx.x;
  int c = tid % CO, sg = tid / CO;
  int n0 = blockIdx.x * NB;
  for(int idx=tid; idx<NB*K; idx+=256){
    int r = idx / K, k = idx % K;
    int row = n0 + r;
    xs[r][k] = (row < n) ? X[(size_t)row*K + k] : 0.f;
  }
  __syncthreads();
  float acc[NPG];
#pragma unroll
  for(int q=0;q<NPG;q++) acc[q]=0.f;
  for(int k=0;k<K;k++){
    float wv = W[(size_t)k*CO + c];
#pragma unroll
    for(int q=0;q<NPG;q++) acc[q] += xs[sg*NPG+q][k]*wv;
  }
  float bv = bias ? bias[c] : 0.f;
#pragma unroll
  for(int q=0;q<NPG;q++){
    int row = n0 + sg*NPG + q;
    if(row < n){
      float v = acc[q] + bv;
      if(DOELU) v = eluf(v);
      Y[(size_t)row*CO + c] = v;
    }
  }
}

// tiny-n tail MLP: compile-time K fully pipelined
template<int K,int CO,int ACT>
__global__ __launch_bounds__(256) void k_mlp_t(
    const float* __restrict__ X, const float* __restrict__ W,
    const float* __restrict__ b, float* __restrict__ Y, int n){
  int i = blockIdx.x*256+threadIdx.x;
  if(i>=n*CO) return;
  int r=i/CO, c=i%CO;
  const float* xr = X + (size_t)r*K;
  float a=0.f;
#pragma unroll 16
  for(int k=0;k<K;k++) a = fmaf(xr[k], W[(size_t)k*CO+c], a);
  a += b[c];
  if(ACT) a = eluf(a);
  Y[i]=a;
}

// gate scalar: wave per row, 64 lanes over K=64, coalesced + shuffle reduce
__global__ __launch_bounds__(256) void k_gatev(
    const float* __restrict__ gateb, const float* __restrict__ gw2,
    const float* __restrict__ gb2, float* __restrict__ gatev, int n){
  int wv = (blockIdx.x*256 + threadIdx.x) >> 6;
  int lane = threadIdx.x & 63;
  if(wv >= n) return;
  float v = gateb[(size_t)wv*64 + lane] * gw2[lane];
#pragma unroll
  for(int o=32;o>0;o>>=1) v += __shfl_down(v, o, 64);
  if(lane==0) gatev[wv] = v + gb2[0];
}

// per-graph softmax over gate scalars -> normalized probs
__global__ __launch_bounds__(256) void k_attn_probs(
    const float* __restrict__ gate, float* __restrict__ prob){
  __shared__ float red[256];
  int g = blockIdx.x, tid = threadIdx.x;
  float mx = -1e30f;
  for(int r=tid;r<KP2;r+=256) mx = fmaxf(mx, gate[g*KP2+r]);
  red[tid]=mx; __syncthreads();
  for(int s=128;s>0;s>>=1){ if(tid<s) red[tid]=fmaxf(red[tid],red[tid+s]); __syncthreads(); }
  mx = red[0]; __syncthreads();
  float sm=0.f;
  for(int r=tid;r<KP2;r+=256) sm += expf(gate[g*KP2+r]-mx);
  red[tid]=sm; __syncthreads();
  for(int s=128;s>0;s>>=1){ if(tid<s) red[tid]+=red[tid+s]; __syncthreads(); }
  float inv = 1.f/red[0];
  for(int r=tid;r<KP2;r+=256) prob[g*KP2+r] = expf(gate[g*KP2+r]-mx)*inv;
}

// weighted sum: grid (graph, r-chunk); block partial atomicAdd into zeroed gvec
__global__ __launch_bounds__(256) void k_attn_acc(
    const float* __restrict__ prob, const float* __restrict__ h,
    float* __restrict__ gvec, int RS){
  int g = blockIdx.x, blk = blockIdx.y, c = threadIdx.x;
  int chunk = (KP2 + RS - 1)/RS;
  int rlo = blk*chunk, rhi = rlo+chunk; if(rhi>KP2) rhi=KP2;
  float acc = 0.f;
#pragma unroll 4
  for(int r=rlo; r<rhi; r++)
    acc += prob[g*KP2+r] * h[((size_t)g*KP2+r)*256 + c];
  atomicAdd(&gvec[g*256+c], acc);
}

__global__ __launch_bounds__(64) void k_head(
    const float* __restrict__ z2, const float* __restrict__ w3,
    const float* __restrict__ b3, float* __restrict__ out){
  __shared__ float zc[10]; __shared__ float mred, sred;
  int g=blockIdx.x, tid=threadIdx.x;
  if(tid<10){
    float a=0.f;
#pragma unroll 16
    for(int k=0;k<128;k++) a += z2[g*128+k]*w3[k*10+tid];
    zc[tid]=a+b3[tid];
  }
  __syncthreads();
  if(tid==0){
    float m=zc[0];
    for(int k=1;k<10;k++) m=fmaxf(m,zc[k]);
    float s=0.f;
    for(int k=0;k<10;k++) s+=expf(zc[k]-m);
    mred=m; sred=logf(s);
  }
  __syncthreads();
  if(tid<10) out[g*10+tid]=zc[tid]-mred-sred;
}

} // namespace pk

extern "C" void kernel_launch(void* const* d_in, const int* in_sizes, int n_in,
                              void* d_out, int out_size, void* d_ws, size_t ws_size,
                              hipStream_t stream){
  using namespace pk;
  (void)in_sizes; (void)n_in; (void)out_size;
  const float* pos = (const float*)d_in[0];
  const int*   src = (const int*)d_in[1];
  const int*   dst = (const int*)d_in[2];
  const float* W1  = (const float*)d_in[3];
  const float* as1 = (const float*)d_in[4];
  const float* ad1 = (const float*)d_in[5];
  const float* b1  = (const float*)d_in[6];
  const float* p1  = (const float*)d_in[7];
  const float* W2  = (const float*)d_in[8];
  const float* as2 = (const float*)d_in[9];
  const float* ad2 = (const float*)d_in[10];
  const float* b2  = (const float*)d_in[11];
  const float* p2  = (const float*)d_in[12];
  const float* W3  = (const float*)d_in[13];
  const float* as3 = (const float*)d_in[14];
  const float* ad3 = (const float*)d_in[15];
  const float* b3  = (const float*)d_in[16];
  const float* gw1 = (const float*)d_in[17];
  const float* gb1 = (const float*)d_in[18];
  const float* gw2 = (const float*)d_in[19];
  const float* gb2 = (const float*)d_in[20];
  const float* aw  = (const float*)d_in[21];
  const float* ab  = (const float*)d_in[22];
  const float* w1  = (const float*)d_in[23];
  const float* bb1 = (const float*)d_in[24];
  const float* w2  = (const float*)d_in[25];
  const float* bb2 = (const float*)d_in[26];
  const float* w3  = (const float*)d_in[27];
  const float* bb3 = (const float*)d_in[28];
  float* out = (float*)d_out;

  char* base = (char*)d_ws; size_t off = 0;
  auto alloc = [&](size_t nbytes)->char*{
    char* p = base + off; off = (off + nbytes + 255) & ~(size_t)255; return p;
  };
  // --- zero-init region (one memset) ---
  int*   cnt1  = (int*)alloc((size_t)NB1*4);
  int*   cnt2  = (int*)alloc((size_t)NN2*4);
  int*   cnt3  = (int*)alloc((size_t)NN3*4);
  int*   ecnt2 = (int*)alloc(4);
  int*   ecnt3 = (int*)alloc(4);
  float* acc1  = (float*)alloc((size_t)BG*32*2*4);
  float* acc2  = (float*)alloc((size_t)BG*128*2*4);
  float* acc3  = (float*)alloc((size_t)BG*256*2*4);
  float* gvec  = (float*)alloc((size_t)BG*256*4);
  size_t zend = off;
  // --- 0xFF-init region (newid = -1, one memset) ---
  int*   newid1 = (int*)alloc((size_t)NB1*4);
  int*   newid2 = (int*)alloc((size_t)NN2*4);
  size_t fstart = (size_t)((char*)newid1 - base);
  size_t fend = off;
  // --- plain scratch ---
  int*      bsum   = (int*)alloc((size_t)64*4);
  float*    xp1    = (float*)alloc((size_t)NB1*32*4);
  float*    als1   = (float*)alloc((size_t)NB1*2*4);
  float*    ald1   = (float*)alloc((size_t)NB1*2*4);
  int*      rowptr1= (int*)alloc((size_t)(NB1+1)*4);
  int*      cursor1= (int*)alloc((size_t)NB1*4);
  int*      esrc1  = (int*)alloc((size_t)NE*4);
  float*    wexp1  = (float*)alloc((size_t)NE*2*4);
  float*    wself1 = (float*)alloc((size_t)NB1*2*4);
  float*    wden1  = (float*)alloc((size_t)NB1*2*4);
  float*    out1   = (float*)alloc((size_t)NB1*32*4);
  float*    score1 = (float*)alloc((size_t)NB1*4);
  unsigned* u1     = (unsigned*)alloc((size_t)NB1*4);
  unsigned* thr1   = (unsigned*)alloc((size_t)BG*4);
  int*      need1  = (int*)alloc((size_t)BG*4);
  int*      oldid1 = (int*)alloc((size_t)NN2*4);
  float*    scale1 = (float*)alloc((size_t)NN2*4);
  float*    xnew1  = (float*)alloc((size_t)NN2*32*4);
  int*      ns2    = (int*)alloc((size_t)CAP2*4);
  int*      nd2    = (int*)alloc((size_t)CAP2*4);
  int*      rowptr2= (int*)alloc((size_t)(NN2+1)*4);
  int*      cursor2= (int*)alloc((size_t)NN2*4);
  int*      esrc2  = (int*)alloc((size_t)CAP2*4);
  float*    wexp2  = (float*)alloc((size_t)CAP2*2*4);
  float*    wself2 = (float*)alloc((size_t)NN2*2*4);
  float*    wden2  = (float*)alloc((size_t)NN2*2*4);
  float*    xp2    = (float*)alloc((size_t)NN2*128*4);
  float*    als2   = (float*)alloc((size_t)NN2*2*4);
  float*    ald2   = (float*)alloc((size_t)NN2*2*4);
  float*    out2   = (float*)alloc((size_t)NN2*128*4);
  float*    score2 = (float*)alloc((size_t)NN2*4);
  unsigned* u2     = (unsigned*)alloc((size_t)NN2*4);
  unsigned* thr2   = (unsigned*)alloc((size_t)BG*4);
  int*      need2  = (int*)alloc((size_t)BG*4);
  int*      oldid2 = (int*)alloc((size_t)NN3*4);
  float*    scale2 = (float*)alloc((size_t)NN3*4);
  float*    xnew2  = (float*)alloc((size_t)NN3*128*4);
  int*      ns3    = (int*)alloc((size_t)CAP3*4);
  int*      nd3    = (int*)alloc((size_t)CAP3*4);
  int*      rowptr3= (int*)alloc((size_t)(NN3+1)*4);
  int*      cursor3= (int*)alloc((size_t)NN3*4);
  int*      esrc3  = (int*)alloc((size_t)CAP3*4);
  float*    wexp3  = (float*)alloc((size_t)CAP3*4);
  float*    wself3 = (float*)alloc((size_t)NN3*4);
  float*    wden3  = (float*)alloc((size_t)NN3*4);
  float*    xp3    = (float*)alloc((size_t)NN3*256*4);
  float*    als3   = (float*)alloc((size_t)NN3*4);
  float*    ald3   = (float*)alloc((size_t)NN3*4);
  float*    out3   = (float*)alloc((size_t)NN3*256*4);
  float*    gateb  = (float*)alloc((size_t)NN3*64*4);
  float*    gatev  = (float*)alloc((size_t)NN3*4);
  float*    probs  = (float*)alloc((size_t)NN3*4);
  float*    hbuf   = (float*)alloc((size_t)NN3*256*4);
  float*    z1     = (float*)alloc((size_t)BG*512*4);
  float*    z2     = (float*)alloc((size_t)BG*128*4);
  if(off > ws_size) return;  // workspace too small: fail visibly

  auto cdiv = [](int a, int b){ return (a+b-1)/b; };
  // 3-dispatch multi-block exclusive scan: cnt[0..n) -> rowptr[0..n], cursor
  auto scan3 = [&](const int* cnt, int n, int* rowptr, int* cursor){
    int nb = cdiv(n, 2048);
    k_scan_part<<<nb,256,0,stream>>>(cnt, n, rowptr, bsum);
    k_scan_mid<<<1,64,0,stream>>>(bsum, nb, rowptr + n);
    k_scan_add<<<cdiv(n,256),256,0,stream>>>(rowptr, bsum, n, rowptr, cursor);
  };

  hipMemsetAsync(base, 0, zend, stream);
  hipMemsetAsync(base + fstart, 0xFF, fend - fstart, stream);

  // ---------------- stage 1: GAT(3->32, H=2,F=16) ----------------
  k_xp1<<<cdiv(NB1,256),256,0,stream>>>(pos,W1,as1,ad1,xp1,als1,ald1);
  k_edge_count<<<cdiv(NE,256),256,0,stream>>>(dst,nullptr,NE,NE,cnt1);
  scan3(cnt1,NB1,rowptr1,cursor1);
  k_scatter<<<cdiv(NE,256),256,0,stream>>>(src,dst,nullptr,NE,NE,cursor1,esrc1);
  k_gat_w<2><<<cdiv(NB1*2,256),256,0,stream>>>(als1,ald1,rowptr1,esrc1,wexp1,wself1,wden1,NB1);
  k_gat_agg<2,16><<<cdiv(NB1*8,256),256,0,stream>>>(xp1,rowptr1,esrc1,wexp1,wself1,wden1,b1,out1,NB1);
  k_inorm_stats<<<BG*16,256,0,stream>>>(out1,8192,32,16,acc1);
  k_inorm_apply<<<cdiv(NB1*32,256),256,0,stream>>>(out1,acc1,8192,32,NB1*32);
  // ---------------- pool 1 (k=2458) ----------------
  k_score<<<cdiv(NB1,256),256,0,stream>>>(out1,p1,32,NB1,score1,u1);
  k_select<<<BG,1024,0,stream>>>(u1,8192,KP1,thr1,need1);
  k_compact<<<BG,1024,0,stream>>>(u1,score1,thr1,need1,8192,KP1,newid1,oldid1,scale1);
  k_pool_gather<<<cdiv(NN2*32,256),256,0,stream>>>(out1,oldid1,scale1,32,NN2*32,xnew1);
  k_edge_compact<<<cdiv(NE,256),256,0,stream>>>(src,dst,nullptr,NE,NE,newid1,ecnt2,ns2,nd2,CAP2,cnt2);
  // ---------------- stage 2: GAT(32->128, H=2,F=64) ----------------
  scan3(cnt2,NN2,rowptr2,cursor2);
  k_scatter<<<cdiv(CAP2,256),256,0,stream>>>(ns2,nd2,ecnt2,0,CAP2,cursor2,esrc2);
  k_gemm<32,128,4,false><<<cdiv(NN2,8),256,0,stream>>>(xnew1,W2,nullptr,xp2,NN2);
  k_al<<<cdiv(NN2*2,256),256,0,stream>>>(xp2,as2,ad2,NN2,2,64,als2,ald2);
  k_gat_w<2><<<cdiv(NN2*2,256),256,0,stream>>>(als2,ald2,rowptr2,esrc2,wexp2,wself2,wden2,NN2);
  k_gat_agg<2,64><<<cdiv(NN2*32,256),256,0,stream>>>(xp2,rowptr2,esrc2,wexp2,wself2,wden2,b2,out2,NN2);
  k_inorm_stats<<<BG*16,256,0,stream>>>(out2,KP1,128,16,acc2);
  k_inorm_apply<<<cdiv(NN2*128,256),256,0,stream>>>(out2,acc2,KP1,128,NN2*128);
  // ---------------- pool 2 (k=738) ----------------
  k_score<<<cdiv(NN2,256),256,0,stream>>>(out2,p2,128,NN2,score2,u2);
  k_select<<<BG,1024,0,stream>>>(u2,KP1,KP2,thr2,need2);
  k_compact<<<BG,1024,0,stream>>>(u2,score2,thr2,need2,KP1,KP2,newid2,oldid2,scale2);
  k_pool_gather<<<cdiv(NN3*128,256),256,0,stream>>>(out2,oldid2,scale2,128,NN3*128,xnew2);
  k_edge_compact<<<cdiv(CAP2,256),256,0,stream>>>(ns2,nd2,ecnt2,0,CAP2,newid2,ecnt3,ns3,nd3,CAP3,cnt3);
  // ---------------- stage 3: GAT(128->256, H=1,F=256) ----------------
  scan3(cnt3,NN3,rowptr3,cursor3);
  k_scatter<<<cdiv(CAP3,256),256,0,stream>>>(ns3,nd3,ecnt3,0,CAP3,cursor3,esrc3);
  k_gemm<128,256,4,false><<<cdiv(NN3,4),256,0,stream>>>(xnew2,W3,nullptr,xp3,NN3);
  k_al<<<cdiv(NN3,256),256,0,stream>>>(xp3,as3,ad3,NN3,1,256,als3,ald3);
  k_gat_w<1><<<cdiv(NN3,256),256,0,stream>>>(als3,ald3,rowptr3,esrc3,wexp3,wself3,wden3,NN3);
  k_gat_agg<1,256><<<cdiv(NN3*64,256),256,0,stream>>>(xp3,rowptr3,esrc3,wexp3,wself3,wden3,b3,out3,NN3);
  k_inorm_stats<<<BG*8,256,0,stream>>>(out3,KP2,256,8,acc3);
  k_inorm_apply<<<cdiv(NN3*256,256),256,0,stream>>>(out3,acc3,KP2,256,NN3*256);
  // ---------------- global attention + MLP head ----------------
  k_gemm<256,64,2,true><<<cdiv(NN3,8),256,0,stream>>>(out3,gw1,gb1,gateb,NN3);
  k_gatev<<<cdiv(NN3,4),256,0,stream>>>(gateb,gw2,gb2,gatev,NN3);
  k_gemm<256,256,4,true><<<cdiv(NN3,4),256,0,stream>>>(out3,aw,ab,hbuf,NN3);
  k_attn_probs<<<BG,256,0,stream>>>(gatev,probs);
  k_attn_acc<<<dim3(BG,24),256,0,stream>>>(probs,hbuf,gvec,24);
  k_mlp_t<256,512,1><<<cdiv(BG*512,256),256,0,stream>>>(gvec,w1,bb1,z1,BG);
  k_mlp_t<512,128,1><<<cdiv(BG*128,256),256,0,stream>>>(z1,w2,bb2,z2,BG);
  k_head<<<BG,64,0,stream>>>(z2,w3,bb3,out);
}

// Round 6
// 697.370 us; speedup vs baseline: 1.7445x; 1.0263x over previous
//
#include <hip/hip_runtime.h>
#include <cstdint>
#include <cstddef>

#define DI __device__ __forceinline__

namespace pk {

constexpr int NB1 = 65536;      // stage-1 nodes (B*N)
constexpr int NE  = 1048576;    // edges (B*N*DEG)
constexpr int BG  = 8;          // graphs
constexpr int KP1 = 2458;       // top-k 1
constexpr int KP2 = 738;        // top-k 2
constexpr int NN2 = BG*KP1;     // 19664
constexpr int NN3 = BG*KP2;     // 5904
constexpr int CAP2 = 524288;    // edge-buffer cap after pool1 (expected ~94K)
constexpr int CAP3 = 131072;    // edge-buffer cap after pool2 (expected ~8.5K)

DI float lrelu(float x){ return x > 0.f ? x : 0.2f*x; }
DI float eluf(float x){ return x > 0.f ? x : expf(x) - 1.f; }

// XCD-affinity swizzle: blocks dispatch round-robin over 8 XCDs (b%8).
// Remap so XCD x handles a CONTIGUOUS 1/8 of the grid -> with 8 graphs,
// XCD x owns graph x: scatter/gather working sets stay in its private L2.
// Perf heuristic only — correctness unaffected if mapping differs.
DI int swz_block(){
  int nb = gridDim.x, b = blockIdx.x;
  if((nb & 7) == 0) return (b & 7)*(nb >> 3) + (b >> 3);
  return b;
}

// ---- stage-1 projection: xp = pos @ W1 (K=3), plus attention logits per head
__global__ __launch_bounds__(256) void k_xp1(
    const float* __restrict__ pos, const float* __restrict__ W,
    const float* __restrict__ as_, const float* __restrict__ ad_,
    float* __restrict__ xp, float* __restrict__ als, float* __restrict__ ald){
  int i = blockIdx.x*256 + threadIdx.x;
  if(i >= NB1) return;
  float p0=pos[3*i], p1=pos[3*i+1], p2=pos[3*i+2];
  float row[32];
#pragma unroll
  for(int c=0;c<32;c++) row[c] = p0*W[c] + p1*W[32+c] + p2*W[64+c];
  float s0=0.f,d0=0.f,s1=0.f,d1=0.f;
#pragma unroll
  for(int f=0;f<16;f++){
    s0 += row[f]*as_[f];        d0 += row[f]*ad_[f];
    s1 += row[16+f]*as_[16+f];  d1 += row[16+f]*ad_[16+f];
  }
  float4* o = reinterpret_cast<float4*>(xp + (size_t)i*32);
#pragma unroll
  for(int q=0;q<8;q++) o[q] = make_float4(row[4*q],row[4*q+1],row[4*q+2],row[4*q+3]);
  als[2*i]=s0; als[2*i+1]=s1; ald[2*i]=d0; ald[2*i+1]=d1;
}

DI int edge_m(const int* mptr, int fixedm, int mcap){
  int m = mptr ? *mptr : fixedm;
  return m < mcap ? m : mcap;
}

__global__ __launch_bounds__(256) void k_edge_count(
    const int* __restrict__ de, const int* __restrict__ mptr,
    int fixedm, int mcap, int* __restrict__ cnt){
  int i = blockIdx.x*256 + threadIdx.x;
  if(i < edge_m(mptr,fixedm,mcap)) atomicAdd(&cnt[de[i]], 1);
}

// CSR scatter with XCD-affinity swizzle: fixes R5's 13x write amplification
// (WRITE_SIZE 53MB for 4MB payload — same esrc line dirtied from many XCDs).
__global__ __launch_bounds__(256) void k_scatter(
    const int* __restrict__ se, const int* __restrict__ de,
    const int* __restrict__ mptr, int fixedm, int mcap,
    int* __restrict__ cursor, int* __restrict__ eo){
  int i = swz_block()*256 + threadIdx.x;
  if(i < edge_m(mptr,fixedm,mcap)){
    int p = atomicAdd(&cursor[de[i]], 1);
    eo[p] = se[i];
  }
}

// block-aggregated stream compaction (one global atomic per block) with
// fused per-dst degree counting for the NEXT stage's CSR build.
__global__ __launch_bounds__(256) void k_edge_compact(
    const int* __restrict__ se, const int* __restrict__ de,
    const int* __restrict__ mptr, int fixedm, int mcap,
    const int* __restrict__ newid, int* __restrict__ ocnt,
    int* __restrict__ ons, int* __restrict__ ond, int ocap,
    int* __restrict__ cnt){
  __shared__ int wcnt[4];
  __shared__ int gbase;
  int tid = threadIdx.x;
  int i = blockIdx.x*256 + tid;
  int m = edge_m(mptr,fixedm,mcap);
  bool act = false; int a = 0, b = 0;
  if(i < m){
    a = newid[se[i]]; b = newid[de[i]];
    act = (a >= 0 && b >= 0);
  }
  unsigned long long mask = __ballot(act);
  int lane = tid & 63, w = tid >> 6;
  int rank = __popcll(mask & ((1ull << lane) - 1ull));
  if(lane == 0) wcnt[w] = __popcll(mask);
  __syncthreads();
  if(tid == 0){
    int t = wcnt[0] + wcnt[1] + wcnt[2] + wcnt[3];
    gbase = t ? atomicAdd(ocnt, t) : 0;
  }
  __syncthreads();
  if(act){
    int off = 0;
    for(int k = 0; k < w; k++) off += wcnt[k];
    int s = gbase + off + rank;
    if(s < ocap){ ons[s] = a; ond[s] = b; atomicAdd(&cnt[b], 1); }
  }
}

// ---- multi-block exclusive scan (3 dispatches)
__global__ __launch_bounds__(256) void k_scan_part(
    const int* __restrict__ cnt, int n, int* __restrict__ pre,
    int* __restrict__ bsum){
  __shared__ int wsum[4];
  int tid = threadIdx.x, lane = tid & 63, w = tid >> 6;
  int base = blockIdx.x*2048 + tid*8;
  int v[8]; int s = 0;
#pragma unroll
  for(int j=0;j<8;j++){ int i = base+j; int x = (i<n)?cnt[i]:0; v[j]=s; s+=x; }
  int inc = s;
  for(int o=1;o<64;o<<=1){ int t=__shfl_up(inc,o,64); if(lane>=o) inc+=t; }
  if(lane==63) wsum[w]=inc;
  __syncthreads();
  int wb=0;
  for(int k=0;k<w;k++) wb+=wsum[k];
  int tb = wb + inc - s;
#pragma unroll
  for(int j=0;j<8;j++){ int i = base+j; if(i<n) pre[i]=tb+v[j]; }
  if(tid==255) bsum[blockIdx.x] = wb + inc;   // block total
}
__global__ __launch_bounds__(64) void k_scan_mid(
    int* __restrict__ bsum, int nb, int* __restrict__ rowptr_n){
  int lane = threadIdx.x;
  int v = (lane<nb) ? bsum[lane] : 0;
  int inc = v;
  for(int o=1;o<64;o<<=1){ int t=__shfl_up(inc,o,64); if(lane>=o) inc+=t; }
  if(lane<nb) bsum[lane] = inc - v;
  if(lane==63) *rowptr_n = inc;
}
__global__ __launch_bounds__(256) void k_scan_add(
    const int* __restrict__ pre, const int* __restrict__ bsum, int n,
    int* __restrict__ rowptr, int* __restrict__ cursor){
  int i = blockIdx.x*256 + threadIdx.x;
  if(i < n){
    int v = pre[i] + bsum[i >> 11];
    rowptr[i] = v; cursor[i] = v;
  }
}

// attention weights, SINGLE pass (no max-subtraction: logits bounded ~|25|,
// exp safe in fp32; the max factor cancels in the normalized weights).
// Stores UNNORMALIZED edge weights (CSR-position-indexed), self weight, den.
template<int H>
__global__ __launch_bounds__(256) void k_gat_w(
    const float* __restrict__ als, const float* __restrict__ ald,
    const int* __restrict__ rowptr, const int* __restrict__ esrc,
    float* __restrict__ wexp, float* __restrict__ wself,
    float* __restrict__ wden, int n){
  int t = swz_block()*256 + threadIdx.x;
  if(t >= n*H) return;
  int node = t / H, hh = t % H;
  float aldn = ald[node*H+hh];
  float sw = expf(lrelu(als[node*H+hh] + aldn));
  float den = sw;
  int r0 = rowptr[node], r1 = rowptr[node+1];
  for(int k=r0;k<r1;k++){
    float ex = expf(lrelu(als[esrc[k]*H+hh] + aldn));
    wexp[(size_t)k*H+hh] = ex;
    den += ex;
  }
  wself[node*H+hh] = sw;
  wden[node*H+hh] = den;
}

// weighted aggregate: thread = (node, 4-channel group). Inner loop per edge:
// 1 broadcast weight load + 1 float4 xp gather + 4 FMAs.
template<int H,int F>
__global__ __launch_bounds__(256) void k_gat_agg(
    const float* __restrict__ xp, const int* __restrict__ rowptr,
    const int* __restrict__ esrc, const float* __restrict__ wexp,
    const float* __restrict__ wself, const float* __restrict__ wden,
    const float* __restrict__ bias, float* __restrict__ out, int n){
  constexpr int C = H*F, C4 = C/4;
  int t = swz_block()*256 + threadIdx.x;
  int node = t / C4, p = t % C4;
  if(node >= n) return;
  int hh = (4*p) / F;
  const float4* xp4 = (const float4*)xp;
  float4 xs = xp4[(size_t)node*C4 + p];
  float sw = wself[node*H+hh];
  float ax = sw*xs.x, ay = sw*xs.y, az = sw*xs.z, aw_ = sw*xs.w;
  int r0 = rowptr[node], r1 = rowptr[node+1];
  for(int k=r0;k<r1;k++){
    int s = esrc[k];
    float wv = wexp[(size_t)k*H+hh];
    float4 v = xp4[(size_t)s*C4 + p];
    ax += wv*v.x; ay += wv*v.y; az += wv*v.z; aw_ += wv*v.w;
  }
  float inv = 1.f / wden[node*H+hh];
  const float4* b4 = (const float4*)bias;
  float4 bv = b4[p];
  float4 r; r.x = ax*inv + bv.x; r.y = ay*inv + bv.y;
  r.z = az*inv + bv.z; r.w = aw_*inv + bv.w;
  ((float4*)out)[(size_t)node*C4 + p] = r;
}

__global__ __launch_bounds__(256) void k_al(
    const float* __restrict__ xp, const float* __restrict__ a_s,
    const float* __restrict__ a_d, int n, int H, int F,
    float* __restrict__ als, float* __restrict__ ald){
  int i = blockIdx.x*256+threadIdx.x;
  if(i >= n*H) return;
  int node = i/H, hh = i%H;
  const float* row = xp + (size_t)node*H*F + hh*F;
  float s=0.f, d=0.f;
  for(int f=0;f<F;f++){ s += row[f]*a_s[hh*F+f]; d += row[f]*a_d[hh*F+f]; }
  als[i]=s; ald[i]=d;
}

__global__ __launch_bounds__(256) void k_inorm_stats(
    const float* __restrict__ x, int R, int C, int RS, float* __restrict__ accum){
  int g = blockIdx.x / RS, blk = blockIdx.x % RS;
  int NS = 256 / C;
  int c = threadIdx.x % C, rs = threadIdx.x / C;
  int chunk = (R + RS - 1)/RS;
  int rlo = blk*chunk, rhi = rlo+chunk; if(rhi>R) rhi=R;
  float s=0.f, sq=0.f;
  for(int r=rlo+rs; r<rhi; r+=NS){ float v = x[((size_t)g*R+r)*C + c]; s+=v; sq+=v*v; }
  atomicAdd(&accum[(g*C+c)*2], s);
  atomicAdd(&accum[(g*C+c)*2+1], sq);
}

__global__ __launch_bounds__(256) void k_inorm_apply(
    float* __restrict__ x, const float* __restrict__ accum, int R, int C, int total){
  int i = blockIdx.x*256+threadIdx.x;
  if(i>=total) return;
  int c = i % C; int g = i / (R*C);
  float s = accum[(g*C+c)*2], sq = accum[(g*C+c)*2+1];
  float mu = s / (float)R;
  float var = sq / (float)R - mu*mu; var = fmaxf(var, 0.f);
  float v = (x[i]-mu)*rsqrtf(var+1e-5f);
  x[i] = eluf(v);
}

__global__ __launch_bounds__(256) void k_score(
    const float* __restrict__ x, const float* __restrict__ p,
    int C, int n, float* __restrict__ score, unsigned* __restrict__ u){
  int i = blockIdx.x*256+threadIdx.x;
  if(i>=n) return;
  float a=0.f, nn=0.f;
  for(int c=0;c<C;c++){ float pv=p[c]; a += x[(size_t)i*C+c]*pv; nn += pv*pv; }
  float sv = tanhf(a/sqrtf(nn));
  score[i]=sv;
  unsigned bts = __float_as_uint(sv);
  u[i] = (bts & 0x80000000u) ? ~bts : (bts | 0x80000000u);
}

// per-graph 3-level radix select on orderable uints: exact k-th value + #ties needed
__global__ __launch_bounds__(1024) void k_select(
    const unsigned* __restrict__ u, int R, int Ksel,
    unsigned* __restrict__ thr_out, int* __restrict__ need_out){
  __shared__ int hist[2048];
  __shared__ int seg[32];
  __shared__ int sh_b, sh_k;
  int g = blockIdx.x, tid = threadIdx.x;
  const unsigned* ug = u + (size_t)g*R;
  unsigned prefix = 0;
  int K = Ksel;
  for(int lev=0; lev<3; lev++){
    int shf = (lev==0)?21:((lev==1)?10:0);
    int nb  = (lev==2)?1024:2048;
    for(int i=tid;i<2048;i+=1024) hist[i]=0;
    __syncthreads();
    for(int i=tid;i<R;i+=1024){
      unsigned v = ug[i];
      bool ok = (lev==0) || (lev==1 && (v>>21)==prefix) || (lev==2 && (v>>10)==prefix);
      if(ok) atomicAdd(&hist[(v>>shf)&(nb-1)], 1);
    }
    __syncthreads();
    int W = nb/32;
    if(tid<32){ int s=0; int lo=nb-W*(tid+1); for(int b=lo;b<lo+W;b++) s+=hist[b]; seg[tid]=s; }
    __syncthreads();
    if(tid==0){
      int kk=K, sgi=0;
      while(seg[sgi]<kk){ kk-=seg[sgi]; sgi++; }
      int b = nb-1-W*sgi;
      while(hist[b]<kk){ kk-=hist[b]; b--; }
      sh_b=b; sh_k=kk;
    }
    __syncthreads();
    int b = sh_b; K = sh_k;
    if(lev==0) prefix = (unsigned)b;
    else if(lev==1) prefix = (prefix<<11) | (unsigned)b;
    else prefix = (prefix<<10) | (unsigned)b;
    __syncthreads();
  }
  if(tid==0){ thr_out[g]=prefix; need_out[g]=K; }
}

// deterministic compaction: take u>thr plus lowest-index u==thr (matches lax.top_k ties)
__global__ __launch_bounds__(1024) void k_compact(
    const unsigned* __restrict__ u, const float* __restrict__ score,
    const unsigned* __restrict__ thr_arr, const int* __restrict__ need_arr,
    int R, int Kout, int* __restrict__ newid, int* __restrict__ oldid,
    float* __restrict__ scale){
  __shared__ int wsA[16], wsB[16];
  __shared__ int carr0, carr1;
  int g = blockIdx.x, tid = threadIdx.x, lane = tid&63, w = tid>>6;
  unsigned thr = thr_arr[g]; int need = need_arr[g];
  if(tid==0){ carr0=0; carr1=0; }
  __syncthreads();
  for(int bb=0; bb<R; bb+=1024){
    int i = bb + tid; bool in = i < R;
    unsigned uv = in ? u[(size_t)g*R+i] : 0u;
    int eq = (in && uv==thr) ? 1:0;
    int gt = (in && uv>thr) ? 1:0;
    int inc = eq;
    for(int o=1;o<64;o<<=1){ int t=__shfl_up(inc,o,64); if(lane>=o) inc+=t; }
    if(lane==63) wsA[w]=inc;
    __syncthreads();
    int wb=0; for(int k=0;k<w;k++) wb+=wsA[k];
    int eq_excl = carr0 + wb + inc - eq;
    int take = (gt || (eq && eq_excl<need)) ? 1 : 0;
    int inc2 = take;
    for(int o=1;o<64;o<<=1){ int t=__shfl_up(inc2,o,64); if(lane>=o) inc2+=t; }
    if(lane==63) wsB[w]=inc2;
    __syncthreads();
    int wb2=0; for(int k=0;k<w;k++) wb2+=wsB[k];
    int pos = carr1 + wb2 + inc2 - take;
    if(take){
      int nr = g*Kout + pos;
      newid[(size_t)g*R+i] = nr;
      oldid[nr] = g*R+i;
      scale[nr] = score[(size_t)g*R+i];
    }
    __syncthreads();
    if(tid==1023){ carr0 += wb + inc; carr1 += wb2 + inc2; }
    __syncthreads();
  }
}

__global__ __launch_bounds__(256) void k_pool_gather(
    const float* __restrict__ x, const int* __restrict__ oldid,
    const float* __restrict__ scale, int C, int total, float* __restrict__ xnew){
  int i = blockIdx.x*256+threadIdx.x;
  if(i>=total) return;
  int r = i / C, c = i % C;
  xnew[i] = x[(size_t)oldid[r]*C + c] * scale[r];
}

// dense row-GEMM: block = 256 threads = (256/CO subgroups) x CO channels
template<int K,int CO,int NPG,bool DOELU>
__global__ __launch_bounds__(256) void k_gemm(
    const float* __restrict__ X, const float* __restrict__ W,
    const float* __restrict__ bias, float* __restrict__ Y, int n){
  constexpr int SUB = 256/CO;
  constexpr int NB = SUB*NPG;
  __shared__ float xs[NB][K];
  int tid = threadIdx.x;
  int c = tid % CO, sg = tid / CO;
  int n0 = blockIdx.x * NB;
  for(int idx=tid; idx<NB*K; idx+=256){
    int r = idx / K, k = idx % K;
    int row = n0 + r;
    xs[r][k] = (row < n) ? X[(size_t)row*K + k] : 0.f;
  }
  __syncthreads();
  float acc[NPG];
#pragma unroll
  for(int q=0;q<NPG;q++) acc[q]=0.f;
  for(int k=0;k<K;k++){
    float wv = W[(size_t)k*CO + c];
#pragma unroll
    for(int q=0;q<NPG;q++) acc[q] += xs[sg*NPG+q][k]*wv;
  }
  float bv = bias ? bias[c] : 0.f;
#pragma unroll
  for(int q=0;q<NPG;q++){
    int row = n0 + sg*NPG + q;
    if(row < n){
      float v = acc[q] + bv;
      if(DOELU) v = eluf(v);
      Y[(size_t)row*CO + c] = v;
    }
  }
}

// tiny-n tail MLP: compile-time K fully pipelined
template<int K,int CO,int ACT>
__global__ __launch_bounds__(256) void k_mlp_t(
    const float* __restrict__ X, const float* __restrict__ W,
    const float* __restrict__ b, float* __restrict__ Y, int n){
  int i = blockIdx.x*256+threadIdx.x;
  if(i>=n*CO) return;
  int r=i/CO, c=i%CO;
  const float* xr = X + (size_t)r*K;
  float a=0.f;
#pragma unroll 16
  for(int k=0;k<K;k++) a = fmaf(xr[k], W[(size_t)k*CO+c], a);
  a += b[c];
  if(ACT) a = eluf(a);
  Y[i]=a;
}

// gate scalar: wave per row, 64 lanes over K=64, coalesced + shuffle reduce
__global__ __launch_bounds__(256) void k_gatev(
    const float* __restrict__ gateb, const float* __restrict__ gw2,
    const float* __restrict__ gb2, float* __restrict__ gatev, int n){
  int wv = (blockIdx.x*256 + threadIdx.x) >> 6;
  int lane = threadIdx.x & 63;
  if(wv >= n) return;
  float v = gateb[(size_t)wv*64 + lane] * gw2[lane];
#pragma unroll
  for(int o=32;o>0;o>>=1) v += __shfl_down(v, o, 64);
  if(lane==0) gatev[wv] = v + gb2[0];
}

// per-graph softmax over gate scalars -> normalized probs
__global__ __launch_bounds__(256) void k_attn_probs(
    const float* __restrict__ gate, float* __restrict__ prob){
  __shared__ float red[256];
  int g = blockIdx.x, tid = threadIdx.x;
  float mx = -1e30f;
  for(int r=tid;r<KP2;r+=256) mx = fmaxf(mx, gate[g*KP2+r]);
  red[tid]=mx; __syncthreads();
  for(int s=128;s>0;s>>=1){ if(tid<s) red[tid]=fmaxf(red[tid],red[tid+s]); __syncthreads(); }
  mx = red[0]; __syncthreads();
  float sm=0.f;
  for(int r=tid;r<KP2;r+=256) sm += expf(gate[g*KP2+r]-mx);
  red[tid]=sm; __syncthreads();
  for(int s=128;s>0;s>>=1){ if(tid<s) red[tid]+=red[tid+s]; __syncthreads(); }
  float inv = 1.f/red[0];
  for(int r=tid;r<KP2;r+=256) prob[g*KP2+r] = expf(gate[g*KP2+r]-mx)*inv;
}

// weighted sum: grid (graph, r-chunk); block partial atomicAdd into zeroed gvec
__global__ __launch_bounds__(256) void k_attn_acc(
    const float* __restrict__ prob, const float* __restrict__ h,
    float* __restrict__ gvec, int RS){
  int g = blockIdx.x, blk = blockIdx.y, c = threadIdx.x;
  int chunk = (KP2 + RS - 1)/RS;
  int rlo = blk*chunk, rhi = rlo+chunk; if(rhi>KP2) rhi=KP2;
  float acc = 0.f;
#pragma unroll 4
  for(int r=rlo; r<rhi; r++)
    acc += prob[g*KP2+r] * h[((size_t)g*KP2+r)*256 + c];
  atomicAdd(&gvec[g*256+c], acc);
}

__global__ __launch_bounds__(64) void k_head(
    const float* __restrict__ z2, const float* __restrict__ w3,
    const float* __restrict__ b3, float* __restrict__ out){
  __shared__ float zc[10]; __shared__ float mred, sred;
  int g=blockIdx.x, tid=threadIdx.x;
  if(tid<10){
    float a=0.f;
#pragma unroll 16
    for(int k=0;k<128;k++) a += z2[g*128+k]*w3[k*10+tid];
    zc[tid]=a+b3[tid];
  }
  __syncthreads();
  if(tid==0){
    float m=zc[0];
    for(int k=1;k<10;k++) m=fmaxf(m,zc[k]);
    float s=0.f;
    for(int k=0;k<10;k++) s+=expf(zc[k]-m);
    mred=m; sred=logf(s);
  }
  __syncthreads();
  if(tid<10) out[g*10+tid]=zc[tid]-mred-sred;
}

} // namespace pk

extern "C" void kernel_launch(void* const* d_in, const int* in_sizes, int n_in,
                              void* d_out, int out_size, void* d_ws, size_t ws_size,
                              hipStream_t stream){
  using namespace pk;
  (void)in_sizes; (void)n_in; (void)out_size;
  const float* pos = (const float*)d_in[0];
  const int*   src = (const int*)d_in[1];
  const int*   dst = (const int*)d_in[2];
  const float* W1  = (const float*)d_in[3];
  const float* as1 = (const float*)d_in[4];
  const float* ad1 = (const float*)d_in[5];
  const float* b1  = (const float*)d_in[6];
  const float* p1  = (const float*)d_in[7];
  const float* W2  = (const float*)d_in[8];
  const float* as2 = (const float*)d_in[9];
  const float* ad2 = (const float*)d_in[10];
  const float* b2  = (const float*)d_in[11];
  const float* p2  = (const float*)d_in[12];
  const float* W3  = (const float*)d_in[13];
  const float* as3 = (const float*)d_in[14];
  const float* ad3 = (const float*)d_in[15];
  const float* b3  = (const float*)d_in[16];
  const float* gw1 = (const float*)d_in[17];
  const float* gb1 = (const float*)d_in[18];
  const float* gw2 = (const float*)d_in[19];
  const float* gb2 = (const float*)d_in[20];
  const float* aw  = (const float*)d_in[21];
  const float* ab  = (const float*)d_in[22];
  const float* w1  = (const float*)d_in[23];
  const float* bb1 = (const float*)d_in[24];
  const float* w2  = (const float*)d_in[25];
  const float* bb2 = (const float*)d_in[26];
  const float* w3  = (const float*)d_in[27];
  const float* bb3 = (const float*)d_in[28];
  float* out = (float*)d_out;

  char* base = (char*)d_ws; size_t off = 0;
  auto alloc = [&](size_t nbytes)->char*{
    char* p = base + off; off = (off + nbytes + 255) & ~(size_t)255; return p;
  };
  // --- zero-init region (one memset) ---
  int*   cnt1  = (int*)alloc((size_t)NB1*4);
  int*   cnt2  = (int*)alloc((size_t)NN2*4);
  int*   cnt3  = (int*)alloc((size_t)NN3*4);
  int*   ecnt2 = (int*)alloc(4);
  int*   ecnt3 = (int*)alloc(4);
  float* acc1  = (float*)alloc((size_t)BG*32*2*4);
  float* acc2  = (float*)alloc((size_t)BG*128*2*4);
  float* acc3  = (float*)alloc((size_t)BG*256*2*4);
  float* gvec  = (float*)alloc((size_t)BG*256*4);
  size_t zend = off;
  // --- 0xFF-init region (newid = -1, one memset) ---
  int*   newid1 = (int*)alloc((size_t)NB1*4);
  int*   newid2 = (int*)alloc((size_t)NN2*4);
  size_t fstart = (size_t)((char*)newid1 - base);
  size_t fend = off;
  // --- plain scratch ---
  int*      bsum   = (int*)alloc((size_t)64*4);
  float*    xp1    = (float*)alloc((size_t)NB1*32*4);
  float*    als1   = (float*)alloc((size_t)NB1*2*4);
  float*    ald1   = (float*)alloc((size_t)NB1*2*4);
  int*      rowptr1= (int*)alloc((size_t)(NB1+1)*4);
  int*      cursor1= (int*)alloc((size_t)NB1*4);
  int*      esrc1  = (int*)alloc((size_t)NE*4);
  float*    wexp1  = (float*)alloc((size_t)NE*2*4);
  float*    wself1 = (float*)alloc((size_t)NB1*2*4);
  float*    wden1  = (float*)alloc((size_t)NB1*2*4);
  float*    out1   = (float*)alloc((size_t)NB1*32*4);
  float*    score1 = (float*)alloc((size_t)NB1*4);
  unsigned* u1     = (unsigned*)alloc((size_t)NB1*4);
  unsigned* thr1   = (unsigned*)alloc((size_t)BG*4);
  int*      need1  = (int*)alloc((size_t)BG*4);
  int*      oldid1 = (int*)alloc((size_t)NN2*4);
  float*    scale1 = (float*)alloc((size_t)NN2*4);
  float*    xnew1  = (float*)alloc((size_t)NN2*32*4);
  int*      ns2    = (int*)alloc((size_t)CAP2*4);
  int*      nd2    = (int*)alloc((size_t)CAP2*4);
  int*      rowptr2= (int*)alloc((size_t)(NN2+1)*4);
  int*      cursor2= (int*)alloc((size_t)NN2*4);
  int*      esrc2  = (int*)alloc((size_t)CAP2*4);
  float*    wexp2  = (float*)alloc((size_t)CAP2*2*4);
  float*    wself2 = (float*)alloc((size_t)NN2*2*4);
  float*    wden2  = (float*)alloc((size_t)NN2*2*4);
  float*    xp2    = (float*)alloc((size_t)NN2*128*4);
  float*    als2   = (float*)alloc((size_t)NN2*2*4);
  float*    ald2   = (float*)alloc((size_t)NN2*2*4);
  float*    out2   = (float*)alloc((size_t)NN2*128*4);
  float*    score2 = (float*)alloc((size_t)NN2*4);
  unsigned* u2     = (unsigned*)alloc((size_t)NN2*4);
  unsigned* thr2   = (unsigned*)alloc((size_t)BG*4);
  int*      need2  = (int*)alloc((size_t)BG*4);
  int*      oldid2 = (int*)alloc((size_t)NN3*4);
  float*    scale2 = (float*)alloc((size_t)NN3*4);
  float*    xnew2  = (float*)alloc((size_t)NN3*128*4);
  int*      ns3    = (int*)alloc((size_t)CAP3*4);
  int*      nd3    = (int*)alloc((size_t)CAP3*4);
  int*      rowptr3= (int*)alloc((size_t)(NN3+1)*4);
  int*      cursor3= (int*)alloc((size_t)NN3*4);
  int*      esrc3  = (int*)alloc((size_t)CAP3*4);
  float*    wexp3  = (float*)alloc((size_t)CAP3*4);
  float*    wself3 = (float*)alloc((size_t)NN3*4);
  float*    wden3  = (float*)alloc((size_t)NN3*4);
  float*    xp3    = (float*)alloc((size_t)NN3*256*4);
  float*    als3   = (float*)alloc((size_t)NN3*4);
  float*    ald3   = (float*)alloc((size_t)NN3*4);
  float*    out3   = (float*)alloc((size_t)NN3*256*4);
  float*    gateb  = (float*)alloc((size_t)NN3*64*4);
  float*    gatev  = (float*)alloc((size_t)NN3*4);
  float*    probs  = (float*)alloc((size_t)NN3*4);
  float*    hbuf   = (float*)alloc((size_t)NN3*256*4);
  float*    z1     = (float*)alloc((size_t)BG*512*4);
  float*    z2     = (float*)alloc((size_t)BG*128*4);
  if(off > ws_size) return;  // workspace too small: fail visibly

  auto cdiv = [](int a, int b){ return (a+b-1)/b; };
  auto scan3 = [&](const int* cnt, int n, int* rowptr, int* cursor){
    int nb = cdiv(n, 2048);
    k_scan_part<<<nb,256,0,stream>>>(cnt, n, rowptr, bsum);
    k_scan_mid<<<1,64,0,stream>>>(bsum, nb, rowptr + n);
    k_scan_add<<<cdiv(n,256),256,0,stream>>>(rowptr, bsum, n, rowptr, cursor);
  };

  hipMemsetAsync(base, 0, zend, stream);
  hipMemsetAsync(base + fstart, 0xFF, fend - fstart, stream);

  // ---------------- stage 1: GAT(3->32, H=2,F=16) ----------------
  k_xp1<<<cdiv(NB1,256),256,0,stream>>>(pos,W1,as1,ad1,xp1,als1,ald1);
  k_edge_count<<<cdiv(NE,256),256,0,stream>>>(dst,nullptr,NE,NE,cnt1);
  scan3(cnt1,NB1,rowptr1,cursor1);
  k_scatter<<<cdiv(NE,256),256,0,stream>>>(src,dst,nullptr,NE,NE,cursor1,esrc1);
  k_gat_w<2><<<cdiv(NB1*2,256),256,0,stream>>>(als1,ald1,rowptr1,esrc1,wexp1,wself1,wden1,NB1);
  k_gat_agg<2,16><<<cdiv(NB1*8,256),256,0,stream>>>(xp1,rowptr1,esrc1,wexp1,wself1,wden1,b1,out1,NB1);
  k_inorm_stats<<<BG*16,256,0,stream>>>(out1,8192,32,16,acc1);
  k_inorm_apply<<<cdiv(NB1*32,256),256,0,stream>>>(out1,acc1,8192,32,NB1*32);
  // ---------------- pool 1 (k=2458) ----------------
  k_score<<<cdiv(NB1,256),256,0,stream>>>(out1,p1,32,NB1,score1,u1);
  k_select<<<BG,1024,0,stream>>>(u1,8192,KP1,thr1,need1);
  k_compact<<<BG,1024,0,stream>>>(u1,score1,thr1,need1,8192,KP1,newid1,oldid1,scale1);
  k_pool_gather<<<cdiv(NN2*32,256),256,0,stream>>>(out1,oldid1,scale1,32,NN2*32,xnew1);
  k_edge_compact<<<cdiv(NE,256),256,0,stream>>>(src,dst,nullptr,NE,NE,newid1,ecnt2,ns2,nd2,CAP2,cnt2);
  // ---------------- stage 2: GAT(32->128, H=2,F=64) ----------------
  scan3(cnt2,NN2,rowptr2,cursor2);
  k_scatter<<<cdiv(CAP2,256),256,0,stream>>>(ns2,nd2,ecnt2,0,CAP2,cursor2,esrc2);
  k_gemm<32,128,4,false><<<cdiv(NN2,8),256,0,stream>>>(xnew1,W2,nullptr,xp2,NN2);
  k_al<<<cdiv(NN2*2,256),256,0,stream>>>(xp2,as2,ad2,NN2,2,64,als2,ald2);
  k_gat_w<2><<<cdiv(NN2*2,256),256,0,stream>>>(als2,ald2,rowptr2,esrc2,wexp2,wself2,wden2,NN2);
  k_gat_agg<2,64><<<cdiv(NN2*32,256),256,0,stream>>>(xp2,rowptr2,esrc2,wexp2,wself2,wden2,b2,out2,NN2);
  k_inorm_stats<<<BG*16,256,0,stream>>>(out2,KP1,128,16,acc2);
  k_inorm_apply<<<cdiv(NN2*128,256),256,0,stream>>>(out2,acc2,KP1,128,NN2*128);
  // ---------------- pool 2 (k=738) ----------------
  k_score<<<cdiv(NN2,256),256,0,stream>>>(out2,p2,128,NN2,score2,u2);
  k_select<<<BG,1024,0,stream>>>(u2,KP1,KP2,thr2,need2);
  k_compact<<<BG,1024,0,stream>>>(u2,score2,thr2,need2,KP1,KP2,newid2,oldid2,scale2);
  k_pool_gather<<<cdiv(NN3*128,256),256,0,stream>>>(out2,oldid2,scale2,128,NN3*128,xnew2);
  k_edge_compact<<<cdiv(CAP2,256),256,0,stream>>>(ns2,nd2,ecnt2,0,CAP2,newid2,ecnt3,ns3,nd3,CAP3,cnt3);
  // ---------------- stage 3: GAT(128->256, H=1,F=256) ----------------
  scan3(cnt3,NN3,rowptr3,cursor3);
  k_scatter<<<cdiv(CAP3,256),256,0,stream>>>(ns3,nd3,ecnt3,0,CAP3,cursor3,esrc3);
  k_gemm<128,256,4,false><<<cdiv(NN3,4),256,0,stream>>>(xnew2,W3,nullptr,xp3,NN3);
  k_al<<<cdiv(NN3,256),256,0,stream>>>(xp3,as3,ad3,NN3,1,256,als3,ald3);
  k_gat_w<1><<<cdiv(NN3,256),256,0,stream>>>(als3,ald3,rowptr3,esrc3,wexp3,wself3,wden3,NN3);
  k_gat_agg<1,256><<<cdiv(NN3*64,256),256,0,stream>>>(xp3,rowptr3,esrc3,wexp3,wself3,wden3,b3,out3,NN3);
  k_inorm_stats<<<BG*8,256,0,stream>>>(out3,KP2,256,8,acc3);
  k_inorm_apply<<<cdiv(NN3*256,256),256,0,stream>>>(out3,acc3,KP2,256,NN3*256);
  // ---------------- global attention + MLP head ----------------
  k_gemm<256,64,2,true><<<cdiv(NN3,8),256,0,stream>>>(out3,gw1,gb1,gateb,NN3);
  k_gatev<<<cdiv(NN3,4),256,0,stream>>>(gateb,gw2,gb2,gatev,NN3);
  k_gemm<256,256,4,true><<<cdiv(NN3,4),256,0,stream>>>(out3,aw,ab,hbuf,NN3);
  k_attn_probs<<<BG,256,0,stream>>>(gatev,probs);
  k_attn_acc<<<dim3(BG,24),256,0,stream>>>(probs,hbuf,gvec,24);
  k_mlp_t<256,512,1><<<cdiv(BG*512,256),256,0,stream>>>(gvec,w1,bb1,z1,BG);
  k_mlp_t<512,128,1><<<cdiv(BG*128,256),256,0,stream>>>(z1,w2,bb2,z2,BG);
  k_head<<<BG,64,0,stream>>>(z2,w3,bb3,out);
}

// Round 7
// 661.711 us; speedup vs baseline: 1.8385x; 1.0539x over previous
//
#include <hip/hip_runtime.h>
#include <cstdint>
#include <cstddef>

#define DI __device__ __forceinline__

namespace pk {

constexpr int NB1 = 65536;      // stage-1 nodes (B*N)
constexpr int NE  = 1048576;    // edges (B*N*DEG)
constexpr int BG  = 8;          // graphs
constexpr int KP1 = 2458;       // top-k 1
constexpr int KP2 = 738;        // top-k 2
constexpr int NN2 = BG*KP1;     // 19664
constexpr int NN3 = BG*KP2;     // 5904
constexpr int CAP2 = 524288;    // edge-buffer cap after pool1 (expected ~94K)
constexpr int CAP3 = 131072;    // edge-buffer cap after pool2 (expected ~8.5K)

DI float lrelu(float x){ return x > 0.f ? x : 0.2f*x; }
DI float eluf(float x){ return x > 0.f ? x : expf(x) - 1.f; }

// XCD-affinity swizzle: blocks dispatch round-robin over 8 XCDs (b%8).
// Remap so XCD x handles a CONTIGUOUS 1/8 of the grid -> with 8 graphs,
// XCD x owns graph x: scatter/gather working sets stay in its private L2.
// Perf heuristic only — correctness unaffected if mapping differs.
DI int swz_block(){
  int nb = gridDim.x, b = blockIdx.x;
  if((nb & 7) == 0) return (b & 7)*(nb >> 3) + (b >> 3);
  return b;
}

// ---- stage-1 projection: xp = pos @ W1 (K=3), plus attention logits per head
__global__ __launch_bounds__(256) void k_xp1(
    const float* __restrict__ pos, const float* __restrict__ W,
    const float* __restrict__ as_, const float* __restrict__ ad_,
    float* __restrict__ xp, float* __restrict__ als, float* __restrict__ ald){
  int i = blockIdx.x*256 + threadIdx.x;
  if(i >= NB1) return;
  float p0=pos[3*i], p1=pos[3*i+1], p2=pos[3*i+2];
  float row[32];
#pragma unroll
  for(int c=0;c<32;c++) row[c] = p0*W[c] + p1*W[32+c] + p2*W[64+c];
  float s0=0.f,d0=0.f,s1=0.f,d1=0.f;
#pragma unroll
  for(int f=0;f<16;f++){
    s0 += row[f]*as_[f];        d0 += row[f]*ad_[f];
    s1 += row[16+f]*as_[16+f];  d1 += row[16+f]*ad_[16+f];
  }
  float4* o = reinterpret_cast<float4*>(xp + (size_t)i*32);
#pragma unroll
  for(int q=0;q<8;q++) o[q] = make_float4(row[4*q],row[4*q+1],row[4*q+2],row[4*q+3]);
  als[2*i]=s0; als[2*i+1]=s1; ald[2*i]=d0; ald[2*i+1]=d1;
}

DI int edge_m(const int* mptr, int fixedm, int mcap){
  int m = mptr ? *mptr : fixedm;
  return m < mcap ? m : mcap;
}

__global__ __launch_bounds__(256) void k_edge_count(
    const int* __restrict__ de, const int* __restrict__ mptr,
    int fixedm, int mcap, int* __restrict__ cnt){
  int i = blockIdx.x*256 + threadIdx.x;
  if(i < edge_m(mptr,fixedm,mcap)) atomicAdd(&cnt[de[i]], 1);
}

// CSR scatter with XCD-affinity swizzle (fixes R5's 13x write amplification).
__global__ __launch_bounds__(256) void k_scatter(
    const int* __restrict__ se, const int* __restrict__ de,
    const int* __restrict__ mptr, int fixedm, int mcap,
    int* __restrict__ cursor, int* __restrict__ eo){
  int i = swz_block()*256 + threadIdx.x;
  if(i < edge_m(mptr,fixedm,mcap)){
    int p = atomicAdd(&cursor[de[i]], 1);
    eo[p] = se[i];
  }
}

// LDS-staged stream compaction: 2048 edges/block over 8 tiles, survivors
// staged in LDS, ONE global atomic per block + coalesced burst write-out.
// (R6: 4096 same-address atomics-with-return ~= 30cy each serialized = 51us;
// this cuts the atomic count 8x and makes output writes coalesced.)
// Fused per-dst degree counting for the NEXT stage's CSR build.
__global__ __launch_bounds__(256) void k_edge_compact(
    const int* __restrict__ se, const int* __restrict__ de,
    const int* __restrict__ mptr, int fixedm, int mcap,
    const int* __restrict__ newid, int* __restrict__ ocnt,
    int* __restrict__ ons, int* __restrict__ ond, int ocap,
    int* __restrict__ cnt){
  constexpr int TILES = 8;
  __shared__ int s_a[256*TILES];
  __shared__ int s_b[256*TILES];
  __shared__ int wcnt[4];
  __shared__ int run;
  __shared__ int tbase;
  int tid = threadIdx.x, lane = tid & 63, w = tid >> 6;
  int m = edge_m(mptr, fixedm, mcap);
  if(tid == 0) run = 0;
  __syncthreads();
  int base = swz_block()*(256*TILES);
  for(int t=0; t<TILES; t++){
    int i = base + t*256 + tid;
    bool act=false; int a=0, b=0;
    if(i < m){ a = newid[se[i]]; b = newid[de[i]]; act = (a>=0 && b>=0); }
    unsigned long long mask = __ballot(act);
    int rank = __popcll(mask & ((1ull<<lane)-1ull));
    if(lane==0) wcnt[w] = __popcll(mask);
    __syncthreads();
    int off = run;
    for(int k=0;k<w;k++) off += wcnt[k];
    if(act){
      int p = off + rank;
      s_a[p] = a; s_b[p] = b;
      atomicAdd(&cnt[b], 1);
    }
    __syncthreads();
    if(tid==0) run += wcnt[0]+wcnt[1]+wcnt[2]+wcnt[3];
    __syncthreads();
  }
  int ns = run;
  if(tid==0) tbase = ns ? atomicAdd(ocnt, ns) : 0;
  __syncthreads();
  int tb = tbase;
  for(int j=tid; j<ns; j+=256){
    int s = tb + j;
    if(s < ocap){ ons[s] = s_a[j]; ond[s] = s_b[j]; }
  }
}

// ---- multi-block exclusive scan (3 dispatches)
__global__ __launch_bounds__(256) void k_scan_part(
    const int* __restrict__ cnt, int n, int* __restrict__ pre,
    int* __restrict__ bsum){
  __shared__ int wsum[4];
  int tid = threadIdx.x, lane = tid & 63, w = tid >> 6;
  int base = blockIdx.x*2048 + tid*8;
  int v[8]; int s = 0;
#pragma unroll
  for(int j=0;j<8;j++){ int i = base+j; int x = (i<n)?cnt[i]:0; v[j]=s; s+=x; }
  int inc = s;
  for(int o=1;o<64;o<<=1){ int t=__shfl_up(inc,o,64); if(lane>=o) inc+=t; }
  if(lane==63) wsum[w]=inc;
  __syncthreads();
  int wb=0;
  for(int k=0;k<w;k++) wb+=wsum[k];
  int tb = wb + inc - s;
#pragma unroll
  for(int j=0;j<8;j++){ int i = base+j; if(i<n) pre[i]=tb+v[j]; }
  if(tid==255) bsum[blockIdx.x] = wb + inc;   // block total
}
__global__ __launch_bounds__(64) void k_scan_mid(
    int* __restrict__ bsum, int nb, int* __restrict__ rowptr_n){
  int lane = threadIdx.x;
  int v = (lane<nb) ? bsum[lane] : 0;
  int inc = v;
  for(int o=1;o<64;o<<=1){ int t=__shfl_up(inc,o,64); if(lane>=o) inc+=t; }
  if(lane<nb) bsum[lane] = inc - v;
  if(lane==63) *rowptr_n = inc;
}
__global__ __launch_bounds__(256) void k_scan_add(
    const int* __restrict__ pre, const int* __restrict__ bsum, int n,
    int* __restrict__ rowptr, int* __restrict__ cursor){
  int i = blockIdx.x*256 + threadIdx.x;
  if(i < n){
    int v = pre[i] + bsum[i >> 11];
    rowptr[i] = v; cursor[i] = v;
  }
}

// attention weights, SINGLE pass (no max-subtraction: logits bounded ~|25|,
// exp safe in fp32; the max factor cancels in the normalized weights).
template<int H>
__global__ __launch_bounds__(256) void k_gat_w(
    const float* __restrict__ als, const float* __restrict__ ald,
    const int* __restrict__ rowptr, const int* __restrict__ esrc,
    float* __restrict__ wexp, float* __restrict__ wself,
    float* __restrict__ wden, int n){
  int t = swz_block()*256 + threadIdx.x;
  if(t >= n*H) return;
  int node = t / H, hh = t % H;
  float aldn = ald[node*H+hh];
  float sw = expf(lrelu(als[node*H+hh] + aldn));
  float den = sw;
  int r0 = rowptr[node], r1 = rowptr[node+1];
  for(int k=r0;k<r1;k++){
    float ex = expf(lrelu(als[esrc[k]*H+hh] + aldn));
    wexp[(size_t)k*H+hh] = ex;
    den += ex;
  }
  wself[node*H+hh] = sw;
  wden[node*H+hh] = den;
}

// weighted aggregate: thread = (node, 4-channel group). Inner loop per edge:
// 1 broadcast weight load + 1 float4 xp gather + 4 FMAs.
template<int H,int F>
__global__ __launch_bounds__(256) void k_gat_agg(
    const float* __restrict__ xp, const int* __restrict__ rowptr,
    const int* __restrict__ esrc, const float* __restrict__ wexp,
    const float* __restrict__ wself, const float* __restrict__ wden,
    const float* __restrict__ bias, float* __restrict__ out, int n){
  constexpr int C = H*F, C4 = C/4;
  int t = swz_block()*256 + threadIdx.x;
  int node = t / C4, p = t % C4;
  if(node >= n) return;
  int hh = (4*p) / F;
  const float4* xp4 = (const float4*)xp;
  float4 xs = xp4[(size_t)node*C4 + p];
  float sw = wself[node*H+hh];
  float ax = sw*xs.x, ay = sw*xs.y, az = sw*xs.z, aw_ = sw*xs.w;
  int r0 = rowptr[node], r1 = rowptr[node+1];
  for(int k=r0;k<r1;k++){
    int s = esrc[k];
    float wv = wexp[(size_t)k*H+hh];
    float4 v = xp4[(size_t)s*C4 + p];
    ax += wv*v.x; ay += wv*v.y; az += wv*v.z; aw_ += wv*v.w;
  }
  float inv = 1.f / wden[node*H+hh];
  const float4* b4 = (const float4*)bias;
  float4 bv = b4[p];
  float4 r; r.x = ax*inv + bv.x; r.y = ay*inv + bv.y;
  r.z = az*inv + bv.z; r.w = aw_*inv + bv.w;
  ((float4*)out)[(size_t)node*C4 + p] = r;
}

__global__ __launch_bounds__(256) void k_al(
    const float* __restrict__ xp, const float* __restrict__ a_s,
    const float* __restrict__ a_d, int n, int H, int F,
    float* __restrict__ als, float* __restrict__ ald){
  int i = blockIdx.x*256+threadIdx.x;
  if(i >= n*H) return;
  int node = i/H, hh = i%H;
  const float* row = xp + (size_t)node*H*F + hh*F;
  float s=0.f, d=0.f;
  for(int f=0;f<F;f++){ s += row[f]*a_s[hh*F+f]; d += row[f]*a_d[hh*F+f]; }
  als[i]=s; ald[i]=d;
}

__global__ __launch_bounds__(256) void k_inorm_stats(
    const float* __restrict__ x, int R, int C, int RS, float* __restrict__ accum){
  int g = blockIdx.x / RS, blk = blockIdx.x % RS;
  int NS = 256 / C;
  int c = threadIdx.x % C, rs = threadIdx.x / C;
  int chunk = (R + RS - 1)/RS;
  int rlo = blk*chunk, rhi = rlo+chunk; if(rhi>R) rhi=R;
  float s=0.f, sq=0.f;
  for(int r=rlo+rs; r<rhi; r+=NS){ float v = x[((size_t)g*R+r)*C + c]; s+=v; sq+=v*v; }
  atomicAdd(&accum[(g*C+c)*2], s);
  atomicAdd(&accum[(g*C+c)*2+1], sq);
}

__global__ __launch_bounds__(256) void k_inorm_apply(
    float* __restrict__ x, const float* __restrict__ accum, int R, int C, int total){
  int i = blockIdx.x*256+threadIdx.x;
  if(i>=total) return;
  int c = i % C; int g = i / (R*C);
  float s = accum[(g*C+c)*2], sq = accum[(g*C+c)*2+1];
  float mu = s / (float)R;
  float var = sq / (float)R - mu*mu; var = fmaxf(var, 0.f);
  float v = (x[i]-mu)*rsqrtf(var+1e-5f);
  x[i] = eluf(v);
}

__global__ __launch_bounds__(256) void k_score(
    const float* __restrict__ x, const float* __restrict__ p,
    int C, int n, float* __restrict__ score, unsigned* __restrict__ u){
  int i = blockIdx.x*256+threadIdx.x;
  if(i>=n) return;
  float a=0.f, nn=0.f;
  for(int c=0;c<C;c++){ float pv=p[c]; a += x[(size_t)i*C+c]*pv; nn += pv*pv; }
  float sv = tanhf(a/sqrtf(nn));
  score[i]=sv;
  unsigned bts = __float_as_uint(sv);
  u[i] = (bts & 0x80000000u) ? ~bts : (bts | 0x80000000u);
}

// per-graph 3-level radix select on orderable uints: exact k-th value + #ties needed
__global__ __launch_bounds__(1024) void k_select(
    const unsigned* __restrict__ u, int R, int Ksel,
    unsigned* __restrict__ thr_out, int* __restrict__ need_out){
  __shared__ int hist[2048];
  __shared__ int seg[32];
  __shared__ int sh_b, sh_k;
  int g = blockIdx.x, tid = threadIdx.x;
  const unsigned* ug = u + (size_t)g*R;
  unsigned prefix = 0;
  int K = Ksel;
  for(int lev=0; lev<3; lev++){
    int shf = (lev==0)?21:((lev==1)?10:0);
    int nb  = (lev==2)?1024:2048;
    for(int i=tid;i<2048;i+=1024) hist[i]=0;
    __syncthreads();
    for(int i=tid;i<R;i+=1024){
      unsigned v = ug[i];
      bool ok = (lev==0) || (lev==1 && (v>>21)==prefix) || (lev==2 && (v>>10)==prefix);
      if(ok) atomicAdd(&hist[(v>>shf)&(nb-1)], 1);
    }
    __syncthreads();
    int W = nb/32;
    if(tid<32){ int s=0; int lo=nb-W*(tid+1); for(int b=lo;b<lo+W;b++) s+=hist[b]; seg[tid]=s; }
    __syncthreads();
    if(tid==0){
      int kk=K, sgi=0;
      while(seg[sgi]<kk){ kk-=seg[sgi]; sgi++; }
      int b = nb-1-W*sgi;
      while(hist[b]<kk){ kk-=hist[b]; b--; }
      sh_b=b; sh_k=kk;
    }
    __syncthreads();
    int b = sh_b; K = sh_k;
    if(lev==0) prefix = (unsigned)b;
    else if(lev==1) prefix = (prefix<<11) | (unsigned)b;
    else prefix = (prefix<<10) | (unsigned)b;
    __syncthreads();
  }
  if(tid==0){ thr_out[g]=prefix; need_out[g]=K; }
}

// deterministic compaction: take u>thr plus lowest-index u==thr (matches lax.top_k ties)
__global__ __launch_bounds__(1024) void k_compact(
    const unsigned* __restrict__ u, const float* __restrict__ score,
    const unsigned* __restrict__ thr_arr, const int* __restrict__ need_arr,
    int R, int Kout, int* __restrict__ newid, int* __restrict__ oldid,
    float* __restrict__ scale){
  __shared__ int wsA[16], wsB[16];
  __shared__ int carr0, carr1;
  int g = blockIdx.x, tid = threadIdx.x, lane = tid&63, w = tid>>6;
  unsigned thr = thr_arr[g]; int need = need_arr[g];
  if(tid==0){ carr0=0; carr1=0; }
  __syncthreads();
  for(int bb=0; bb<R; bb+=1024){
    int i = bb + tid; bool in = i < R;
    unsigned uv = in ? u[(size_t)g*R+i] : 0u;
    int eq = (in && uv==thr) ? 1:0;
    int gt = (in && uv>thr) ? 1:0;
    int inc = eq;
    for(int o=1;o<64;o<<=1){ int t=__shfl_up(inc,o,64); if(lane>=o) inc+=t; }
    if(lane==63) wsA[w]=inc;
    __syncthreads();
    int wb=0; for(int k=0;k<w;k++) wb+=wsA[k];
    int eq_excl = carr0 + wb + inc - eq;
    int take = (gt || (eq && eq_excl<need)) ? 1 : 0;
    int inc2 = take;
    for(int o=1;o<64;o<<=1){ int t=__shfl_up(inc2,o,64); if(lane>=o) inc2+=t; }
    if(lane==63) wsB[w]=inc2;
    __syncthreads();
    int wb2=0; for(int k=0;k<w;k++) wb2+=wsB[k];
    int pos = carr1 + wb2 + inc2 - take;
    if(take){
      int nr = g*Kout + pos;
      newid[(size_t)g*R+i] = nr;
      oldid[nr] = g*R+i;
      scale[nr] = score[(size_t)g*R+i];
    }
    __syncthreads();
    if(tid==1023){ carr0 += wb + inc; carr1 += wb2 + inc2; }
    __syncthreads();
  }
}

__global__ __launch_bounds__(256) void k_pool_gather(
    const float* __restrict__ x, const int* __restrict__ oldid,
    const float* __restrict__ scale, int C, int total, float* __restrict__ xnew){
  int i = blockIdx.x*256+threadIdx.x;
  if(i>=total) return;
  int r = i / C, c = i % C;
  xnew[i] = x[(size_t)oldid[r]*C + c] * scale[r];
}

// dense row-GEMM: block = 256 threads = (256/CO subgroups) x CO channels
template<int K,int CO,int NPG,bool DOELU>
__global__ __launch_bounds__(256) void k_gemm(
    const float* __restrict__ X, const float* __restrict__ W,
    const float* __restrict__ bias, float* __restrict__ Y, int n){
  constexpr int SUB = 256/CO;
  constexpr int NB = SUB*NPG;
  __shared__ float xs[NB][K];
  int tid = threadIdx.x;
  int c = tid % CO, sg = tid / CO;
  int n0 = blockIdx.x * NB;
  for(int idx=tid; idx<NB*K; idx+=256){
    int r = idx / K, k = idx % K;
    int row = n0 + r;
    xs[r][k] = (row < n) ? X[(size_t)row*K + k] : 0.f;
  }
  __syncthreads();
  float acc[NPG];
#pragma unroll
  for(int q=0;q<NPG;q++) acc[q]=0.f;
  for(int k=0;k<K;k++){
    float wv = W[(size_t)k*CO + c];
#pragma unroll
    for(int q=0;q<NPG;q++) acc[q] += xs[sg*NPG+q][k]*wv;
  }
  float bv = bias ? bias[c] : 0.f;
#pragma unroll
  for(int q=0;q<NPG;q++){
    int row = n0 + sg*NPG + q;
    if(row < n){
      float v = acc[q] + bv;
      if(DOELU) v = eluf(v);
      Y[(size_t)row*CO + c] = v;
    }
  }
}

// tiny-n tail MLP: compile-time K fully pipelined
template<int K,int CO,int ACT>
__global__ __launch_bounds__(256) void k_mlp_t(
    const float* __restrict__ X, const float* __restrict__ W,
    const float* __restrict__ b, float* __restrict__ Y, int n){
  int i = blockIdx.x*256+threadIdx.x;
  if(i>=n*CO) return;
  int r=i/CO, c=i%CO;
  const float* xr = X + (size_t)r*K;
  float a=0.f;
#pragma unroll 16
  for(int k=0;k<K;k++) a = fmaf(xr[k], W[(size_t)k*CO+c], a);
  a += b[c];
  if(ACT) a = eluf(a);
  Y[i]=a;
}

// gate scalar: wave per row, 64 lanes over K=64, coalesced + shuffle reduce
__global__ __launch_bounds__(256) void k_gatev(
    const float* __restrict__ gateb, const float* __restrict__ gw2,
    const float* __restrict__ gb2, float* __restrict__ gatev, int n){
  int wv = (blockIdx.x*256 + threadIdx.x) >> 6;
  int lane = threadIdx.x & 63;
  if(wv >= n) return;
  float v = gateb[(size_t)wv*64 + lane] * gw2[lane];
#pragma unroll
  for(int o=32;o>0;o>>=1) v += __shfl_down(v, o, 64);
  if(lane==0) gatev[wv] = v + gb2[0];
}

// per-graph softmax over gate scalars -> normalized probs
__global__ __launch_bounds__(256) void k_attn_probs(
    const float* __restrict__ gate, float* __restrict__ prob){
  __shared__ float red[256];
  int g = blockIdx.x, tid = threadIdx.x;
  float mx = -1e30f;
  for(int r=tid;r<KP2;r+=256) mx = fmaxf(mx, gate[g*KP2+r]);
  red[tid]=mx; __syncthreads();
  for(int s=128;s>0;s>>=1){ if(tid<s) red[tid]=fmaxf(red[tid],red[tid+s]); __syncthreads(); }
  mx = red[0]; __syncthreads();
  float sm=0.f;
  for(int r=tid;r<KP2;r+=256) sm += expf(gate[g*KP2+r]-mx);
  red[tid]=sm; __syncthreads();
  for(int s=128;s>0;s>>=1){ if(tid<s) red[tid]+=red[tid+s]; __syncthreads(); }
  float inv = 1.f/red[0];
  for(int r=tid;r<KP2;r+=256) prob[g*KP2+r] = expf(gate[g*KP2+r]-mx)*inv;
}

// weighted sum: grid (graph, r-chunk); block partial atomicAdd into zeroed gvec
__global__ __launch_bounds__(256) void k_attn_acc(
    const float* __restrict__ prob, const float* __restrict__ h,
    float* __restrict__ gvec, int RS){
  int g = blockIdx.x, blk = blockIdx.y, c = threadIdx.x;
  int chunk = (KP2 + RS - 1)/RS;
  int rlo = blk*chunk, rhi = rlo+chunk; if(rhi>KP2) rhi=KP2;
  float acc = 0.f;
#pragma unroll 4
  for(int r=rlo; r<rhi; r++)
    acc += prob[g*KP2+r] * h[((size_t)g*KP2+r)*256 + c];
  atomicAdd(&gvec[g*256+c], acc);
}

__global__ __launch_bounds__(64) void k_head(
    const float* __restrict__ z2, const float* __restrict__ w3,
    const float* __restrict__ b3, float* __restrict__ out){
  __shared__ float zc[10]; __shared__ float mred, sred;
  int g=blockIdx.x, tid=threadIdx.x;
  if(tid<10){
    float a=0.f;
#pragma unroll 16
    for(int k=0;k<128;k++) a += z2[g*128+k]*w3[k*10+tid];
    zc[tid]=a+b3[tid];
  }
  __syncthreads();
  if(tid==0){
    float m=zc[0];
    for(int k=1;k<10;k++) m=fmaxf(m,zc[k]);
    float s=0.f;
    for(int k=0;k<10;k++) s+=expf(zc[k]-m);
    mred=m; sred=logf(s);
  }
  __syncthreads();
  if(tid<10) out[g*10+tid]=zc[tid]-mred-sred;
}

} // namespace pk

extern "C" void kernel_launch(void* const* d_in, const int* in_sizes, int n_in,
                              void* d_out, int out_size, void* d_ws, size_t ws_size,
                              hipStream_t stream){
  using namespace pk;
  (void)in_sizes; (void)n_in; (void)out_size;
  const float* pos = (const float*)d_in[0];
  const int*   src = (const int*)d_in[1];
  const int*   dst = (const int*)d_in[2];
  const float* W1  = (const float*)d_in[3];
  const float* as1 = (const float*)d_in[4];
  const float* ad1 = (const float*)d_in[5];
  const float* b1  = (const float*)d_in[6];
  const float* p1  = (const float*)d_in[7];
  const float* W2  = (const float*)d_in[8];
  const float* as2 = (const float*)d_in[9];
  const float* ad2 = (const float*)d_in[10];
  const float* b2  = (const float*)d_in[11];
  const float* p2  = (const float*)d_in[12];
  const float* W3  = (const float*)d_in[13];
  const float* as3 = (const float*)d_in[14];
  const float* ad3 = (const float*)d_in[15];
  const float* b3  = (const float*)d_in[16];
  const float* gw1 = (const float*)d_in[17];
  const float* gb1 = (const float*)d_in[18];
  const float* gw2 = (const float*)d_in[19];
  const float* gb2 = (const float*)d_in[20];
  const float* aw  = (const float*)d_in[21];
  const float* ab  = (const float*)d_in[22];
  const float* w1  = (const float*)d_in[23];
  const float* bb1 = (const float*)d_in[24];
  const float* w2  = (const float*)d_in[25];
  const float* bb2 = (const float*)d_in[26];
  const float* w3  = (const float*)d_in[27];
  const float* bb3 = (const float*)d_in[28];
  float* out = (float*)d_out;

  char* base = (char*)d_ws; size_t off = 0;
  auto alloc = [&](size_t nbytes)->char*{
    char* p = base + off; off = (off + nbytes + 255) & ~(size_t)255; return p;
  };
  // --- zero-init region (one memset) ---
  int*   cnt1  = (int*)alloc((size_t)NB1*4);
  int*   cnt2  = (int*)alloc((size_t)NN2*4);
  int*   cnt3  = (int*)alloc((size_t)NN3*4);
  int*   ecnt2 = (int*)alloc(4);
  int*   ecnt3 = (int*)alloc(4);
  float* acc1  = (float*)alloc((size_t)BG*32*2*4);
  float* acc2  = (float*)alloc((size_t)BG*128*2*4);
  float* acc3  = (float*)alloc((size_t)BG*256*2*4);
  float* gvec  = (float*)alloc((size_t)BG*256*4);
  size_t zend = off;
  // --- 0xFF-init region (newid = -1, one memset) ---
  int*   newid1 = (int*)alloc((size_t)NB1*4);
  int*   newid2 = (int*)alloc((size_t)NN2*4);
  size_t fstart = (size_t)((char*)newid1 - base);
  size_t fend = off;
  // --- plain scratch ---
  int*      bsum   = (int*)alloc((size_t)64*4);
  float*    xp1    = (float*)alloc((size_t)NB1*32*4);
  float*    als1   = (float*)alloc((size_t)NB1*2*4);
  float*    ald1   = (float*)alloc((size_t)NB1*2*4);
  int*      rowptr1= (int*)alloc((size_t)(NB1+1)*4);
  int*      cursor1= (int*)alloc((size_t)NB1*4);
  int*      esrc1  = (int*)alloc((size_t)NE*4);
  float*    wexp1  = (float*)alloc((size_t)NE*2*4);
  float*    wself1 = (float*)alloc((size_t)NB1*2*4);
  float*    wden1  = (float*)alloc((size_t)NB1*2*4);
  float*    out1   = (float*)alloc((size_t)NB1*32*4);
  float*    score1 = (float*)alloc((size_t)NB1*4);
  unsigned* u1     = (unsigned*)alloc((size_t)NB1*4);
  unsigned* thr1   = (unsigned*)alloc((size_t)BG*4);
  int*      need1  = (int*)alloc((size_t)BG*4);
  int*      oldid1 = (int*)alloc((size_t)NN2*4);
  float*    scale1 = (float*)alloc((size_t)NN2*4);
  float*    xnew1  = (float*)alloc((size_t)NN2*32*4);
  int*      ns2    = (int*)alloc((size_t)CAP2*4);
  int*      nd2    = (int*)alloc((size_t)CAP2*4);
  int*      rowptr2= (int*)alloc((size_t)(NN2+1)*4);
  int*      cursor2= (int*)alloc((size_t)NN2*4);
  int*      esrc2  = (int*)alloc((size_t)CAP2*4);
  float*    wexp2  = (float*)alloc((size_t)CAP2*2*4);
  float*    wself2 = (float*)alloc((size_t)NN2*2*4);
  float*    wden2  = (float*)alloc((size_t)NN2*2*4);
  float*    xp2    = (float*)alloc((size_t)NN2*128*4);
  float*    als2   = (float*)alloc((size_t)NN2*2*4);
  float*    ald2   = (float*)alloc((size_t)NN2*2*4);
  float*    out2   = (float*)alloc((size_t)NN2*128*4);
  float*    score2 = (float*)alloc((size_t)NN2*4);
  unsigned* u2     = (unsigned*)alloc((size_t)NN2*4);
  unsigned* thr2   = (unsigned*)alloc((size_t)BG*4);
  int*      need2  = (int*)alloc((size_t)BG*4);
  int*      oldid2 = (int*)alloc((size_t)NN3*4);
  float*    scale2 = (float*)alloc((size_t)NN3*4);
  float*    xnew2  = (float*)alloc((size_t)NN3*128*4);
  int*      ns3    = (int*)alloc((size_t)CAP3*4);
  int*      nd3    = (int*)alloc((size_t)CAP3*4);
  int*      rowptr3= (int*)alloc((size_t)(NN3+1)*4);
  int*      cursor3= (int*)alloc((size_t)NN3*4);
  int*      esrc3  = (int*)alloc((size_t)CAP3*4);
  float*    wexp3  = (float*)alloc((size_t)CAP3*4);
  float*    wself3 = (float*)alloc((size_t)NN3*4);
  float*    wden3  = (float*)alloc((size_t)NN3*4);
  float*    xp3    = (float*)alloc((size_t)NN3*256*4);
  float*    als3   = (float*)alloc((size_t)NN3*4);
  float*    ald3   = (float*)alloc((size_t)NN3*4);
  float*    out3   = (float*)alloc((size_t)NN3*256*4);
  float*    gateb  = (float*)alloc((size_t)NN3*64*4);
  float*    gatev  = (float*)alloc((size_t)NN3*4);
  float*    probs  = (float*)alloc((size_t)NN3*4);
  float*    hbuf   = (float*)alloc((size_t)NN3*256*4);
  float*    z1     = (float*)alloc((size_t)BG*512*4);
  float*    z2     = (float*)alloc((size_t)BG*128*4);
  if(off > ws_size) return;  // workspace too small: fail visibly

  auto cdiv = [](int a, int b){ return (a+b-1)/b; };
  auto scan3 = [&](const int* cnt, int n, int* rowptr, int* cursor){
    int nb = cdiv(n, 2048);
    k_scan_part<<<nb,256,0,stream>>>(cnt, n, rowptr, bsum);
    k_scan_mid<<<1,64,0,stream>>>(bsum, nb, rowptr + n);
    k_scan_add<<<cdiv(n,256),256,0,stream>>>(rowptr, bsum, n, rowptr, cursor);
  };

  hipMemsetAsync(base, 0, zend, stream);
  hipMemsetAsync(base + fstart, 0xFF, fend - fstart, stream);

  // ---------------- stage 1: GAT(3->32, H=2,F=16) ----------------
  k_xp1<<<cdiv(NB1,256),256,0,stream>>>(pos,W1,as1,ad1,xp1,als1,ald1);
  k_edge_count<<<cdiv(NE,256),256,0,stream>>>(dst,nullptr,NE,NE,cnt1);
  scan3(cnt1,NB1,rowptr1,cursor1);
  k_scatter<<<cdiv(NE,256),256,0,stream>>>(src,dst,nullptr,NE,NE,cursor1,esrc1);
  k_gat_w<2><<<cdiv(NB1*2,256),256,0,stream>>>(als1,ald1,rowptr1,esrc1,wexp1,wself1,wden1,NB1);
  k_gat_agg<2,16><<<cdiv(NB1*8,256),256,0,stream>>>(xp1,rowptr1,esrc1,wexp1,wself1,wden1,b1,out1,NB1);
  k_inorm_stats<<<BG*16,256,0,stream>>>(out1,8192,32,16,acc1);
  k_inorm_apply<<<cdiv(NB1*32,256),256,0,stream>>>(out1,acc1,8192,32,NB1*32);
  // ---------------- pool 1 (k=2458) ----------------
  k_score<<<cdiv(NB1,256),256,0,stream>>>(out1,p1,32,NB1,score1,u1);
  k_select<<<BG,1024,0,stream>>>(u1,8192,KP1,thr1,need1);
  k_compact<<<BG,1024,0,stream>>>(u1,score1,thr1,need1,8192,KP1,newid1,oldid1,scale1);
  k_pool_gather<<<cdiv(NN2*32,256),256,0,stream>>>(out1,oldid1,scale1,32,NN2*32,xnew1);
  k_edge_compact<<<cdiv(NE,2048),256,0,stream>>>(src,dst,nullptr,NE,NE,newid1,ecnt2,ns2,nd2,CAP2,cnt2);
  // ---------------- stage 2: GAT(32->128, H=2,F=64) ----------------
  scan3(cnt2,NN2,rowptr2,cursor2);
  k_scatter<<<cdiv(CAP2,256),256,0,stream>>>(ns2,nd2,ecnt2,0,CAP2,cursor2,esrc2);
  k_gemm<32,128,4,false><<<cdiv(NN2,8),256,0,stream>>>(xnew1,W2,nullptr,xp2,NN2);
  k_al<<<cdiv(NN2*2,256),256,0,stream>>>(xp2,as2,ad2,NN2,2,64,als2,ald2);
  k_gat_w<2><<<cdiv(NN2*2,256),256,0,stream>>>(als2,ald2,rowptr2,esrc2,wexp2,wself2,wden2,NN2);
  k_gat_agg<2,64><<<cdiv(NN2*32,256),256,0,stream>>>(xp2,rowptr2,esrc2,wexp2,wself2,wden2,b2,out2,NN2);
  k_inorm_stats<<<BG*16,256,0,stream>>>(out2,KP1,128,16,acc2);
  k_inorm_apply<<<cdiv(NN2*128,256),256,0,stream>>>(out2,acc2,KP1,128,NN2*128);
  // ---------------- pool 2 (k=738) ----------------
  k_score<<<cdiv(NN2,256),256,0,stream>>>(out2,p2,128,NN2,score2,u2);
  k_select<<<BG,1024,0,stream>>>(u2,KP1,KP2,thr2,need2);
  k_compact<<<BG,1024,0,stream>>>(u2,score2,thr2,need2,KP1,KP2,newid2,oldid2,scale2);
  k_pool_gather<<<cdiv(NN3*128,256),256,0,stream>>>(out2,oldid2,scale2,128,NN3*128,xnew2);
  k_edge_compact<<<cdiv(CAP2,2048),256,0,stream>>>(ns2,nd2,ecnt2,0,CAP2,newid2,ecnt3,ns3,nd3,CAP3,cnt3);
  // ---------------- stage 3: GAT(128->256, H=1,F=256) ----------------
  scan3(cnt3,NN3,rowptr3,cursor3);
  k_scatter<<<cdiv(CAP3,256),256,0,stream>>>(ns3,nd3,ecnt3,0,CAP3,cursor3,esrc3);
  k_gemm<128,256,4,false><<<cdiv(NN3,4),256,0,stream>>>(xnew2,W3,nullptr,xp3,NN3);
  k_al<<<cdiv(NN3,256),256,0,stream>>>(xp3,as3,ad3,NN3,1,256,als3,ald3);
  k_gat_w<1><<<cdiv(NN3,256),256,0,stream>>>(als3,ald3,rowptr3,esrc3,wexp3,wself3,wden3,NN3);
  k_gat_agg<1,256><<<cdiv(NN3*64,256),256,0,stream>>>(xp3,rowptr3,esrc3,wexp3,wself3,wden3,b3,out3,NN3);
  k_inorm_stats<<<BG*8,256,0,stream>>>(out3,KP2,256,8,acc3);
  k_inorm_apply<<<cdiv(NN3*256,256),256,0,stream>>>(out3,acc3,KP2,256,NN3*256);
  // ---------------- global attention + MLP head ----------------
  k_gemm<256,64,2,true><<<cdiv(NN3,8),256,0,stream>>>(out3,gw1,gb1,gateb,NN3);
  k_gatev<<<cdiv(NN3,4),256,0,stream>>>(gateb,gw2,gb2,gatev,NN3);
  k_gemm<256,256,4,true><<<cdiv(NN3,4),256,0,stream>>>(out3,aw,ab,hbuf,NN3);
  k_attn_probs<<<BG,256,0,stream>>>(gatev,probs);
  k_attn_acc<<<dim3(BG,24),256,0,stream>>>(probs,hbuf,gvec,24);
  k_mlp_t<256,512,1><<<cdiv(BG*512,256),256,0,stream>>>(gvec,w1,bb1,z1,BG);
  k_mlp_t<512,128,1><<<cdiv(BG*128,256),256,0,stream>>>(z1,w2,bb2,z2,BG);
  k_head<<<BG,64,0,stream>>>(z2,w3,bb3,out);
}